// Round 1
// baseline (22250.885 us; speedup 1.0000x reference)
//
#include <hip/hip_runtime.h>
#include <math.h>

// Problem constants
#define TT 128
#define ZD 2048          // 4*H
#define HH 512
#define IFC 471
#define EPSF 1e-6f
#define MST 65           // M LDS stride (padded, Wd=64)
#define LST 129          // link LDS stride (padded, N=128)

__device__ __forceinline__ float sig_(float x){ return 1.f/(1.f+expf(-x)); }
__device__ __forceinline__ float sp_(float x){ return fmaxf(x,0.f)+log1pf(expf(-fabsf(x))); }

// ---------------- generic tiled GEMM: C[M,N] = A[M,K] @ B[K,N] + bias[N]
// block 256 threads, tile 64x64, BK=16, 4x4 per-thread microtile.
__global__ __launch_bounds__(256) void gemm_bias(
    const float* __restrict__ A, const float* __restrict__ B,
    const float* __restrict__ bias, float* __restrict__ C,
    int Mr, int Nc, int K)
{
  __shared__ float As[16][68];   // [k][m], padded
  __shared__ float Bs[16][68];   // [k][n], padded
  const int tid = threadIdx.x;
  const int bx = blockIdx.x, by = blockIdx.y;
  const int tx = tid & 15, ty = tid >> 4;
  const int am = tid >> 2, ak = (tid & 3) * 4;
  const int bk = tid >> 4, bn = (tid & 15) * 4;
  float acc[4][4] = {};
  const float* Ap = A + (size_t)(by*64+am)*K + ak;
  const float* Bp = B + (size_t)bk*Nc + bx*64 + bn;
  for (int k0 = 0; k0 < K; k0 += 16) {
    float4 av = *(const float4*)Ap; Ap += 16;
    float4 bv = *(const float4*)Bp; Bp += (size_t)16*Nc;
    As[ak+0][am]=av.x; As[ak+1][am]=av.y; As[ak+2][am]=av.z; As[ak+3][am]=av.w;
    *(float4*)&Bs[bk][bn] = bv;
    __syncthreads();
#pragma unroll
    for (int kk = 0; kk < 16; ++kk) {
      float4 a4 = *(const float4*)&As[kk][ty*4];
      float4 b4 = *(const float4*)&Bs[kk][tx*4];
      acc[0][0]+=a4.x*b4.x; acc[0][1]+=a4.x*b4.y; acc[0][2]+=a4.x*b4.z; acc[0][3]+=a4.x*b4.w;
      acc[1][0]+=a4.y*b4.x; acc[1][1]+=a4.y*b4.y; acc[1][2]+=a4.y*b4.z; acc[1][3]+=a4.y*b4.w;
      acc[2][0]+=a4.z*b4.x; acc[2][1]+=a4.z*b4.y; acc[2][2]+=a4.z*b4.z; acc[2][3]+=a4.z*b4.w;
      acc[3][0]+=a4.w*b4.x; acc[3][1]+=a4.w*b4.y; acc[3][2]+=a4.w*b4.z; acc[3][3]+=a4.w*b4.w;
    }
    __syncthreads();
  }
  float4 bb = *(const float4*)(bias + bx*64 + tx*4);
#pragma unroll
  for (int i = 0; i < 4; ++i) {
    float4 o;
    o.x = acc[i][0]+bb.x; o.y = acc[i][1]+bb.y; o.z = acc[i][2]+bb.z; o.w = acc[i][3]+bb.w;
    *(float4*)(C + (size_t)(by*64+ty*4+i)*Nc + bx*64 + tx*4) = o;
  }
}

// ---------------- LDS layout (floats) for the persistent DNC kernel
#define SM_L    0                     // link   128*129 = 16512
#define SM_M    (SM_L + 128*LST)      // M      128*65  = 8320
#define SM_Z    (SM_M + 128*MST)      // z      2048
#define SM_H    (SM_Z + 2048)         // h      512
#define SM_C    (SM_H + 512)          // c      512
#define SM_RD   (SM_C + 512)          // reads  256
#define SM_V    (SM_RD + 256)         // v      472
#define SM_WR   (SM_V + 472)          // wr     512
#define SM_FW   (SM_WR + 512)         // fw     512
#define SM_BW   (SM_FW + 512)         // bw     512
#define SM_CR   (SM_BW + 512)         // cr     512 (sims then weights)
#define SM_USG  (SM_CR + 512)         // usage  128
#define SM_PRC  (SM_USG + 128)        // prec   128
#define SM_WW   (SM_PRC + 128)        // ww     128
#define SM_SU   (SM_WW + 128)         // sorted usage 128
#define SM_CPX  (SM_SU + 128)         // excl cumprod 128
#define SM_MN   (SM_CPX + 128)        // M row norms 128
#define SM_SW   (SM_MN + 128)         // write sim 128
#define SM_CW   (SM_SW + 128)         // write content wt 128
#define SM_RNK  (SM_CW + 128)         // rank (int) 128
#define SM_MSC  (SM_RNK + 128)        // scalars 64: [0]=sum_ww,[1..4]=knorm,[8..19]=modes
#define SM_TOT  (SM_MSC + 64)         // = 31896 floats = 127584 B

__global__ __launch_bounds__(1024) void dnc_main(
    const float* __restrict__ Xproj,   // [B*T, 2048] = x@Wx[:512] + b_lstm
    const float* __restrict__ WxR,     // Wx rows 512..767  [256,2048]
    const float* __restrict__ Wh,      // [512,2048]
    const float* __restrict__ Wif,     // [512,471]
    const float* __restrict__ bif,     // [471]
    float* __restrict__ Hist)          // [B*T, 768]: [0:256)=reads_n [256:768)=h_n
{
  const int b = blockIdx.x;
  const int tid = threadIdx.x;
  extern __shared__ float sm[];
  float* L   = sm + SM_L;
  float* Ms  = sm + SM_M;
  float* z   = sm + SM_Z;
  float* h   = sm + SM_H;
  float* c   = sm + SM_C;
  float* rd  = sm + SM_RD;
  float* v   = sm + SM_V;
  float* wr  = sm + SM_WR;
  float* fw  = sm + SM_FW;
  float* bw  = sm + SM_BW;
  float* cr  = sm + SM_CR;
  float* usg = sm + SM_USG;
  float* prc = sm + SM_PRC;
  float* ww  = sm + SM_WW;
  float* su  = sm + SM_SU;
  float* cpx = sm + SM_CPX;
  float* Mn  = sm + SM_MN;
  float* swv = sm + SM_SW;
  float* cw  = sm + SM_CW;
  int*   rnk = (int*)(sm + SM_RNK);
  float* msc = sm + SM_MSC;

  for (int i = tid; i < SM_TOT; i += 1024) sm[i] = 0.f;
  __syncthreads();

  const float* xp = Xproj + (size_t)b * TT * ZD;
  float* hist = Hist + (size_t)b * TT * 768;

  for (int t = 0; t < TT; ++t) {
    // ---- P1: z = Xproj[t] + reads@WxR + h@Wh  (1024 thr x 2 cols)
    {
      const int c0 = tid * 2;
      const float2 xv = *(const float2*)(xp + (size_t)t*ZD + c0);
      float ax = xv.x, ay = xv.y;
      const float* wp = WxR + c0;
#pragma unroll 4
      for (int k = 0; k < 256; k += 4) {
        float4 h4 = *(const float4*)(rd + k);
        float2 w0 = *(const float2*)(wp);            float2 w1 = *(const float2*)(wp + ZD);
        float2 w2 = *(const float2*)(wp + 2*ZD);     float2 w3 = *(const float2*)(wp + 3*ZD);
        wp += 4*ZD;
        ax += h4.x*w0.x; ay += h4.x*w0.y;
        ax += h4.y*w1.x; ay += h4.y*w1.y;
        ax += h4.z*w2.x; ay += h4.z*w2.y;
        ax += h4.w*w3.x; ay += h4.w*w3.y;
      }
      const float* wp2 = Wh + c0;
#pragma unroll 4
      for (int k = 0; k < 512; k += 4) {
        float4 h4 = *(const float4*)(h + k);
        float2 w0 = *(const float2*)(wp2);           float2 w1 = *(const float2*)(wp2 + ZD);
        float2 w2 = *(const float2*)(wp2 + 2*ZD);    float2 w3 = *(const float2*)(wp2 + 3*ZD);
        wp2 += 4*ZD;
        ax += h4.x*w0.x; ay += h4.x*w0.y;
        ax += h4.y*w1.x; ay += h4.y*w1.y;
        ax += h4.z*w2.x; ay += h4.z*w2.y;
        ax += h4.w*w3.x; ay += h4.w*w3.y;
      }
      z[c0] = ax; z[c0+1] = ay;
    }
    __syncthreads();
    // ---- P2: LSTM gates -> h_n, c_n ; stash h_n for deferred output GEMM
    if (tid < 512) {
      float ig = sig_(z[tid]);
      float fg = sig_(z[tid+512]);
      float gg = tanhf(z[tid+1024]);
      float og = sig_(z[tid+1536]);
      float cn = fg*c[tid] + ig*gg;
      float hn = og*tanhf(cn);
      c[tid] = cn; h[tid] = hn;
      hist[(size_t)t*768 + 256 + tid] = hn;
    }
    __syncthreads();
    // ---- P3: v = h_n@W_iface + b ; old-M row norms
    if (tid < IFC) {
      float a = bif[tid];
      const float* wp = Wif + tid;
#pragma unroll 4
      for (int k = 0; k < 512; k += 4) {
        float4 h4 = *(const float4*)(h + k);
        a += h4.x*wp[0] + h4.y*wp[IFC] + h4.z*wp[2*IFC] + h4.w*wp[3*IFC];
        wp += 4*IFC;
      }
      v[tid] = a;
    } else if (tid >= 512 && tid < 640) {
      int n = tid - 512;
      float s = 0.f;
#pragma unroll 8
      for (int w = 0; w < 64; ++w) { float m = Ms[n*MST+w]; s += m*m; }
      Mn[n] = sqrtf(s);
    }
    __syncthreads();
    // ---- P4: usage update (old ww, old wr) ; write sim (old M) ; key norms ; modes
    if (tid < 128) {
      float ret = 1.f;
#pragma unroll
      for (int r = 0; r < 4; ++r) { float fr = sig_(v[453+r]); ret *= 1.f - fr*wr[r*128+tid]; }
      float u = usg[tid], w_ = ww[tid];
      usg[tid] = (u + w_ - u*w_) * ret;
    } else if (tid < 256) {
      int n = tid - 128;
      float nk = 0.f, dot = 0.f;
#pragma unroll 8
      for (int w = 0; w < 64; ++w) { float kv = v[260+w]; nk += kv*kv; dot += Ms[n*MST+w]*kv; }
      nk = sqrtf(nk);
      float beta = 1.f + sp_(v[324]);
      swv[n] = beta * dot / ((Mn[n]+EPSF)*(nk+EPSF));
    } else if (tid < 260) {
      int r = tid - 256; float s = 0.f;
      for (int w = 0; w < 64; ++w) { float kv = v[r*64+w]; s += kv*kv; }
      msc[1+r] = sqrtf(s);
    } else if (tid == 260) {
      for (int r = 0; r < 4; ++r) {
        float a0 = v[459+r*3], a1 = v[459+r*3+1], a2 = v[459+r*3+2];
        float mx = fmaxf(a0, fmaxf(a1, a2));
        float e0 = expf(a0-mx), e1 = expf(a1-mx), e2 = expf(a2-mx);
        float dn = e0+e1+e2;
        msc[8+r*3] = e0/dn; msc[8+r*3+1] = e1/dn; msc[8+r*3+2] = e2/dn;
      }
    }
    __syncthreads();
    // ---- P5: stable-ascending rank + scatter sorted usage ; write softmax (wave 2)
    if (tid < 128) {
      float ui = usg[tid]; int rk = 0;
      for (int j = 0; j < 128; ++j) {
        float uj = usg[j];
        rk += (uj < ui || (uj == ui && j < tid)) ? 1 : 0;
      }
      rnk[tid] = rk;
      su[rk] = ui;
    } else if (tid < 192) {
      int l = tid - 128;
      float s1 = swv[l], s2 = swv[l+64];
      float m = fmaxf(s1, s2);
#pragma unroll
      for (int o = 32; o > 0; o >>= 1) m = fmaxf(m, __shfl_xor(m, o, 64));
      float e1 = expf(s1-m), e2 = expf(s2-m);
      float dn = e1 + e2;
#pragma unroll
      for (int o = 32; o > 0; o >>= 1) dn += __shfl_xor(dn, o, 64);
      cw[l] = e1/dn; cw[l+64] = e2/dn;
    }
    __syncthreads();
    // ---- P6: exclusive cumprod of sorted usage (serial, thread 0)
    if (tid == 0) {
      float p = 1.f;
      for (int i = 0; i < 128; ++i) { cpx[i] = p; p *= su[i]; }
    }
    __syncthreads();
    // ---- P7: ww_n = wg*(ag*a + (1-ag)*cw)
    if (tid < 128) {
      float a_i = (1.f - usg[tid]) * cpx[rnk[tid]];
      float ag = sig_(v[457]), wg = sig_(v[458]);
      ww[tid] = wg * (ag*a_i + (1.f-ag)*cw[tid]);
    }
    __syncthreads();
    // ---- P8: M update (erase/write) ; link update (uses OLD prec)
    {
      int n = tid >> 3, w0 = (tid & 7) * 8;
      float wwn = ww[n];
#pragma unroll
      for (int q = 0; q < 8; ++q) {
        int w = w0 + q;
        float er = sig_(v[325+w]);
        float wv = v[389+w];
        float m = Ms[n*MST+w];
        Ms[n*MST+w] = m*(1.f - wwn*er) + wwn*wv;
      }
#pragma unroll
      for (int q = 0; q < 16; ++q) {
        int e = tid*16 + q; int i2 = e >> 7, j2 = e & 127;
        float lv = L[i2*LST+j2];
        lv = (1.f - ww[i2] - ww[j2])*lv + ww[i2]*prc[j2];
        L[i2*LST+j2] = (i2 == j2) ? 0.f : lv;
      }
    }
    __syncthreads();
    // ---- P9: sum(ww) (wave 0) ; NEW M row norms
    if (tid < 64) {
      float s = ww[tid] + ww[tid+64];
#pragma unroll
      for (int o = 32; o > 0; o >>= 1) s += __shfl_xor(s, o, 64);
      if (tid == 0) msc[0] = s;
    } else if (tid < 192) {
      int n = tid - 64;
      float s = 0.f;
#pragma unroll 8
      for (int w = 0; w < 64; ++w) { float m = Ms[n*MST+w]; s += m*m; }
      Mn[n] = sqrtf(s);
    }
    __syncthreads();
    // ---- P10: fw/bw = link_n · wr_prev (all 1024 threads)
    {
      int dir = tid >> 9, r = (tid >> 7) & 3, i2 = tid & 127;
      const float* wrr = wr + r*128;
      float s = 0.f;
      if (dir == 0) {
#pragma unroll 4
        for (int j = 0; j < 128; ++j) s += L[i2*LST+j] * wrr[j];
        fw[r*128+i2] = s;
      } else {
#pragma unroll 4
        for (int j = 0; j < 128; ++j) s += L[j*LST+i2] * wrr[j];
        bw[r*128+i2] = s;
      }
    }
    __syncthreads();
    // ---- P11: prec update ; read sims vs NEW M
    if (tid < 128) {
      prc[tid] = (1.f - msc[0])*prc[tid] + ww[tid];
    } else if (tid >= 512) {
      int r = (tid >> 7) & 3, n = tid & 127;
      float dot = 0.f;
#pragma unroll 8
      for (int w = 0; w < 64; ++w) dot += Ms[n*MST+w] * v[r*64+w];
      float beta = 1.f + sp_(v[256+r]);
      cr[r*128+n] = beta * dot / ((Mn[n]+EPSF)*(msc[1+r]+EPSF));
    }
    __syncthreads();
    // ---- P12: per-head read softmax (waves 0..3, in-place in cr)
    if (tid < 256) {
      int r = tid >> 6, l = tid & 63;
      float s1 = cr[r*128+l], s2 = cr[r*128+l+64];
      float m = fmaxf(s1, s2);
#pragma unroll
      for (int o = 32; o > 0; o >>= 1) m = fmaxf(m, __shfl_xor(m, o, 64));
      float e1 = expf(s1-m), e2 = expf(s2-m);
      float dn = e1 + e2;
#pragma unroll
      for (int o = 32; o > 0; o >>= 1) dn += __shfl_xor(dn, o, 64);
      cr[r*128+l] = e1/dn; cr[r*128+l+64] = e2/dn;
    }
    __syncthreads();
    // ---- P13: wr_n = m0*bw + m1*cr + m2*fw
    if (tid < 512) {
      int r = tid >> 7, n = tid & 127;
      wr[tid] = msc[8+r*3]*bw[tid] + msc[8+r*3+1]*cr[tid] + msc[8+r*3+2]*fw[tid];
    }
    __syncthreads();
    // ---- P14: reads_n = wr_n @ M_n ; stash for output GEMM
    if (tid < 256) {
      int r = tid >> 6, w = tid & 63;
      const float* wrr = wr + r*128;
      float s = 0.f;
#pragma unroll 4
      for (int n = 0; n < 128; ++n) s += wrr[n] * Ms[n*MST+w];
      rd[tid] = s;
      hist[(size_t)t*768 + tid] = s;
    }
    __syncthreads();
  }
}

extern "C" void kernel_launch(void* const* d_in, const int* in_sizes, int n_in,
                              void* d_out, int out_size, void* d_ws, size_t ws_size,
                              hipStream_t stream) {
  const float* x   = (const float*)d_in[0];   // [32,128,512]
  const float* Wx  = (const float*)d_in[1];   // [768,2048]
  const float* Wh  = (const float*)d_in[2];   // [512,2048]
  const float* bl  = (const float*)d_in[3];   // [2048]
  const float* Wif = (const float*)d_in[4];   // [512,471]
  const float* bif = (const float*)d_in[5];   // [471]
  const float* Wo  = (const float*)d_in[6];   // [768,512]
  const float* bo  = (const float*)d_in[7];   // [512]
  float* out = (float*)d_out;                 // [32,128,512]

  float* Xproj = (float*)d_ws;                         // 4096*2048 floats (33.5 MB)
  float* Hist  = Xproj + (size_t)4096*2048;            // 4096*768 floats (12.6 MB)
  // ws needed: 46.2 MB

  // 1) Precompute x@Wx[:512] + b_lstm  (no recurrent dependency)
  gemm_bias<<<dim3(2048/64, 4096/64), dim3(256), 0, stream>>>(x, Wx, bl, Xproj, 4096, 2048, 512);

  // 2) Persistent recurrent core: one block per example, state in LDS
  const int smem_bytes = SM_TOT * 4;  // 127584
  hipFuncSetAttribute((const void*)dnc_main, hipFuncAttributeMaxDynamicSharedMemorySize, smem_bytes);
  dnc_main<<<dim3(32), dim3(1024), smem_bytes, stream>>>(Xproj, Wx + (size_t)512*ZD, Wh, Wif, bif, Hist);

  // 3) Deferred output projection: [reads_n, h_n] @ W_out + b_out
  gemm_bias<<<dim3(512/64, 4096/64), dim3(256), 0, stream>>>(Hist, Wo, bo, out, 4096, 512, 768);
}

// Round 2
// 18819.240 us; speedup vs baseline: 1.1823x; 1.1823x over previous
//
#include <hip/hip_runtime.h>
#include <math.h>

#define TT 128
#define ZD 2048
#define IFC 471
#define EPSF 1e-6f
#define MST 68      // M LDS row stride (floats, mult of 4, %32==4)
#define LST 132     // link LDS row stride
#define VST 480     // v_buf global stride
#define UST 768     // u_buf global stride
#define USS 260     // staged-u LDS row stride
#define WSS 772     // z weight slice LDS row stride ([16][772])
#define WIS 516     // iface weight slice LDS row stride ([8][516])

#define D4(a,b) ((a).x*(b).x + (a).y*(b).y + (a).z*(b).z + (a).w*(b).w)

__device__ __forceinline__ float sig_(float x){ return 1.f/(1.f+expf(-x)); }
__device__ __forceinline__ float sp_(float x){ return fmaxf(x,0.f)+log1pf(expf(-fabsf(x))); }

// ---------------- generic tiled GEMM: C[M,N] = A[M,K] @ B[K,N] + bias[N]
__global__ __launch_bounds__(256) void gemm_bias(
    const float* __restrict__ A, const float* __restrict__ B,
    const float* __restrict__ bias, float* __restrict__ C,
    int Mr, int Nc, int K)
{
  __shared__ float As[16][68];
  __shared__ float Bs[16][68];
  const int tid = threadIdx.x;
  const int bx = blockIdx.x, by = blockIdx.y;
  const int tx = tid & 15, ty = tid >> 4;
  const int am = tid >> 2, ak = (tid & 3) * 4;
  const int bk = tid >> 4, bn = (tid & 15) * 4;
  float acc[4][4] = {};
  const float* Ap = A + (size_t)(by*64+am)*K + ak;
  const float* Bp = B + (size_t)bk*Nc + bx*64 + bn;
  for (int k0 = 0; k0 < K; k0 += 16) {
    float4 av = *(const float4*)Ap; Ap += 16;
    float4 bv = *(const float4*)Bp; Bp += (size_t)16*Nc;
    As[ak+0][am]=av.x; As[ak+1][am]=av.y; As[ak+2][am]=av.z; As[ak+3][am]=av.w;
    *(float4*)&Bs[bk][bn] = bv;
    __syncthreads();
#pragma unroll
    for (int kk = 0; kk < 16; ++kk) {
      float4 a4 = *(const float4*)&As[kk][ty*4];
      float4 b4 = *(const float4*)&Bs[kk][tx*4];
      acc[0][0]+=a4.x*b4.x; acc[0][1]+=a4.x*b4.y; acc[0][2]+=a4.x*b4.z; acc[0][3]+=a4.x*b4.w;
      acc[1][0]+=a4.y*b4.x; acc[1][1]+=a4.y*b4.y; acc[1][2]+=a4.y*b4.z; acc[1][3]+=a4.y*b4.w;
      acc[2][0]+=a4.z*b4.x; acc[2][1]+=a4.z*b4.y; acc[2][2]+=a4.z*b4.z; acc[2][3]+=a4.z*b4.w;
      acc[3][0]+=a4.w*b4.x; acc[3][1]+=a4.w*b4.y; acc[3][2]+=a4.w*b4.z; acc[3][3]+=a4.w*b4.w;
    }
    __syncthreads();
  }
  float4 bb = *(const float4*)(bias + bx*64 + tx*4);
#pragma unroll
  for (int i = 0; i < 4; ++i) {
    float4 o;
    o.x = acc[i][0]+bb.x; o.y = acc[i][1]+bb.y; o.z = acc[i][2]+bb.z; o.w = acc[i][3]+bb.w;
    *(float4*)(C + (size_t)(by*64+ty*4+i)*Nc + bx*64 + tx*4) = o;
  }
}

// ---------------- state-block LDS layout (floats)
#define SL_L    0
#define SL_M    16896
#define SL_H    25600
#define SL_C    26112
#define SL_RD   26624
#define SL_V    26880
#define SL_WR   27360
#define SL_FW   27872
#define SL_BW   28384
#define SL_CR   28896
#define SL_USG  29408
#define SL_PRC  29536
#define SL_WW   29664
#define SL_SU   29792
#define SL_CPX  29920
#define SL_MN   30048
#define SL_SW   30176
#define SL_CW   30304
#define SL_RNK  30432
#define SL_MSC  30560
#define SL_ER   30624
#define SL_WV   30688
#define SL_TOT  30752   // 123008 bytes

// z-block LDS: Ws[16][772]=12352 | us[32][260]=8320 | zh[512]
#define GZ_W 0
#define GZ_U 12352
#define GZ_ZH 20672
// iface LDS: Wi[8][516]=4128 | us[32][260]
#define GI_W 0
#define GI_U 4128

// all-report / all-check device barrier (256 blocks)
__device__ __forceinline__ void gbar(unsigned* flags, unsigned gen) {
  __syncthreads();
  if (threadIdx.x == 0)
    __hip_atomic_store(&flags[blockIdx.x], gen, __ATOMIC_RELEASE, __HIP_MEMORY_SCOPE_AGENT);
  if (threadIdx.x < 256) {
    while (__hip_atomic_load(&flags[threadIdx.x], __ATOMIC_RELAXED, __HIP_MEMORY_SCOPE_AGENT) < gen) {
      __builtin_amdgcn_s_sleep(1);
    }
    __threadfence();  // acquire: invalidate caches once after all flags seen
  }
  __syncthreads();
}

__device__ __forceinline__ void stage_u(float* us, const float* u_buf, int cbase) {
  const int tid = threadIdx.x;
#pragma unroll
  for (int i = 0; i < 2; ++i) {
    int idx = tid + i*1024;            // 2048 float4 slots = 32x256 floats
    int e = idx >> 6, q = (idx & 63) * 4;
    *(float4*)&us[e*USS + q] = *(const float4*)&u_buf[e*UST + cbase + q];
  }
}

__device__ __forceinline__ void zgemm_chunk(const float* Ws, const float* us, int kbase, float acc[4][4]) {
  const int tid = threadIdx.x;
  const int tile = tid >> 5, s = tid & 31;
  const int e0 = (tile >> 2) * 4, jj = (tile & 3) * 4;
#pragma unroll
  for (int g = 0; g < 2; ++g) {
    int kk = g*128 + s*4;
    float4 u0 = *(const float4*)&us[(e0+0)*USS + kk];
    float4 u1 = *(const float4*)&us[(e0+1)*USS + kk];
    float4 u2 = *(const float4*)&us[(e0+2)*USS + kk];
    float4 u3 = *(const float4*)&us[(e0+3)*USS + kk];
    float4 w0 = *(const float4*)&Ws[(jj+0)*WSS + kbase + kk];
    float4 w1 = *(const float4*)&Ws[(jj+1)*WSS + kbase + kk];
    float4 w2 = *(const float4*)&Ws[(jj+2)*WSS + kbase + kk];
    float4 w3 = *(const float4*)&Ws[(jj+3)*WSS + kbase + kk];
    acc[0][0]+=D4(u0,w0); acc[0][1]+=D4(u0,w1); acc[0][2]+=D4(u0,w2); acc[0][3]+=D4(u0,w3);
    acc[1][0]+=D4(u1,w0); acc[1][1]+=D4(u1,w1); acc[1][2]+=D4(u1,w2); acc[1][3]+=D4(u1,w3);
    acc[2][0]+=D4(u2,w0); acc[2][1]+=D4(u2,w1); acc[2][2]+=D4(u2,w2); acc[2][3]+=D4(u2,w3);
    acc[3][0]+=D4(u3,w0); acc[3][1]+=D4(u3,w1); acc[3][2]+=D4(u3,w2); acc[3][3]+=D4(u3,w3);
  }
}

__device__ __forceinline__ void zreduce(float acc[4][4]) {
#pragma unroll
  for (int i = 0; i < 4; ++i)
#pragma unroll
    for (int j = 0; j < 4; ++j) {
      float a = acc[i][j];
      a += __shfl_xor(a, 1); a += __shfl_xor(a, 2); a += __shfl_xor(a, 4);
      a += __shfl_xor(a, 8); a += __shfl_xor(a, 16);
      acc[i][j] = a;
    }
}

__global__ void init_flags(unsigned* flags) {
  if (threadIdx.x < 256) flags[threadIdx.x] = 0u;
}

__global__ __launch_bounds__(1024) void dnc_coop(
    const float* __restrict__ Xproj, const float* __restrict__ Wx,
    const float* __restrict__ Wh, const float* __restrict__ Wif,
    const float* __restrict__ bif, float* __restrict__ Hist,
    float* __restrict__ z_buf, float* __restrict__ v_buf,
    float* __restrict__ u_buf, unsigned* __restrict__ flags)
{
  const int blk = blockIdx.x, tid = threadIdx.x;
  extern __shared__ float sm[];
  unsigned gen = 0;

  if (blk < 32) {
    // ================= STATE BLOCK (one example) =================
    const int e = blk;
    float* L   = sm + SL_L;   float* Ms  = sm + SL_M;
    float* h   = sm + SL_H;   float* c   = sm + SL_C;
    float* rd  = sm + SL_RD;  float* v   = sm + SL_V;
    float* wr  = sm + SL_WR;  float* fw  = sm + SL_FW;
    float* bw  = sm + SL_BW;  float* cr  = sm + SL_CR;
    float* usg = sm + SL_USG; float* prc = sm + SL_PRC;
    float* ww  = sm + SL_WW;  float* su  = sm + SL_SU;
    float* cpx = sm + SL_CPX; float* Mn  = sm + SL_MN;
    float* swv = sm + SL_SW;  float* cw  = sm + SL_CW;
    int*   rnk = (int*)(sm + SL_RNK);
    float* msc = sm + SL_MSC; float* er_ = sm + SL_ER; float* wv_ = sm + SL_WV;
    float* hist = Hist + (size_t)e * TT * 768;

    for (int i = tid; i < SL_TOT; i += 1024) sm[i] = 0.f;
    gbar(flags, ++gen);

    for (int t = 0; t < TT; ++t) {
      // ---- S1: LSTM gates
      if (tid < 512) {
        const float* zr = z_buf + e*ZD;
        float ig = sig_(zr[tid]);
        float fg = sig_(zr[tid+512]);
        float gg = tanhf(zr[tid+1024]);
        float og = sig_(zr[tid+1536]);
        float cn = fg*c[tid] + ig*gg;
        float hn = og*tanhf(cn);
        c[tid] = cn; h[tid] = hn;
        u_buf[e*UST + 256 + tid] = hn;
        hist[t*768 + 256 + tid] = hn;
      }
      gbar(flags, ++gen);   // bar_a (h published)
      gbar(flags, ++gen);   // bar_b (v ready)

      // ---- S2: DNC memory ops
      // A: v copy + old-M row norms
      if (tid < IFC) v[tid] = v_buf[e*VST + tid];
      else if (tid >= 512 && tid < 640) {
        int n = tid - 512; float s = 0.f;
#pragma unroll
        for (int w = 0; w < 64; w += 4) { float4 m = *(float4*)&Ms[n*MST+w]; s += D4(m,m); }
        Mn[n] = sqrtf(s);
      }
      __syncthreads();
      // B: usage update / write sim / key norms / modes / erase-write prep
      if (tid < 128) {
        float ret = 1.f;
#pragma unroll
        for (int r = 0; r < 4; ++r) { float fr = sig_(v[453+r]); ret *= 1.f - fr*wr[r*128+tid]; }
        float u = usg[tid], w_ = ww[tid];
        usg[tid] = (u + w_ - u*w_) * ret;
      } else if (tid < 256) {
        int n = tid - 128; float nk = 0.f, dot = 0.f;
#pragma unroll
        for (int w = 0; w < 64; w += 4) {
          float4 k4 = *(float4*)&v[260+w];
          float4 m4 = *(float4*)&Ms[n*MST+w];
          nk += D4(k4,k4); dot += D4(m4,k4);
        }
        float beta = 1.f + sp_(v[324]);
        swv[n] = beta * dot / ((Mn[n]+EPSF)*(sqrtf(nk)+EPSF));
      } else if (tid < 260) {
        int r = tid - 256; float s = 0.f;
#pragma unroll
        for (int w = 0; w < 64; w += 4) { float4 k4 = *(float4*)&v[r*64+w]; s += D4(k4,k4); }
        msc[1+r] = sqrtf(s);
      } else if (tid == 260) {
        for (int r = 0; r < 4; ++r) {
          float a0 = v[459+r*3], a1 = v[459+r*3+1], a2 = v[459+r*3+2];
          float mx = fmaxf(a0, fmaxf(a1, a2));
          float e0 = expf(a0-mx), e1 = expf(a1-mx), e2 = expf(a2-mx);
          float dn = e0+e1+e2;
          msc[8+r*3] = e0/dn; msc[8+r*3+1] = e1/dn; msc[8+r*3+2] = e2/dn;
        }
      } else if (tid >= 640 && tid < 704) { int w = tid-640; er_[w] = sig_(v[325+w]); }
      else if (tid >= 704 && tid < 768) { int w = tid-704; wv_[w] = v[389+w]; }
      __syncthreads();
      // C: stable-ascending rank + write softmax
      if (tid < 128) {
        float ui = usg[tid]; int rk = 0;
        for (int j = 0; j < 128; ++j) {
          float uj = usg[j];
          rk += (uj < ui || (uj == ui && j < tid)) ? 1 : 0;
        }
        rnk[tid] = rk; su[rk] = ui;
      } else if (tid < 192) {
        int l = tid - 128;
        float s1 = swv[l], s2 = swv[l+64];
        float m = fmaxf(s1, s2);
#pragma unroll
        for (int o = 32; o > 0; o >>= 1) m = fmaxf(m, __shfl_xor(m, o));
        float e1 = expf(s1-m), e2 = expf(s2-m);
        float dn = e1 + e2;
#pragma unroll
        for (int o = 32; o > 0; o >>= 1) dn += __shfl_xor(dn, o);
        cw[l] = e1/dn; cw[l+64] = e2/dn;
      }
      __syncthreads();
      // D: exclusive cumprod via wave scan
      if (tid < 64) {
        float a0 = su[2*tid], a1 = su[2*tid+1];
        float p = a0*a1, sc = p;
#pragma unroll
        for (int off = 1; off < 64; off <<= 1) {
          float o = __shfl_up(sc, off);
          if ((int)tid >= off) sc *= o;
        }
        float ex = __shfl_up(sc, 1);
        if (tid == 0) ex = 1.f;
        cpx[2*tid] = ex;
        cpx[2*tid+1] = ex*a0;
      }
      __syncthreads();
      // E: ww_n
      if (tid < 128) {
        float a_i = (1.f - usg[tid]) * cpx[rnk[tid]];
        float ag = sig_(v[457]), wg = sig_(v[458]);
        ww[tid] = wg * (ag*a_i + (1.f-ag)*cw[tid]);
      }
      __syncthreads();
      // F: M erase/write + link update (old prec)
      {
        int n = tid >> 3, q = tid & 7;
        float wwn = ww[n];
        int w8 = q*8;
#pragma unroll
        for (int g = 0; g < 2; ++g) {
          int w = w8 + g*4;
          float4 m = *(float4*)&Ms[n*MST+w];
          float4 e4 = *(float4*)&er_[w];
          float4 v4 = *(float4*)&wv_[w];
          m.x = m.x*(1.f - wwn*e4.x) + wwn*v4.x;
          m.y = m.y*(1.f - wwn*e4.y) + wwn*v4.y;
          m.z = m.z*(1.f - wwn*e4.z) + wwn*v4.z;
          m.w = m.w*(1.f - wwn*e4.w) + wwn*v4.w;
          *(float4*)&Ms[n*MST+w] = m;
        }
        int j16 = q*16;
        float wwi = wwn;
#pragma unroll
        for (int g = 0; g < 4; ++g) {
          int j = j16 + g*4;
          float4 lv = *(float4*)&L[n*LST + j];
          float4 p4 = *(float4*)&prc[j];
          float4 w4 = *(float4*)&ww[j];
          lv.x = (1.f - wwi - w4.x)*lv.x + wwi*p4.x;
          lv.y = (1.f - wwi - w4.y)*lv.y + wwi*p4.y;
          lv.z = (1.f - wwi - w4.z)*lv.z + wwi*p4.z;
          lv.w = (1.f - wwi - w4.w)*lv.w + wwi*p4.w;
          int d = n - j;
          if (d >= 0 && d < 4) ((float*)&lv)[d] = 0.f;
          *(float4*)&L[n*LST + j] = lv;
        }
      }
      __syncthreads();
      // G: sum(ww) + new M norms
      if (tid < 64) {
        float s = ww[tid] + ww[tid+64];
#pragma unroll
        for (int o = 32; o > 0; o >>= 1) s += __shfl_xor(s, o);
        if (tid == 0) msc[0] = s;
      } else if (tid < 192) {
        int n = tid - 64; float s = 0.f;
#pragma unroll
        for (int w = 0; w < 64; w += 4) { float4 m = *(float4*)&Ms[n*MST+w]; s += D4(m,m); }
        Mn[n] = sqrtf(s);
      }
      __syncthreads();
      // H: fw/bw = link_n · wr_prev  (tiled 4r x 4i, 4-way j-split, shfl reduce)
      if (tid < 256) {
        int half = tid >> 7, t2 = tid & 127;
        int i0 = (t2 >> 2) * 4, sg = t2 & 3;
        float4 av[4] = {{0,0,0,0},{0,0,0,0},{0,0,0,0},{0,0,0,0}};
        if (half == 0) {
#pragma unroll
          for (int m = 0; m < 8; ++m) {
            int j = sg*4 + m*16;
            float4 w0 = *(float4*)&wr[0*128+j];
            float4 w1 = *(float4*)&wr[1*128+j];
            float4 w2 = *(float4*)&wr[2*128+j];
            float4 w3 = *(float4*)&wr[3*128+j];
            float4 l0 = *(float4*)&L[(i0+0)*LST+j];
            float4 l1 = *(float4*)&L[(i0+1)*LST+j];
            float4 l2 = *(float4*)&L[(i0+2)*LST+j];
            float4 l3 = *(float4*)&L[(i0+3)*LST+j];
            av[0].x+=D4(l0,w0); av[0].y+=D4(l1,w0); av[0].z+=D4(l2,w0); av[0].w+=D4(l3,w0);
            av[1].x+=D4(l0,w1); av[1].y+=D4(l1,w1); av[1].z+=D4(l2,w1); av[1].w+=D4(l3,w1);
            av[2].x+=D4(l0,w2); av[2].y+=D4(l1,w2); av[2].z+=D4(l2,w2); av[2].w+=D4(l3,w2);
            av[3].x+=D4(l0,w3); av[3].y+=D4(l1,w3); av[3].z+=D4(l2,w3); av[3].w+=D4(l3,w3);
          }
        } else {
#pragma unroll
          for (int m = 0; m < 32; ++m) {
            int j = sg + m*4;
            float4 lv = *(float4*)&L[j*LST + i0];
            float w0 = wr[j], w1 = wr[128+j], w2 = wr[256+j], w3 = wr[384+j];
            av[0].x+=w0*lv.x; av[0].y+=w0*lv.y; av[0].z+=w0*lv.z; av[0].w+=w0*lv.w;
            av[1].x+=w1*lv.x; av[1].y+=w1*lv.y; av[1].z+=w1*lv.z; av[1].w+=w1*lv.w;
            av[2].x+=w2*lv.x; av[2].y+=w2*lv.y; av[2].z+=w2*lv.z; av[2].w+=w2*lv.w;
            av[3].x+=w3*lv.x; av[3].y+=w3*lv.y; av[3].z+=w3*lv.z; av[3].w+=w3*lv.w;
          }
        }
#pragma unroll
        for (int r = 0; r < 4; ++r) {
          av[r].x += __shfl_xor(av[r].x,1); av[r].x += __shfl_xor(av[r].x,2);
          av[r].y += __shfl_xor(av[r].y,1); av[r].y += __shfl_xor(av[r].y,2);
          av[r].z += __shfl_xor(av[r].z,1); av[r].z += __shfl_xor(av[r].z,2);
          av[r].w += __shfl_xor(av[r].w,1); av[r].w += __shfl_xor(av[r].w,2);
        }
        if (sg == 0) {
          float* dst = half ? bw : fw;
#pragma unroll
          for (int r = 0; r < 4; ++r) {
            dst[r*128 + i0+0] = av[r].x; dst[r*128 + i0+1] = av[r].y;
            dst[r*128 + i0+2] = av[r].z; dst[r*128 + i0+3] = av[r].w;
          }
        }
      }
      __syncthreads();
      // I: prec update + read sims (new M)
      if (tid < 128) {
        prc[tid] = (1.f - msc[0])*prc[tid] + ww[tid];
      } else if (tid >= 512) {
        int r = (tid >> 7) & 3, n = tid & 127;
        float dot = 0.f;
#pragma unroll
        for (int w = 0; w < 64; w += 4) {
          float4 m4 = *(float4*)&Ms[n*MST+w];
          float4 k4 = *(float4*)&v[r*64+w];
          dot += D4(m4,k4);
        }
        float beta = 1.f + sp_(v[256+r]);
        cr[r*128+n] = beta * dot / ((Mn[n]+EPSF)*(msc[1+r]+EPSF));
      }
      __syncthreads();
      // J: per-head read softmax
      if (tid < 256) {
        int r = tid >> 6, l = tid & 63;
        float s1 = cr[r*128+l], s2 = cr[r*128+l+64];
        float m = fmaxf(s1, s2);
#pragma unroll
        for (int o = 32; o > 0; o >>= 1) m = fmaxf(m, __shfl_xor(m, o));
        float e1 = expf(s1-m), e2 = expf(s2-m);
        float dn = e1 + e2;
#pragma unroll
        for (int o = 32; o > 0; o >>= 1) dn += __shfl_xor(dn, o);
        cr[r*128+l] = e1/dn; cr[r*128+l+64] = e2/dn;
      }
      __syncthreads();
      // K: wr_n
      if (tid < 512) {
        int r = tid >> 7;
        wr[tid] = msc[8+r*3]*bw[tid] + msc[8+r*3+1]*cr[tid] + msc[8+r*3+2]*fw[tid];
      }
      __syncthreads();
      // L: reads_n = wr_n @ M_n (tiled, 8-way n-split, shfl reduce) + publish
      if (tid < 512) {
        int r = tid >> 7, t2 = tid & 127;
        int w0 = (t2 >> 3) * 4, ns = t2 & 7;
        float4 a = {0,0,0,0};
#pragma unroll
        for (int m = 0; m < 16; ++m) {
          int n = ns + m*8;
          float4 mr = *(float4*)&Ms[n*MST + w0];
          float wv = wr[r*128 + n];
          a.x += wv*mr.x; a.y += wv*mr.y; a.z += wv*mr.z; a.w += wv*mr.w;
        }
        a.x += __shfl_xor(a.x,1); a.x += __shfl_xor(a.x,2); a.x += __shfl_xor(a.x,4);
        a.y += __shfl_xor(a.y,1); a.y += __shfl_xor(a.y,2); a.y += __shfl_xor(a.y,4);
        a.z += __shfl_xor(a.z,1); a.z += __shfl_xor(a.z,2); a.z += __shfl_xor(a.z,4);
        a.w += __shfl_xor(a.w,1); a.w += __shfl_xor(a.w,2); a.w += __shfl_xor(a.w,4);
        if (ns == 0) {
          int o = r*64 + w0;
          *(float4*)&rd[o] = a;
          *(float4*)&hist[t*768 + o] = a;
          *(float4*)&u_buf[e*UST + o] = a;
        }
      }
      gbar(flags, ++gen);   // bar_c (reads published)
      gbar(flags, ++gen);   // bar_d (z(t+1) ready)
    }
  } else if (blk < 160) {
    // ================= Z BLOCK (16 cols of [WxR;Wh]) =================
    const int j0z = (blk - 32) * 16;
    float* Ws = sm + GZ_W;
    float* us = sm + GZ_U;
    float* zh = sm + GZ_ZH;
    for (int i = tid; i < 16*768; i += 1024) {
      int k = i >> 4, j = i & 15;
      Ws[j*WSS + k] = (k < 256) ? Wx[(size_t)(512+k)*ZD + j0z + j]
                                : Wh[(size_t)(k-256)*ZD + j0z + j];
    }
    if (tid < 512) {
      int e2 = tid >> 4, j = tid & 15;
      z_buf[e2*ZD + j0z + j] = Xproj[(size_t)(e2*TT)*ZD + j0z + j];
    }
    gbar(flags, ++gen);

    for (int t = 0; t < TT; ++t) {
      gbar(flags, ++gen);   // bar_a: h(t) ready
      bool act = (t+1 < TT);
      if (act) {
        // G1: zh(t+1) = Xproj(t+1) + h(t) @ Wh-part
        if (tid < 512) {
          int e2 = tid >> 4, j = tid & 15;
          zh[tid] = Xproj[(size_t)(e2*TT + t+1)*ZD + j0z + j];
        }
        float acc[4][4] = {};
        stage_u(us, u_buf, 256); __syncthreads();
        zgemm_chunk(Ws, us, 256, acc); __syncthreads();
        stage_u(us, u_buf, 512); __syncthreads();
        zgemm_chunk(Ws, us, 512, acc);
        zreduce(acc);
        {
          int tile = tid >> 5, s = tid & 31;
          int e0 = (tile >> 2) * 4, jj = (tile & 3) * 4;
          if (s == 0) {
#pragma unroll
            for (int i = 0; i < 4; ++i)
#pragma unroll
              for (int j = 0; j < 4; ++j)
                zh[(e0+i)*16 + jj + j] += acc[i][j];
          }
        }
      }
      gbar(flags, ++gen);   // bar_b
      gbar(flags, ++gen);   // bar_c: reads(t) ready
      if (act) {
        // G2: z(t+1) = zh + reads(t) @ WxR-part
        float acc[4][4] = {};
        stage_u(us, u_buf, 0); __syncthreads();
        zgemm_chunk(Ws, us, 0, acc);
        zreduce(acc);
        {
          int tile = tid >> 5, s = tid & 31;
          int e0 = (tile >> 2) * 4, jj = (tile & 3) * 4;
          if (s == 0) {
#pragma unroll
            for (int i = 0; i < 4; ++i)
#pragma unroll
              for (int j = 0; j < 4; ++j)
                z_buf[(e0+i)*ZD + j0z + jj + j] = zh[(e0+i)*16 + jj + j] + acc[i][j];
          }
        }
      }
      gbar(flags, ++gen);   // bar_d
    }
  } else {
    // ================= IFACE BLOCK (5 cols of W_iface) =================
    const int j0i = (blk - 160) * 5;
    float* Wi = sm + GI_W;
    float* us = sm + GI_U;
    for (int i = tid; i < 8*512; i += 1024) {
      int k = i >> 3, j = i & 7;
      int col = j0i + j;
      Wi[j*WIS + k] = (j < 5 && col < IFC) ? Wif[(size_t)k*IFC + col] : 0.f;
    }
    gbar(flags, ++gen);

    for (int t = 0; t < TT; ++t) {
      gbar(flags, ++gen);   // bar_a: h(t) ready
      // G1: v(t) = h(t) @ Wif + bif
      float accI[5] = {0,0,0,0,0};
      stage_u(us, u_buf, 256); __syncthreads();
      if (tid < 512) {
        int e2 = tid >> 4, ks = tid & 15;
#pragma unroll
        for (int g = 0; g < 4; ++g) {
          int kk = g*64 + ks*4;
          float4 u4 = *(const float4*)&us[e2*USS + kk];
#pragma unroll
          for (int j = 0; j < 5; ++j) {
            float4 w4 = *(const float4*)&Wi[j*WIS + kk];
            accI[j] += D4(u4,w4);
          }
        }
      }
      __syncthreads();
      stage_u(us, u_buf, 512); __syncthreads();
      if (tid < 512) {
        int e2 = tid >> 4, ks = tid & 15;
#pragma unroll
        for (int g = 0; g < 4; ++g) {
          int kk = g*64 + ks*4;
          float4 u4 = *(const float4*)&us[e2*USS + kk];
#pragma unroll
          for (int j = 0; j < 5; ++j) {
            float4 w4 = *(const float4*)&Wi[j*WIS + 256 + kk];
            accI[j] += D4(u4,w4);
          }
        }
#pragma unroll
        for (int j = 0; j < 5; ++j) {
          float a = accI[j];
          a += __shfl_xor(a,1); a += __shfl_xor(a,2); a += __shfl_xor(a,4); a += __shfl_xor(a,8);
          accI[j] = a;
        }
        int ks2 = tid & 15;
        if (ks2 == 0) {
#pragma unroll
          for (int j = 0; j < 5; ++j) {
            int col = j0i + j;
            if (col < IFC) v_buf[e2*VST + col] = bif[col] + accI[j];
          }
        }
      }
      gbar(flags, ++gen);   // bar_b
      gbar(flags, ++gen);   // bar_c
      gbar(flags, ++gen);   // bar_d
    }
  }
}

extern "C" void kernel_launch(void* const* d_in, const int* in_sizes, int n_in,
                              void* d_out, int out_size, void* d_ws, size_t ws_size,
                              hipStream_t stream) {
  const float* x   = (const float*)d_in[0];   // [32,128,512]
  const float* Wx  = (const float*)d_in[1];   // [768,2048]
  const float* Wh  = (const float*)d_in[2];   // [512,2048]
  const float* bl  = (const float*)d_in[3];   // [2048]
  const float* Wif = (const float*)d_in[4];   // [512,471]
  const float* bif = (const float*)d_in[5];   // [471]
  const float* Wo  = (const float*)d_in[6];   // [768,512]
  const float* bo  = (const float*)d_in[7];   // [512]
  float* out = (float*)d_out;                 // [32,128,512]

  float* Xp   = (float*)d_ws;                          // 4096*2048
  float* Hist = Xp + (size_t)4096*2048;                // 4096*768
  float* zb   = Hist + (size_t)4096*768;               // 32*2048
  float* vb   = zb + 32*2048;                          // 32*480
  float* ub   = vb + 32*480;                           // 32*768
  unsigned* fl = (unsigned*)(ub + 32*768);             // 256
  // total ~46.6 MB

  // 1) Precompute x@Wx[:512] + b_lstm
  gemm_bias<<<dim3(2048/64, 4096/64), dim3(256), 0, stream>>>(x, Wx, bl, Xp, 4096, 2048, 512);

  // 2) barrier flags init
  init_flags<<<dim3(1), dim3(256), 0, stream>>>(fl);

  // 3) cooperative weight-stationary recurrent core
  const int smem_bytes = SL_TOT * 4;  // 123008
  static bool attr_set = false;
  hipFuncSetAttribute((const void*)dnc_coop, hipFuncAttributeMaxDynamicSharedMemorySize, smem_bytes);
  (void)attr_set;
  void* args[] = { (void*)&Xp, (void*)&Wx, (void*)&Wh, (void*)&Wif, (void*)&bif,
                   (void*)&Hist, (void*)&zb, (void*)&vb, (void*)&ub, (void*)&fl };
  hipLaunchCooperativeKernel((void*)dnc_coop, dim3(256), dim3(1024), args,
                             (unsigned int)smem_bytes, stream);

  // 4) Deferred output projection
  gemm_bias<<<dim3(512/64, 4096/64), dim3(256), 0, stream>>>(Hist, Wo, bo, out, 4096, 512, 768);
}

// Round 3
// 7763.184 us; speedup vs baseline: 2.8662x; 2.4242x over previous
//
#include <hip/hip_runtime.h>
#include <math.h>

#define TT 128
#define ZD 2048
#define IFC 471
#define EPSF 1e-6f
#define MST 68      // M LDS row stride
#define LST 132     // link LDS row stride
#define VST 480     // v_buf global stride
#define UST 768     // u_buf global stride
#define USS 260     // staged-u LDS row stride
#define WSS 772     // z weight slice LDS row stride
#define WIS 516     // iface weight slice LDS row stride
#define NBLK 160

#define D4(a,b) ((a).x*(b).x + (a).y*(b).y + (a).z*(b).z + (a).w*(b).w)

__device__ __forceinline__ float sig_(float x){ return 1.f/(1.f+expf(-x)); }
__device__ __forceinline__ float sp_(float x){ return fmaxf(x,0.f)+log1pf(expf(-fabsf(x))); }

// -------- coherent-point (agent-scope, cache-bypassing) data movement --------
__device__ __forceinline__ float ld1(const float* p){
  unsigned u = __hip_atomic_load((const unsigned*)p, __ATOMIC_RELAXED, __HIP_MEMORY_SCOPE_AGENT);
  float f; __builtin_memcpy(&f,&u,4); return f;
}
__device__ __forceinline__ void st1(float* p, float v){
  unsigned u; __builtin_memcpy(&u,&v,4);
  __hip_atomic_store((unsigned*)p, u, __ATOMIC_RELAXED, __HIP_MEMORY_SCOPE_AGENT);
}
__device__ __forceinline__ float2 ld2(const float* p){
  unsigned long long u = __hip_atomic_load((const unsigned long long*)p, __ATOMIC_RELAXED, __HIP_MEMORY_SCOPE_AGENT);
  float2 f; __builtin_memcpy(&f,&u,8); return f;
}
__device__ __forceinline__ void st2(float* p, float2 v){
  unsigned long long u; __builtin_memcpy(&u,&v,8);
  __hip_atomic_store((unsigned long long*)p, u, __ATOMIC_RELAXED, __HIP_MEMORY_SCOPE_AGENT);
}

// -------- fence-free all-report/all-check barrier: wave 0 polls, no threadfence
__device__ __forceinline__ void gbar(unsigned* flags, unsigned gen){
  __syncthreads();
  if (threadIdx.x == 0)
    __hip_atomic_store(&flags[blockIdx.x], gen, __ATOMIC_RELEASE, __HIP_MEMORY_SCOPE_AGENT);
  if (threadIdx.x < 64){
    for (int f = threadIdx.x; f < NBLK; f += 64){
      while (__hip_atomic_load(&flags[f], __ATOMIC_RELAXED, __HIP_MEMORY_SCOPE_AGENT) < gen)
        __builtin_amdgcn_s_sleep(2);
    }
  }
  __syncthreads();
}

// ---------------- generic tiled GEMM: C[M,N] = A[M,K] @ B[K,N] + bias[N]
__global__ __launch_bounds__(256) void gemm_bias(
    const float* __restrict__ A, const float* __restrict__ B,
    const float* __restrict__ bias, float* __restrict__ C,
    int Mr, int Nc, int K)
{
  __shared__ float As[16][68];
  __shared__ float Bs[16][68];
  const int tid = threadIdx.x;
  const int bx = blockIdx.x, by = blockIdx.y;
  const int tx = tid & 15, ty = tid >> 4;
  const int am = tid >> 2, ak = (tid & 3) * 4;
  const int bk = tid >> 4, bn = (tid & 15) * 4;
  float acc[4][4] = {};
  const float* Ap = A + (size_t)(by*64+am)*K + ak;
  const float* Bp = B + (size_t)bk*Nc + bx*64 + bn;
  for (int k0 = 0; k0 < K; k0 += 16) {
    float4 av = *(const float4*)Ap; Ap += 16;
    float4 bv = *(const float4*)Bp; Bp += (size_t)16*Nc;
    As[ak+0][am]=av.x; As[ak+1][am]=av.y; As[ak+2][am]=av.z; As[ak+3][am]=av.w;
    *(float4*)&Bs[bk][bn] = bv;
    __syncthreads();
#pragma unroll
    for (int kk = 0; kk < 16; ++kk) {
      float4 a4 = *(const float4*)&As[kk][ty*4];
      float4 b4 = *(const float4*)&Bs[kk][tx*4];
      acc[0][0]+=a4.x*b4.x; acc[0][1]+=a4.x*b4.y; acc[0][2]+=a4.x*b4.z; acc[0][3]+=a4.x*b4.w;
      acc[1][0]+=a4.y*b4.x; acc[1][1]+=a4.y*b4.y; acc[1][2]+=a4.y*b4.z; acc[1][3]+=a4.y*b4.w;
      acc[2][0]+=a4.z*b4.x; acc[2][1]+=a4.z*b4.y; acc[2][2]+=a4.z*b4.z; acc[2][3]+=a4.z*b4.w;
      acc[3][0]+=a4.w*b4.x; acc[3][1]+=a4.w*b4.y; acc[3][2]+=a4.w*b4.z; acc[3][3]+=a4.w*b4.w;
    }
    __syncthreads();
  }
  float4 bb = *(const float4*)(bias + bx*64 + tx*4);
#pragma unroll
  for (int i = 0; i < 4; ++i) {
    float4 o;
    o.x = acc[i][0]+bb.x; o.y = acc[i][1]+bb.y; o.z = acc[i][2]+bb.z; o.w = acc[i][3]+bb.w;
    *(float4*)(C + (size_t)(by*64+ty*4+i)*Nc + bx*64 + tx*4) = o;
  }
}

// ---------------- state-block LDS layout (floats)
#define SL_L    0
#define SL_M    16896
#define SL_H    25600
#define SL_C    26112
#define SL_RD   26624
#define SL_V    26880
#define SL_WR   27360
#define SL_FW   27872
#define SL_BW   28384
#define SL_CR   28896
#define SL_USG  29408
#define SL_PRC  29536
#define SL_WW   29664
#define SL_SU   29792
#define SL_CPX  29920
#define SL_MN   30048
#define SL_SW   30176
#define SL_CW   30304
#define SL_RNK  30432
#define SL_MSC  30560
#define SL_ER   30624
#define SL_WV   30688
#define SL_TOT  30752   // 123008 bytes

// combined z+iface block LDS layout
#define GZ_W  0          // Ws [16][772] = 12352
#define GZ_WI 12352      // Wi [4][516]  = 2064
#define GZ_U  14416      // us [32][260] = 8320
#define GZ_ZH 22736      // zh [512]
// total 23248 floats

__device__ __forceinline__ void stage_u(float* us, const float* u_buf, int cbase) {
  const int tid = threadIdx.x;
#pragma unroll
  for (int i = 0; i < 4; ++i) {
    int idx = tid + i*1024;            // 4096 float2 slots = 32 x 256 floats
    int e = idx >> 7, q = (idx & 127) * 2;
    float2 v = ld2(&u_buf[e*UST + cbase + q]);
    *(float2*)&us[e*USS + q] = v;
  }
}

__device__ __forceinline__ void zgemm_chunk(const float* Ws, const float* us, int kbase, float acc[4][4]) {
  const int tid = threadIdx.x;
  const int tile = tid >> 5, s = tid & 31;
  const int e0 = (tile >> 2) * 4, jj = (tile & 3) * 4;
#pragma unroll
  for (int g = 0; g < 2; ++g) {
    int kk = g*128 + s*4;
    float4 u0 = *(const float4*)&us[(e0+0)*USS + kk];
    float4 u1 = *(const float4*)&us[(e0+1)*USS + kk];
    float4 u2 = *(const float4*)&us[(e0+2)*USS + kk];
    float4 u3 = *(const float4*)&us[(e0+3)*USS + kk];
    float4 w0 = *(const float4*)&Ws[(jj+0)*WSS + kbase + kk];
    float4 w1 = *(const float4*)&Ws[(jj+1)*WSS + kbase + kk];
    float4 w2 = *(const float4*)&Ws[(jj+2)*WSS + kbase + kk];
    float4 w3 = *(const float4*)&Ws[(jj+3)*WSS + kbase + kk];
    acc[0][0]+=D4(u0,w0); acc[0][1]+=D4(u0,w1); acc[0][2]+=D4(u0,w2); acc[0][3]+=D4(u0,w3);
    acc[1][0]+=D4(u1,w0); acc[1][1]+=D4(u1,w1); acc[1][2]+=D4(u1,w2); acc[1][3]+=D4(u1,w3);
    acc[2][0]+=D4(u2,w0); acc[2][1]+=D4(u2,w1); acc[2][2]+=D4(u2,w2); acc[2][3]+=D4(u2,w3);
    acc[3][0]+=D4(u3,w0); acc[3][1]+=D4(u3,w1); acc[3][2]+=D4(u3,w2); acc[3][3]+=D4(u3,w3);
  }
}

__device__ __forceinline__ void zreduce(float acc[4][4]) {
#pragma unroll
  for (int i = 0; i < 4; ++i)
#pragma unroll
    for (int j = 0; j < 4; ++j) {
      float a = acc[i][j];
      a += __shfl_xor(a, 1); a += __shfl_xor(a, 2); a += __shfl_xor(a, 4);
      a += __shfl_xor(a, 8); a += __shfl_xor(a, 16);
      acc[i][j] = a;
    }
}

__device__ __forceinline__ void iface_chunk(const float* Wi, const float* us, int wk, float accI[4]) {
  const int tid = threadIdx.x;
  if (tid < 512) {
    int e2 = tid >> 4, ks = tid & 15;
#pragma unroll
    for (int g = 0; g < 4; ++g) {
      int kk = g*64 + ks*4;
      float4 u4 = *(const float4*)&us[e2*USS + kk];
#pragma unroll
      for (int j = 0; j < 4; ++j) {
        float4 w4 = *(const float4*)&Wi[j*WIS + wk + kk];
        accI[j] += D4(u4,w4);
      }
    }
  }
}

__global__ void init_flags(unsigned* flags) {
  if (threadIdx.x < 256) flags[threadIdx.x] = 0u;
}

__global__ __launch_bounds__(1024) void dnc_coop(
    const float* __restrict__ Xproj, const float* __restrict__ Wx,
    const float* __restrict__ Wh, const float* __restrict__ Wif,
    const float* __restrict__ bif, float* __restrict__ Hist,
    float* __restrict__ z_buf, float* __restrict__ v_buf,
    float* __restrict__ u_buf, unsigned* __restrict__ flags)
{
  const int blk = blockIdx.x, tid = threadIdx.x;
  extern __shared__ float sm[];
  unsigned gen = 0;

  if (blk < 32) {
    // ================= STATE BLOCK (one example) =================
    const int e = blk;
    float* L   = sm + SL_L;   float* Ms  = sm + SL_M;
    float* h   = sm + SL_H;   float* c   = sm + SL_C;
    float* rd  = sm + SL_RD;  float* v   = sm + SL_V;
    float* wr  = sm + SL_WR;  float* fw  = sm + SL_FW;
    float* bw  = sm + SL_BW;  float* cr  = sm + SL_CR;
    float* usg = sm + SL_USG; float* prc = sm + SL_PRC;
    float* ww  = sm + SL_WW;  float* su  = sm + SL_SU;
    float* cpx = sm + SL_CPX; float* Mn  = sm + SL_MN;
    float* swv = sm + SL_SW;  float* cw  = sm + SL_CW;
    int*   rnk = (int*)(sm + SL_RNK);
    float* msc = sm + SL_MSC; float* er_ = sm + SL_ER; float* wv_ = sm + SL_WV;
    float* hist = Hist + (size_t)e * TT * 768;

    for (int i = tid; i < SL_TOT; i += 1024) sm[i] = 0.f;
    gbar(flags, ++gen);

    for (int t = 0; t < TT; ++t) {
      // ---- S1: LSTM gates (2 cols/thread, float2 coherent loads)
      if (tid < 256) {
        const float* zr = z_buf + e*ZD;
        float2 z0 = ld2(zr + 2*tid);
        float2 z1 = ld2(zr + 2*tid + 512);
        float2 z2 = ld2(zr + 2*tid + 1024);
        float2 z3 = ld2(zr + 2*tid + 1536);
        float cn0 = sig_(z1.x)*c[2*tid]   + sig_(z0.x)*tanhf(z2.x);
        float cn1 = sig_(z1.y)*c[2*tid+1] + sig_(z0.y)*tanhf(z2.y);
        float hn0 = sig_(z3.x)*tanhf(cn0);
        float hn1 = sig_(z3.y)*tanhf(cn1);
        c[2*tid] = cn0; c[2*tid+1] = cn1;
        h[2*tid] = hn0; h[2*tid+1] = hn1;
        float2 hv = {hn0, hn1};
        st2(&u_buf[e*UST + 256 + 2*tid], hv);
        *(float2*)&hist[t*768 + 256 + 2*tid] = hv;
      }
      gbar(flags, ++gen);   // bar_a (h published)
      gbar(flags, ++gen);   // bar_b (v ready)

      // A: v copy (Mn is already valid: phase G of step t-1 / zero-init at t=0)
      if (tid < IFC) v[tid] = ld1(&v_buf[e*VST + tid]);
      __syncthreads();
      // B: usage update / write sim / key norms / modes / erase-write prep
      if (tid < 128) {
        float ret = 1.f;
#pragma unroll
        for (int r = 0; r < 4; ++r) { float fr = sig_(v[453+r]); ret *= 1.f - fr*wr[r*128+tid]; }
        float u = usg[tid], w_ = ww[tid];
        usg[tid] = (u + w_ - u*w_) * ret;
      } else if (tid < 256) {
        int n = tid - 128; float nk = 0.f, dot = 0.f;
#pragma unroll
        for (int w = 0; w < 64; w += 4) {
          float4 k4 = *(float4*)&v[260+w];
          float4 m4 = *(float4*)&Ms[n*MST+w];
          nk += D4(k4,k4); dot += D4(m4,k4);
        }
        float beta = 1.f + sp_(v[324]);
        swv[n] = beta * dot / ((Mn[n]+EPSF)*(sqrtf(nk)+EPSF));
      } else if (tid < 260) {
        int r = tid - 256; float s = 0.f;
#pragma unroll
        for (int w = 0; w < 64; w += 4) { float4 k4 = *(float4*)&v[r*64+w]; s += D4(k4,k4); }
        msc[1+r] = sqrtf(s);
      } else if (tid == 260) {
        for (int r = 0; r < 4; ++r) {
          float a0 = v[459+r*3], a1 = v[459+r*3+1], a2 = v[459+r*3+2];
          float mx = fmaxf(a0, fmaxf(a1, a2));
          float e0 = expf(a0-mx), e1 = expf(a1-mx), e2 = expf(a2-mx);
          float dn = e0+e1+e2;
          msc[8+r*3] = e0/dn; msc[8+r*3+1] = e1/dn; msc[8+r*3+2] = e2/dn;
        }
      } else if (tid >= 640 && tid < 704) { int w = tid-640; er_[w] = sig_(v[325+w]); }
      else if (tid >= 704 && tid < 768) { int w = tid-704; wv_[w] = v[389+w]; }
      __syncthreads();
      // C: stable-ascending rank + write softmax
      if (tid < 128) {
        float ui = usg[tid]; int rk = 0;
        for (int j = 0; j < 128; ++j) {
          float uj = usg[j];
          rk += (uj < ui || (uj == ui && j < tid)) ? 1 : 0;
        }
        rnk[tid] = rk; su[rk] = ui;
      } else if (tid < 192) {
        int l = tid - 128;
        float s1 = swv[l], s2 = swv[l+64];
        float m = fmaxf(s1, s2);
#pragma unroll
        for (int o = 32; o > 0; o >>= 1) m = fmaxf(m, __shfl_xor(m, o));
        float e1 = expf(s1-m), e2 = expf(s2-m);
        float dn = e1 + e2;
#pragma unroll
        for (int o = 32; o > 0; o >>= 1) dn += __shfl_xor(dn, o);
        cw[l] = e1/dn; cw[l+64] = e2/dn;
      }
      __syncthreads();
      // D: exclusive cumprod via wave scan
      if (tid < 64) {
        float a0 = su[2*tid], a1 = su[2*tid+1];
        float p = a0*a1, sc = p;
#pragma unroll
        for (int off = 1; off < 64; off <<= 1) {
          float o = __shfl_up(sc, off);
          if ((int)tid >= off) sc *= o;
        }
        float ex = __shfl_up(sc, 1);
        if (tid == 0) ex = 1.f;
        cpx[2*tid] = ex;
        cpx[2*tid+1] = ex*a0;
      }
      __syncthreads();
      // E: ww_n
      if (tid < 128) {
        float a_i = (1.f - usg[tid]) * cpx[rnk[tid]];
        float ag = sig_(v[457]), wg = sig_(v[458]);
        ww[tid] = wg * (ag*a_i + (1.f-ag)*cw[tid]);
      }
      __syncthreads();
      // F: M erase/write + link update (old prec)
      {
        int n = tid >> 3, q = tid & 7;
        float wwn = ww[n];
        int w8 = q*8;
#pragma unroll
        for (int g = 0; g < 2; ++g) {
          int w = w8 + g*4;
          float4 m = *(float4*)&Ms[n*MST+w];
          float4 e4 = *(float4*)&er_[w];
          float4 v4 = *(float4*)&wv_[w];
          m.x = m.x*(1.f - wwn*e4.x) + wwn*v4.x;
          m.y = m.y*(1.f - wwn*e4.y) + wwn*v4.y;
          m.z = m.z*(1.f - wwn*e4.z) + wwn*v4.z;
          m.w = m.w*(1.f - wwn*e4.w) + wwn*v4.w;
          *(float4*)&Ms[n*MST+w] = m;
        }
        int j16 = q*16;
#pragma unroll
        for (int g = 0; g < 4; ++g) {
          int j = j16 + g*4;
          float4 lv = *(float4*)&L[n*LST + j];
          float4 p4 = *(float4*)&prc[j];
          float4 w4 = *(float4*)&ww[j];
          lv.x = (1.f - wwn - w4.x)*lv.x + wwn*p4.x;
          lv.y = (1.f - wwn - w4.y)*lv.y + wwn*p4.y;
          lv.z = (1.f - wwn - w4.z)*lv.z + wwn*p4.z;
          lv.w = (1.f - wwn - w4.w)*lv.w + wwn*p4.w;
          int d = n - j;
          if (d >= 0 && d < 4) ((float*)&lv)[d] = 0.f;
          *(float4*)&L[n*LST + j] = lv;
        }
      }
      __syncthreads();
      // G: sum(ww) + new M norms (these norms also serve next step's write lookup)
      if (tid < 64) {
        float s = ww[tid] + ww[tid+64];
#pragma unroll
        for (int o = 32; o > 0; o >>= 1) s += __shfl_xor(s, o);
        if (tid == 0) msc[0] = s;
      } else if (tid < 192) {
        int n = tid - 64; float s = 0.f;
#pragma unroll
        for (int w = 0; w < 64; w += 4) { float4 m = *(float4*)&Ms[n*MST+w]; s += D4(m,m); }
        Mn[n] = sqrtf(s);
      }
      __syncthreads();
      // H: fw/bw = link_n · wr_prev
      if (tid < 256) {
        int half = tid >> 7, t2 = tid & 127;
        int i0 = (t2 >> 2) * 4, sg = t2 & 3;
        float4 av[4] = {{0,0,0,0},{0,0,0,0},{0,0,0,0},{0,0,0,0}};
        if (half == 0) {
#pragma unroll
          for (int m = 0; m < 8; ++m) {
            int j = sg*4 + m*16;
            float4 w0 = *(float4*)&wr[0*128+j];
            float4 w1 = *(float4*)&wr[1*128+j];
            float4 w2 = *(float4*)&wr[2*128+j];
            float4 w3 = *(float4*)&wr[3*128+j];
            float4 l0 = *(float4*)&L[(i0+0)*LST+j];
            float4 l1 = *(float4*)&L[(i0+1)*LST+j];
            float4 l2 = *(float4*)&L[(i0+2)*LST+j];
            float4 l3 = *(float4*)&L[(i0+3)*LST+j];
            av[0].x+=D4(l0,w0); av[0].y+=D4(l1,w0); av[0].z+=D4(l2,w0); av[0].w+=D4(l3,w0);
            av[1].x+=D4(l0,w1); av[1].y+=D4(l1,w1); av[1].z+=D4(l2,w1); av[1].w+=D4(l3,w1);
            av[2].x+=D4(l0,w2); av[2].y+=D4(l1,w2); av[2].z+=D4(l2,w2); av[2].w+=D4(l3,w2);
            av[3].x+=D4(l0,w3); av[3].y+=D4(l1,w3); av[3].z+=D4(l2,w3); av[3].w+=D4(l3,w3);
          }
        } else {
#pragma unroll
          for (int m = 0; m < 32; ++m) {
            int j = sg + m*4;
            float4 lv = *(float4*)&L[j*LST + i0];
            float w0 = wr[j], w1 = wr[128+j], w2 = wr[256+j], w3 = wr[384+j];
            av[0].x+=w0*lv.x; av[0].y+=w0*lv.y; av[0].z+=w0*lv.z; av[0].w+=w0*lv.w;
            av[1].x+=w1*lv.x; av[1].y+=w1*lv.y; av[1].z+=w1*lv.z; av[1].w+=w1*lv.w;
            av[2].x+=w2*lv.x; av[2].y+=w2*lv.y; av[2].z+=w2*lv.z; av[2].w+=w2*lv.w;
            av[3].x+=w3*lv.x; av[3].y+=w3*lv.y; av[3].z+=w3*lv.z; av[3].w+=w3*lv.w;
          }
        }
#pragma unroll
        for (int r = 0; r < 4; ++r) {
          av[r].x += __shfl_xor(av[r].x,1); av[r].x += __shfl_xor(av[r].x,2);
          av[r].y += __shfl_xor(av[r].y,1); av[r].y += __shfl_xor(av[r].y,2);
          av[r].z += __shfl_xor(av[r].z,1); av[r].z += __shfl_xor(av[r].z,2);
          av[r].w += __shfl_xor(av[r].w,1); av[r].w += __shfl_xor(av[r].w,2);
        }
        if (sg == 0) {
          float* dst = half ? bw : fw;
#pragma unroll
          for (int r = 0; r < 4; ++r) {
            dst[r*128 + i0+0] = av[r].x; dst[r*128 + i0+1] = av[r].y;
            dst[r*128 + i0+2] = av[r].z; dst[r*128 + i0+3] = av[r].w;
          }
        }
      }
      __syncthreads();
      // I: prec update + read sims (new M)
      if (tid < 128) {
        prc[tid] = (1.f - msc[0])*prc[tid] + ww[tid];
      } else if (tid >= 512) {
        int r = (tid >> 7) & 3, n = tid & 127;
        float dot = 0.f;
#pragma unroll
        for (int w = 0; w < 64; w += 4) {
          float4 m4 = *(float4*)&Ms[n*MST+w];
          float4 k4 = *(float4*)&v[r*64+w];
          dot += D4(m4,k4);
        }
        float beta = 1.f + sp_(v[256+r]);
        cr[r*128+n] = beta * dot / ((Mn[n]+EPSF)*(msc[1+r]+EPSF));
      }
      __syncthreads();
      // J: per-head read softmax
      if (tid < 256) {
        int r = tid >> 6, l = tid & 63;
        float s1 = cr[r*128+l], s2 = cr[r*128+l+64];
        float m = fmaxf(s1, s2);
#pragma unroll
        for (int o = 32; o > 0; o >>= 1) m = fmaxf(m, __shfl_xor(m, o));
        float e1 = expf(s1-m), e2 = expf(s2-m);
        float dn = e1 + e2;
#pragma unroll
        for (int o = 32; o > 0; o >>= 1) dn += __shfl_xor(dn, o);
        cr[r*128+l] = e1/dn; cr[r*128+l+64] = e2/dn;
      }
      __syncthreads();
      // K: wr_n
      if (tid < 512) {
        int r = tid >> 7;
        wr[tid] = msc[8+r*3]*bw[tid] + msc[8+r*3+1]*cr[tid] + msc[8+r*3+2]*fw[tid];
      }
      __syncthreads();
      // L: reads_n = wr_n @ M_n + publish
      if (tid < 512) {
        int r = tid >> 7, t2 = tid & 127;
        int w0 = (t2 >> 3) * 4, ns = t2 & 7;
        float4 a = {0,0,0,0};
#pragma unroll
        for (int m = 0; m < 16; ++m) {
          int n = ns + m*8;
          float4 mr = *(float4*)&Ms[n*MST + w0];
          float wv = wr[r*128 + n];
          a.x += wv*mr.x; a.y += wv*mr.y; a.z += wv*mr.z; a.w += wv*mr.w;
        }
        a.x += __shfl_xor(a.x,1); a.x += __shfl_xor(a.x,2); a.x += __shfl_xor(a.x,4);
        a.y += __shfl_xor(a.y,1); a.y += __shfl_xor(a.y,2); a.y += __shfl_xor(a.y,4);
        a.z += __shfl_xor(a.z,1); a.z += __shfl_xor(a.z,2); a.z += __shfl_xor(a.z,4);
        a.w += __shfl_xor(a.w,1); a.w += __shfl_xor(a.w,2); a.w += __shfl_xor(a.w,4);
        if (ns == 0) {
          int o = r*64 + w0;
          *(float4*)&rd[o] = a;
          *(float4*)&hist[t*768 + o] = a;
          float2 lo = {a.x, a.y}, hi = {a.z, a.w};
          st2(&u_buf[e*UST + o], lo);
          st2(&u_buf[e*UST + o + 2], hi);
        }
      }
      gbar(flags, ++gen);   // bar_c (reads published)
      gbar(flags, ++gen);   // bar_d (z(t+1) ready)
    }
  } else {
    // ============ COMBINED BLOCK: 16 z-cols + 4 iface cols ============
    const int cb = blk - 32;
    const int j0z = cb * 16;
    const int j0i = cb * 4;
    float* Ws = sm + GZ_W;
    float* Wi = sm + GZ_WI;
    float* us = sm + GZ_U;
    float* zh = sm + GZ_ZH;
    for (int i = tid; i < 16*768; i += 1024) {
      int k = i >> 4, j = i & 15;
      Ws[j*WSS + k] = (k < 256) ? Wx[(size_t)(512+k)*ZD + j0z + j]
                                : Wh[(size_t)(k-256)*ZD + j0z + j];
    }
    for (int i = tid; i < 4*512; i += 1024) {
      int k = i >> 2, j = i & 3;
      int col = j0i + j;
      Wi[j*WIS + k] = (col < IFC) ? Wif[(size_t)k*IFC + col] : 0.f;
    }
    if (tid < 512) {
      int e2 = tid >> 4, j = tid & 15;
      st1(&z_buf[e2*ZD + j0z + j], Xproj[(size_t)(e2*TT)*ZD + j0z + j]);
    }
    gbar(flags, ++gen);

    for (int t = 0; t < TT; ++t) {
      gbar(flags, ++gen);   // bar_a: h(t) ready
      bool act = (t+1 < TT);
      {
        // G1: v(t) = h@Wif + bif ; zh(t+1) = Xproj(t+1) + h@Wh
        if (act && tid < 512) {
          int e2 = tid >> 4, j = tid & 15;
          zh[tid] = Xproj[(size_t)(e2*TT + t+1)*ZD + j0z + j];
        }
        float acc[4][4] = {};
        float accI[4] = {0,0,0,0};
        stage_u(us, u_buf, 256); __syncthreads();
        iface_chunk(Wi, us, 0, accI);
        if (act) zgemm_chunk(Ws, us, 256, acc);
        __syncthreads();
        stage_u(us, u_buf, 512); __syncthreads();
        iface_chunk(Wi, us, 256, accI);
        if (act) zgemm_chunk(Ws, us, 512, acc);
        // publish v
        if (tid < 512) {
          int e2 = tid >> 4, ks = tid & 15;
#pragma unroll
          for (int j = 0; j < 4; ++j) {
            float a = accI[j];
            a += __shfl_xor(a,1); a += __shfl_xor(a,2); a += __shfl_xor(a,4); a += __shfl_xor(a,8);
            accI[j] = a;
          }
          if (ks == 0) {
#pragma unroll
            for (int j = 0; j < 4; ++j) {
              int col = j0i + j;
              if (col < IFC) st1(&v_buf[e2*VST + col], bif[col] + accI[j]);
            }
          }
        }
        if (act) {
          zreduce(acc);
          int tile = tid >> 5, s = tid & 31;
          int e0 = (tile >> 2) * 4, jj = (tile & 3) * 4;
          if (s == 0) {
#pragma unroll
            for (int i = 0; i < 4; ++i)
#pragma unroll
              for (int j = 0; j < 4; ++j)
                zh[(e0+i)*16 + jj + j] += acc[i][j];
          }
        }
      }
      gbar(flags, ++gen);   // bar_b (v published)
      gbar(flags, ++gen);   // bar_c: reads(t) ready
      if (act) {
        // G2: z(t+1) = zh + reads(t) @ WxR
        float acc[4][4] = {};
        stage_u(us, u_buf, 0); __syncthreads();
        zgemm_chunk(Ws, us, 0, acc);
        zreduce(acc);
        int tile = tid >> 5, s = tid & 31;
        int e0 = (tile >> 2) * 4, jj = (tile & 3) * 4;
        if (s == 0) {
#pragma unroll
          for (int i = 0; i < 4; ++i) {
#pragma unroll
            for (int jp = 0; jp < 2; ++jp) {
              float2 val = { zh[(e0+i)*16 + jj + 2*jp]   + acc[i][2*jp],
                             zh[(e0+i)*16 + jj + 2*jp+1] + acc[i][2*jp+1] };
              st2(&z_buf[(size_t)(e0+i)*ZD + j0z + jj + 2*jp], val);
            }
          }
        }
      }
      gbar(flags, ++gen);   // bar_d
    }
  }
}

extern "C" void kernel_launch(void* const* d_in, const int* in_sizes, int n_in,
                              void* d_out, int out_size, void* d_ws, size_t ws_size,
                              hipStream_t stream) {
  const float* x   = (const float*)d_in[0];
  const float* Wx  = (const float*)d_in[1];
  const float* Wh  = (const float*)d_in[2];
  const float* bl  = (const float*)d_in[3];
  const float* Wif = (const float*)d_in[4];
  const float* bif = (const float*)d_in[5];
  const float* Wo  = (const float*)d_in[6];
  const float* bo  = (const float*)d_in[7];
  float* out = (float*)d_out;

  float* Xp   = (float*)d_ws;                          // 4096*2048
  float* Hist = Xp + (size_t)4096*2048;                // 4096*768
  float* zb   = Hist + (size_t)4096*768;               // 32*2048
  float* vb   = zb + 32*2048;                          // 32*480
  float* ub   = vb + 32*480;                           // 32*768
  unsigned* fl = (unsigned*)(ub + 32*768);             // 256

  gemm_bias<<<dim3(2048/64, 4096/64), dim3(256), 0, stream>>>(x, Wx, bl, Xp, 4096, 2048, 512);
  init_flags<<<dim3(1), dim3(256), 0, stream>>>(fl);

  const int smem_bytes = SL_TOT * 4;  // 123008
  hipFuncSetAttribute((const void*)dnc_coop, hipFuncAttributeMaxDynamicSharedMemorySize, smem_bytes);
  void* args[] = { (void*)&Xp, (void*)&Wx, (void*)&Wh, (void*)&Wif, (void*)&bif,
                   (void*)&Hist, (void*)&zb, (void*)&vb, (void*)&ub, (void*)&fl };
  hipLaunchCooperativeKernel((void*)dnc_coop, dim3(NBLK), dim3(1024), args,
                             (unsigned int)smem_bytes, stream);

  gemm_bias<<<dim3(512/64, 4096/64), dim3(256), 0, stream>>>(Hist, Wo, bo, out, 4096, 512, 768);
}

// Round 4
// 6610.369 us; speedup vs baseline: 3.3661x; 1.1744x over previous
//
#include <hip/hip_runtime.h>
#include <math.h>

#define TT 128
#define ZD 2048
#define IFC 471
#define EPSF 1e-6f
#define MST 68      // M LDS row stride
#define LST 132     // link LDS row stride
#define NBLK 160
#define UHT 24640   // per-t stride of Uh: 32*768 + 64 guard floats
#define VHT 15424   // per-t stride of Vh: 32*480 + 64 guard floats
#define USS 516     // staged activation LDS row stride
#define WSS 772     // z weight slice LDS row stride
#define WIS 516     // iface weight slice LDS row stride

#define D4(a,b) ((a).x*(b).x + (a).y*(b).y + (a).z*(b).z + (a).w*(b).w)

__device__ __forceinline__ float sig_(float x){ return 1.f/(1.f+expf(-x)); }
__device__ __forceinline__ float sp_(float x){ return fmaxf(x,0.f)+log1pf(expf(-fabsf(x))); }

// -------- agent-scope (write-through, cache-bypassing) publishes --------
__device__ __forceinline__ void st1(float* p, float v){
  unsigned u; __builtin_memcpy(&u,&v,4);
  __hip_atomic_store((unsigned*)p, u, __ATOMIC_RELAXED, __HIP_MEMORY_SCOPE_AGENT);
}
__device__ __forceinline__ void st2(float* p, float2 v){
  unsigned long long u; __builtin_memcpy(&u,&v,8);
  __hip_atomic_store((unsigned long long*)p, u, __ATOMIC_RELAXED, __HIP_MEMORY_SCOPE_AGENT);
}

// -------- fence-free all-report/all-check barrier: wave 0 polls ----------
// __syncthreads() drains each wave's vmcnt(0) before s_barrier, so all prior
// agent-scope stores are at the coherent point before the flag release.
__device__ __forceinline__ void gbar(unsigned* flags, unsigned gen){
  __syncthreads();
  if (threadIdx.x == 0)
    __hip_atomic_store(&flags[blockIdx.x], gen, __ATOMIC_RELEASE, __HIP_MEMORY_SCOPE_AGENT);
  if (threadIdx.x < 64){
    for (int f = threadIdx.x; f < NBLK; f += 64){
      while (__hip_atomic_load(&flags[f], __ATOMIC_RELAXED, __HIP_MEMORY_SCOPE_AGENT) < gen)
        __builtin_amdgcn_s_sleep(2);
    }
  }
  __syncthreads();
}

// ---------------- GEMM #1: C[M,N] = A[M,K] @ B[K,N] + bias[N]
__global__ __launch_bounds__(256) void gemm_bias(
    const float* __restrict__ A, const float* __restrict__ B,
    const float* __restrict__ bias, float* __restrict__ C,
    int Nc, int K)
{
  __shared__ float As[16][68];
  __shared__ float Bs[16][68];
  const int tid = threadIdx.x;
  const int bx = blockIdx.x, by = blockIdx.y;
  const int tx = tid & 15, ty = tid >> 4;
  const int am = tid >> 2, ak = (tid & 3) * 4;
  const int bk = tid >> 4, bn = (tid & 15) * 4;
  float acc[4][4] = {};
  const float* Ap = A + (size_t)(by*64+am)*K + ak;
  const float* Bp = B + (size_t)bk*Nc + bx*64 + bn;
  for (int k0 = 0; k0 < K; k0 += 16) {
    float4 av = *(const float4*)Ap; Ap += 16;
    float4 bv = *(const float4*)Bp; Bp += (size_t)16*Nc;
    As[ak+0][am]=av.x; As[ak+1][am]=av.y; As[ak+2][am]=av.z; As[ak+3][am]=av.w;
    *(float4*)&Bs[bk][bn] = bv;
    __syncthreads();
#pragma unroll
    for (int kk = 0; kk < 16; ++kk) {
      float4 a4 = *(const float4*)&As[kk][ty*4];
      float4 b4 = *(const float4*)&Bs[kk][tx*4];
      acc[0][0]+=a4.x*b4.x; acc[0][1]+=a4.x*b4.y; acc[0][2]+=a4.x*b4.z; acc[0][3]+=a4.x*b4.w;
      acc[1][0]+=a4.y*b4.x; acc[1][1]+=a4.y*b4.y; acc[1][2]+=a4.y*b4.z; acc[1][3]+=a4.y*b4.w;
      acc[2][0]+=a4.z*b4.x; acc[2][1]+=a4.z*b4.y; acc[2][2]+=a4.z*b4.z; acc[2][3]+=a4.z*b4.w;
      acc[3][0]+=a4.w*b4.x; acc[3][1]+=a4.w*b4.y; acc[3][2]+=a4.w*b4.z; acc[3][3]+=a4.w*b4.w;
    }
    __syncthreads();
  }
  float4 bb = *(const float4*)(bias + bx*64 + tx*4);
#pragma unroll
  for (int i = 0; i < 4; ++i) {
    float4 o;
    o.x = acc[i][0]+bb.x; o.y = acc[i][1]+bb.y; o.z = acc[i][2]+bb.z; o.w = acc[i][3]+bb.w;
    *(float4*)(C + (size_t)(by*64+ty*4+i)*Nc + bx*64 + tx*4) = o;
  }
}

// ---------------- GEMM #2 (output): A rows live in Uh[t][e] layout.
// A row m (m = t*32+e): addr = t*UHT + e*768, K=768. C row = e*128+t, N=512.
__global__ __launch_bounds__(256) void gemm_out(
    const float* __restrict__ A, const float* __restrict__ B,
    const float* __restrict__ bias, float* __restrict__ C)
{
  __shared__ float As[16][68];
  __shared__ float Bs[16][68];
  const int tid = threadIdx.x;
  const int bx = blockIdx.x, by = blockIdx.y;
  const int tx = tid & 15, ty = tid >> 4;
  const int am = tid >> 2, ak = (tid & 3) * 4;
  const int bk = tid >> 4, bn = (tid & 15) * 4;
  float acc[4][4] = {};
  const int arow = by*64 + am;
  const float* Ap = A + (size_t)(arow >> 5)*UHT + (size_t)(arow & 31)*768 + ak;
  const float* Bp = B + (size_t)bk*512 + bx*64 + bn;
  for (int k0 = 0; k0 < 768; k0 += 16) {
    float4 av = *(const float4*)Ap; Ap += 16;
    float4 bv = *(const float4*)Bp; Bp += (size_t)16*512;
    As[ak+0][am]=av.x; As[ak+1][am]=av.y; As[ak+2][am]=av.z; As[ak+3][am]=av.w;
    *(float4*)&Bs[bk][bn] = bv;
    __syncthreads();
#pragma unroll
    for (int kk = 0; kk < 16; ++kk) {
      float4 a4 = *(const float4*)&As[kk][ty*4];
      float4 b4 = *(const float4*)&Bs[kk][tx*4];
      acc[0][0]+=a4.x*b4.x; acc[0][1]+=a4.x*b4.y; acc[0][2]+=a4.x*b4.z; acc[0][3]+=a4.x*b4.w;
      acc[1][0]+=a4.y*b4.x; acc[1][1]+=a4.y*b4.y; acc[1][2]+=a4.y*b4.z; acc[1][3]+=a4.y*b4.w;
      acc[2][0]+=a4.z*b4.x; acc[2][1]+=a4.z*b4.y; acc[2][2]+=a4.z*b4.z; acc[2][3]+=a4.z*b4.w;
      acc[3][0]+=a4.w*b4.x; acc[3][1]+=a4.w*b4.y; acc[3][2]+=a4.w*b4.z; acc[3][3]+=a4.w*b4.w;
    }
    __syncthreads();
  }
  float4 bb = *(const float4*)(bias + bx*64 + tx*4);
#pragma unroll
  for (int i = 0; i < 4; ++i) {
    int row = by*64 + ty*4 + i;
    int crow = (row & 31)*128 + (row >> 5);   // (e,t) -> e*128+t
    float4 o;
    o.x = acc[i][0]+bb.x; o.y = acc[i][1]+bb.y; o.z = acc[i][2]+bb.z; o.w = acc[i][3]+bb.w;
    *(float4*)(C + (size_t)crow*512 + bx*64 + tx*4) = o;
  }
}

// ---------------- state-block LDS layout (floats)
#define SL_L    0
#define SL_M    16896
#define SL_V    25600
#define SL_WR   26080
#define SL_FW   26592
#define SL_BW   27104
#define SL_CR   27616
#define SL_USG  28128
#define SL_PRC  28256
#define SL_WW   28384
#define SL_SU   28512
#define SL_CPX  28640
#define SL_MN   28768
#define SL_SW   28896
#define SL_CW   29024
#define SL_RNK  29152
#define SL_MSC  29280
#define SL_ER   29344
#define SL_WV   29408
#define SL_TOT  29472

// ---------------- col-block LDS layout (floats)
#define CL_WS  0                      // Ws [16][772] = 12352
#define CL_WI  12352                  // Wi [4][516]  = 2064
#define CL_US  14416                  // us [32][516] = 16512
#define CL_ZH  30928                  // zh [512]
#define CL_CS  31440                  // c  [128]
#define CL_HL  31568                  // h  [128]
#define CL_TOT 31696                  // 126784 bytes

__device__ __forceinline__ void zgemm(const float* Ws, const float* us, int wofs,
                                      int giters, float acc[4][4]) {
  const int tid = threadIdx.x;
  const int tile = tid >> 5, s = tid & 31;
  const int e0 = (tile >> 2)*4, jj = (tile & 3)*4;
  for (int g = 0; g < giters; ++g) {
    int kk = g*128 + s*4;
    float4 u0 = *(const float4*)&us[(e0+0)*USS + kk];
    float4 u1 = *(const float4*)&us[(e0+1)*USS + kk];
    float4 u2 = *(const float4*)&us[(e0+2)*USS + kk];
    float4 u3 = *(const float4*)&us[(e0+3)*USS + kk];
    float4 w0 = *(const float4*)&Ws[(jj+0)*WSS + wofs + kk];
    float4 w1 = *(const float4*)&Ws[(jj+1)*WSS + wofs + kk];
    float4 w2 = *(const float4*)&Ws[(jj+2)*WSS + wofs + kk];
    float4 w3 = *(const float4*)&Ws[(jj+3)*WSS + wofs + kk];
    acc[0][0]+=D4(u0,w0); acc[0][1]+=D4(u0,w1); acc[0][2]+=D4(u0,w2); acc[0][3]+=D4(u0,w3);
    acc[1][0]+=D4(u1,w0); acc[1][1]+=D4(u1,w1); acc[1][2]+=D4(u1,w2); acc[1][3]+=D4(u1,w3);
    acc[2][0]+=D4(u2,w0); acc[2][1]+=D4(u2,w1); acc[2][2]+=D4(u2,w2); acc[2][3]+=D4(u2,w3);
    acc[3][0]+=D4(u3,w0); acc[3][1]+=D4(u3,w1); acc[3][2]+=D4(u3,w2); acc[3][3]+=D4(u3,w3);
  }
}

__device__ __forceinline__ void zreduce(float acc[4][4]) {
#pragma unroll
  for (int i = 0; i < 4; ++i)
#pragma unroll
    for (int j = 0; j < 4; ++j) {
      float a = acc[i][j];
      a += __shfl_xor(a, 1); a += __shfl_xor(a, 2); a += __shfl_xor(a, 4);
      a += __shfl_xor(a, 8); a += __shfl_xor(a, 16);
      acc[i][j] = a;
    }
}

__global__ void init_flags(unsigned* flags) {
  if (threadIdx.x < 256) flags[threadIdx.x] = 0u;
}

__global__ __launch_bounds__(1024) void dnc_coop(
    const float* __restrict__ Xproj, const float* __restrict__ Wx,
    const float* __restrict__ Wh, const float* __restrict__ Wif,
    const float* __restrict__ bif,
    float* __restrict__ Uh, float* __restrict__ Vh,
    unsigned* __restrict__ flags)
{
  const int blk = blockIdx.x, tid = threadIdx.x;
  extern __shared__ float sm[];
  unsigned gen = 0;

  if (blk < 32) {
    // ================= STATE BLOCK (one example) =================
    const int e = blk;
    float* L   = sm + SL_L;   float* Ms  = sm + SL_M;
    float* v   = sm + SL_V;   float* wr  = sm + SL_WR;
    float* fw  = sm + SL_FW;  float* bw  = sm + SL_BW;
    float* cr  = sm + SL_CR;  float* usg = sm + SL_USG;
    float* prc = sm + SL_PRC; float* ww  = sm + SL_WW;
    float* su  = sm + SL_SU;  float* cpx = sm + SL_CPX;
    float* Mn  = sm + SL_MN;  float* swv = sm + SL_SW;
    float* cw  = sm + SL_CW;  int*   rnk = (int*)(sm + SL_RNK);
    float* msc = sm + SL_MSC; float* er_ = sm + SL_ER; float* wv_ = sm + SL_WV;

    for (int i = tid; i < SL_TOT; i += 1024) sm[i] = 0.f;
    gbar(flags, ++gen);   // bar_a(0)

    for (int t = 0; t < TT; ++t) {
      gbar(flags, ++gen);   // bar_b: v(t) visible
      // A: v copy (plain cached loads from fresh per-t region)
      if (tid < IFC) v[tid] = Vh[(size_t)t*VHT + e*480 + tid];
      __syncthreads();
      // B: usage update / write sim / key norms / modes / erase-write prep
      if (tid < 128) {
        float ret = 1.f;
#pragma unroll
        for (int r = 0; r < 4; ++r) { float fr = sig_(v[453+r]); ret *= 1.f - fr*wr[r*128+tid]; }
        float u = usg[tid], w_ = ww[tid];
        usg[tid] = (u + w_ - u*w_) * ret;
      } else if (tid < 256) {
        int n = tid - 128; float nk = 0.f, dot = 0.f;
#pragma unroll
        for (int w = 0; w < 64; w += 4) {
          float4 k4 = *(float4*)&v[260+w];
          float4 m4 = *(float4*)&Ms[n*MST+w];
          nk += D4(k4,k4); dot += D4(m4,k4);
        }
        float beta = 1.f + sp_(v[324]);
        swv[n] = beta * dot / ((Mn[n]+EPSF)*(sqrtf(nk)+EPSF));
      } else if (tid < 260) {
        int r = tid - 256; float s = 0.f;
#pragma unroll
        for (int w = 0; w < 64; w += 4) { float4 k4 = *(float4*)&v[r*64+w]; s += D4(k4,k4); }
        msc[1+r] = sqrtf(s);
      } else if (tid == 260) {
        for (int r = 0; r < 4; ++r) {
          float a0 = v[459+r*3], a1 = v[459+r*3+1], a2 = v[459+r*3+2];
          float mx = fmaxf(a0, fmaxf(a1, a2));
          float e0 = expf(a0-mx), e1 = expf(a1-mx), e2 = expf(a2-mx);
          float dn = e0+e1+e2;
          msc[8+r*3] = e0/dn; msc[8+r*3+1] = e1/dn; msc[8+r*3+2] = e2/dn;
        }
      } else if (tid >= 640 && tid < 704) { int w = tid-640; er_[w] = sig_(v[325+w]); }
      else if (tid >= 704 && tid < 768) { int w = tid-704; wv_[w] = v[389+w]; }
      __syncthreads();
      // C: stable-ascending rank + write softmax
      if (tid < 128) {
        float ui = usg[tid]; int rk = 0;
        for (int j = 0; j < 128; ++j) {
          float uj = usg[j];
          rk += (uj < ui || (uj == ui && j < tid)) ? 1 : 0;
        }
        rnk[tid] = rk; su[rk] = ui;
      } else if (tid < 192) {
        int l = tid - 128;
        float s1 = swv[l], s2 = swv[l+64];
        float m = fmaxf(s1, s2);
#pragma unroll
        for (int o = 32; o > 0; o >>= 1) m = fmaxf(m, __shfl_xor(m, o));
        float e1 = expf(s1-m), e2 = expf(s2-m);
        float dn = e1 + e2;
#pragma unroll
        for (int o = 32; o > 0; o >>= 1) dn += __shfl_xor(dn, o);
        cw[l] = e1/dn; cw[l+64] = e2/dn;
      }
      __syncthreads();
      // D: exclusive cumprod via wave scan
      if (tid < 64) {
        float a0 = su[2*tid], a1 = su[2*tid+1];
        float p = a0*a1, sc = p;
#pragma unroll
        for (int off = 1; off < 64; off <<= 1) {
          float o = __shfl_up(sc, off);
          if ((int)tid >= off) sc *= o;
        }
        float ex = __shfl_up(sc, 1);
        if (tid == 0) ex = 1.f;
        cpx[2*tid] = ex;
        cpx[2*tid+1] = ex*a0;
      }
      __syncthreads();
      // E: ww_n
      if (tid < 128) {
        float a_i = (1.f - usg[tid]) * cpx[rnk[tid]];
        float ag = sig_(v[457]), wg = sig_(v[458]);
        ww[tid] = wg * (ag*a_i + (1.f-ag)*cw[tid]);
      }
      __syncthreads();
      // F: M erase/write + link update (old prec)
      {
        int n = tid >> 3, q = tid & 7;
        float wwn = ww[n];
        int w8 = q*8;
#pragma unroll
        for (int g = 0; g < 2; ++g) {
          int w = w8 + g*4;
          float4 m = *(float4*)&Ms[n*MST+w];
          float4 e4 = *(float4*)&er_[w];
          float4 v4 = *(float4*)&wv_[w];
          m.x = m.x*(1.f - wwn*e4.x) + wwn*v4.x;
          m.y = m.y*(1.f - wwn*e4.y) + wwn*v4.y;
          m.z = m.z*(1.f - wwn*e4.z) + wwn*v4.z;
          m.w = m.w*(1.f - wwn*e4.w) + wwn*v4.w;
          *(float4*)&Ms[n*MST+w] = m;
        }
        int j16 = q*16;
#pragma unroll
        for (int g = 0; g < 4; ++g) {
          int j = j16 + g*4;
          float4 lv = *(float4*)&L[n*LST + j];
          float4 p4 = *(float4*)&prc[j];
          float4 w4 = *(float4*)&ww[j];
          lv.x = (1.f - wwn - w4.x)*lv.x + wwn*p4.x;
          lv.y = (1.f - wwn - w4.y)*lv.y + wwn*p4.y;
          lv.z = (1.f - wwn - w4.z)*lv.z + wwn*p4.z;
          lv.w = (1.f - wwn - w4.w)*lv.w + wwn*p4.w;
          int d = n - j;
          if (d >= 0 && d < 4) ((float*)&lv)[d] = 0.f;
          *(float4*)&L[n*LST + j] = lv;
        }
      }
      __syncthreads();
      // G: sum(ww) + new M norms
      if (tid < 64) {
        float s = ww[tid] + ww[tid+64];
#pragma unroll
        for (int o = 32; o > 0; o >>= 1) s += __shfl_xor(s, o);
        if (tid == 0) msc[0] = s;
      } else if (tid < 192) {
        int n = tid - 64; float s = 0.f;
#pragma unroll
        for (int w = 0; w < 64; w += 4) { float4 m = *(float4*)&Ms[n*MST+w]; s += D4(m,m); }
        Mn[n] = sqrtf(s);
      }
      __syncthreads();
      // H: fw/bw = link_n · wr_prev
      if (tid < 256) {
        int half = tid >> 7, t2 = tid & 127;
        int i0 = (t2 >> 2) * 4, sg = t2 & 3;
        float4 av[4] = {{0,0,0,0},{0,0,0,0},{0,0,0,0},{0,0,0,0}};
        if (half == 0) {
#pragma unroll
          for (int m = 0; m < 8; ++m) {
            int j = sg*4 + m*16;
            float4 w0 = *(float4*)&wr[0*128+j];
            float4 w1 = *(float4*)&wr[1*128+j];
            float4 w2 = *(float4*)&wr[2*128+j];
            float4 w3 = *(float4*)&wr[3*128+j];
            float4 l0 = *(float4*)&L[(i0+0)*LST+j];
            float4 l1 = *(float4*)&L[(i0+1)*LST+j];
            float4 l2 = *(float4*)&L[(i0+2)*LST+j];
            float4 l3 = *(float4*)&L[(i0+3)*LST+j];
            av[0].x+=D4(l0,w0); av[0].y+=D4(l1,w0); av[0].z+=D4(l2,w0); av[0].w+=D4(l3,w0);
            av[1].x+=D4(l0,w1); av[1].y+=D4(l1,w1); av[1].z+=D4(l2,w1); av[1].w+=D4(l3,w1);
            av[2].x+=D4(l0,w2); av[2].y+=D4(l1,w2); av[2].z+=D4(l2,w2); av[2].w+=D4(l3,w2);
            av[3].x+=D4(l0,w3); av[3].y+=D4(l1,w3); av[3].z+=D4(l2,w3); av[3].w+=D4(l3,w3);
          }
        } else {
#pragma unroll
          for (int m = 0; m < 32; ++m) {
            int j = sg + m*4;
            float4 lv = *(float4*)&L[j*LST + i0];
            float w0 = wr[j], w1 = wr[128+j], w2 = wr[256+j], w3 = wr[384+j];
            av[0].x+=w0*lv.x; av[0].y+=w0*lv.y; av[0].z+=w0*lv.z; av[0].w+=w0*lv.w;
            av[1].x+=w1*lv.x; av[1].y+=w1*lv.y; av[1].z+=w1*lv.z; av[1].w+=w1*lv.w;
            av[2].x+=w2*lv.x; av[2].y+=w2*lv.y; av[2].z+=w2*lv.z; av[2].w+=w2*lv.w;
            av[3].x+=w3*lv.x; av[3].y+=w3*lv.y; av[3].z+=w3*lv.z; av[3].w+=w3*lv.w;
          }
        }
#pragma unroll
        for (int r = 0; r < 4; ++r) {
          av[r].x += __shfl_xor(av[r].x,1); av[r].x += __shfl_xor(av[r].x,2);
          av[r].y += __shfl_xor(av[r].y,1); av[r].y += __shfl_xor(av[r].y,2);
          av[r].z += __shfl_xor(av[r].z,1); av[r].z += __shfl_xor(av[r].z,2);
          av[r].w += __shfl_xor(av[r].w,1); av[r].w += __shfl_xor(av[r].w,2);
        }
        if (sg == 0) {
          float* dst = half ? bw : fw;
#pragma unroll
          for (int r = 0; r < 4; ++r) {
            dst[r*128 + i0+0] = av[r].x; dst[r*128 + i0+1] = av[r].y;
            dst[r*128 + i0+2] = av[r].z; dst[r*128 + i0+3] = av[r].w;
          }
        }
      }
      __syncthreads();
      // I: prec update + read sims (new M)
      if (tid < 128) {
        prc[tid] = (1.f - msc[0])*prc[tid] + ww[tid];
      } else if (tid >= 512) {
        int r = (tid >> 7) & 3, n = tid & 127;
        float dot = 0.f;
#pragma unroll
        for (int w = 0; w < 64; w += 4) {
          float4 m4 = *(float4*)&Ms[n*MST+w];
          float4 k4 = *(float4*)&v[r*64+w];
          dot += D4(m4,k4);
        }
        float beta = 1.f + sp_(v[256+r]);
        cr[r*128+n] = beta * dot / ((Mn[n]+EPSF)*(msc[1+r]+EPSF));
      }
      __syncthreads();
      // J: per-head read softmax
      if (tid < 256) {
        int r = tid >> 6, l = tid & 63;
        float s1 = cr[r*128+l], s2 = cr[r*128+l+64];
        float m = fmaxf(s1, s2);
#pragma unroll
        for (int o = 32; o > 0; o >>= 1) m = fmaxf(m, __shfl_xor(m, o));
        float e1 = expf(s1-m), e2 = expf(s2-m);
        float dn = e1 + e2;
#pragma unroll
        for (int o = 32; o > 0; o >>= 1) dn += __shfl_xor(dn, o);
        cr[r*128+l] = e1/dn; cr[r*128+l+64] = e2/dn;
      }
      __syncthreads();
      // K: wr_n
      if (tid < 512) {
        int r = tid >> 7;
        wr[tid] = msc[8+r*3]*bw[tid] + msc[8+r*3+1]*cr[tid] + msc[8+r*3+2]*fw[tid];
      }
      __syncthreads();
      // L: reads_n = wr_n @ M_n, publish to Uh[t]
      if (tid < 512) {
        int r = tid >> 7, t2 = tid & 127;
        int w0 = (t2 >> 3) * 4, ns = t2 & 7;
        float4 a = {0,0,0,0};
#pragma unroll
        for (int m = 0; m < 16; ++m) {
          int n = ns + m*8;
          float4 mr = *(float4*)&Ms[n*MST + w0];
          float wv = wr[r*128 + n];
          a.x += wv*mr.x; a.y += wv*mr.y; a.z += wv*mr.z; a.w += wv*mr.w;
        }
        a.x += __shfl_xor(a.x,1); a.x += __shfl_xor(a.x,2); a.x += __shfl_xor(a.x,4);
        a.y += __shfl_xor(a.y,1); a.y += __shfl_xor(a.y,2); a.y += __shfl_xor(a.y,4);
        a.z += __shfl_xor(a.z,1); a.z += __shfl_xor(a.z,2); a.z += __shfl_xor(a.z,4);
        a.w += __shfl_xor(a.w,1); a.w += __shfl_xor(a.w,2); a.w += __shfl_xor(a.w,4);
        if (ns == 0) {
          int o = r*64 + w0;
          float2 lo = {a.x, a.y}, hi = {a.z, a.w};
          st2(&Uh[(size_t)t*UHT + e*768 + o], lo);
          st2(&Uh[(size_t)t*UHT + e*768 + o + 2], hi);
        }
      }
      gbar(flags, ++gen);   // bar_c: reads(t) published
      gbar(flags, ++gen);   // bar_a(t+1): h(t+1) published by col-blocks
    }
  } else {
    // ======== COL BLOCK: z-cols {q*512 + cb*4 + d} + 4 iface cols ========
    const int cb = blk - 32;
    float* Ws = sm + CL_WS;
    float* Wi = sm + CL_WI;
    float* us = sm + CL_US;
    float* zh = sm + CL_ZH;
    float* cst= sm + CL_CS;
    float* hl = sm + CL_HL;
    // load weight slices (once)
    for (int i = tid; i < 16*768; i += 1024) {
      int j = i & 15, k = i >> 4;
      int gc = (j >> 2)*512 + cb*4 + (j & 3);
      Ws[j*WSS + k] = (k < 256) ? Wx[(size_t)(512+k)*ZD + gc]
                                : Wh[(size_t)(k-256)*ZD + gc];
    }
    for (int i = tid; i < 4*512; i += 1024) {
      int j = i & 3, k = i >> 2;
      int col = cb*4 + j;
      Wi[j*WIS + k] = (col < IFC) ? Wif[(size_t)k*IFC + col] : 0.f;
    }
    if (tid < 512) {
      int e2 = tid >> 4, j = tid & 15;
      int gc = (j >> 2)*512 + cb*4 + (j & 3);
      zh[tid] = Xproj[((size_t)e2*TT + 0)*ZD + gc];
    }
    if (tid < 128) cst[tid] = 0.f;
    __syncthreads();
    // gates t=0 (h_prev=0, c_prev=0, reads_prev=0 => z = Xproj)
    if (tid < 128) {
      int e2 = tid >> 2, d = tid & 3;
      float zi = zh[e2*16 + d], zf = zh[e2*16 + 4 + d];
      float zg = zh[e2*16 + 8 + d], zo = zh[e2*16 + 12 + d];
      float cn = sig_(zi)*tanhf(zg);              // f*0 dropped
      float hn = sig_(zo)*tanhf(cn);
      cst[tid] = cn; hl[tid] = hn;
    }
    __syncthreads();
    if (tid < 64) {
      int e2 = tid >> 1, p = tid & 1;
      float2 hv = { hl[e2*4 + 2*p], hl[e2*4 + 2*p + 1] };
      st2(&Uh[(size_t)0*UHT + e2*768 + 256 + cb*4 + 2*p], hv);
    }
    gbar(flags, ++gen);   // bar_a(0)

    for (int t = 0; t < TT; ++t) {
      const size_t uhb = (size_t)t*UHT;
      // stage h(t) — plain cached float4 loads of fresh per-t region
      for (int i = tid; i < 4096; i += 1024) {
        int e2 = i >> 7, q4 = (i & 127) * 4;
        *(float4*)&us[e2*USS + q4] = *(const float4*)&Uh[uhb + e2*768 + 256 + q4];
      }
      __syncthreads();
      // v slice: 4 cols, K=512
      if (tid < 512) {
        float accI[4] = {0,0,0,0};
        int e2 = tid >> 4, ks = tid & 15;
#pragma unroll
        for (int g = 0; g < 8; ++g) {
          int kk = g*64 + ks*4;
          float4 u4 = *(const float4*)&us[e2*USS + kk];
#pragma unroll
          for (int j = 0; j < 4; ++j) {
            float4 w4 = *(const float4*)&Wi[j*WIS + kk];
            accI[j] += D4(u4,w4);
          }
        }
#pragma unroll
        for (int j = 0; j < 4; ++j) {
          float a = accI[j];
          a += __shfl_xor(a,1); a += __shfl_xor(a,2); a += __shfl_xor(a,4); a += __shfl_xor(a,8);
          accI[j] = a;
        }
        if (ks == 0) {
          int c0 = cb*4;
          float* vrow = Vh + (size_t)t*VHT + e2*480;
          if (c0+1 < IFC) { float2 vv = {bif[c0]+accI[0], bif[c0+1]+accI[1]}; st2(&vrow[c0], vv); }
          else if (c0 < IFC) st1(&vrow[c0], bif[c0]+accI[0]);
          if (c0+3 < IFC) { float2 vv = {bif[c0+2]+accI[2], bif[c0+3]+accI[3]}; st2(&vrow[c0+2], vv); }
          else if (c0+2 < IFC) st1(&vrow[c0+2], bif[c0+2]+accI[2]);
        }
      }
      gbar(flags, ++gen);   // bar_b (v published)
      if (t+1 < TT) {
        // zh(t+1) = Xproj(t+1) + h(t)@Wh — overlaps state's DNC chain
        if (tid < 512) {
          int e2 = tid >> 4, j = tid & 15;
          int gc = (j >> 2)*512 + cb*4 + (j & 3);
          zh[tid] = Xproj[((size_t)e2*TT + t+1)*ZD + gc];
        }
        __syncthreads();
        float acc[4][4] = {};
        zgemm(Ws, us, 256, 4, acc);
        zreduce(acc);
        int tile = tid >> 5, s = tid & 31;
        int e0 = (tile >> 2)*4, jj = (tile & 3)*4;
        if (s == 0) {
#pragma unroll
          for (int i = 0; i < 4; ++i)
#pragma unroll
            for (int j = 0; j < 4; ++j)
              zh[(e0+i)*16 + jj + j] += acc[i][j];
        }
      }
      gbar(flags, ++gen);   // bar_c (reads(t) visible)
      if (t+1 < TT) {
        // stage reads(t)
        for (int i = tid; i < 2048; i += 1024) {
          int e2 = i >> 6, q4 = (i & 63) * 4;
          *(float4*)&us[e2*USS + q4] = *(const float4*)&Uh[uhb + e2*768 + q4];
        }
        __syncthreads();
        float acc[4][4] = {};
        zgemm(Ws, us, 0, 2, acc);
        zreduce(acc);
        int tile = tid >> 5, s = tid & 31;
        int e0 = (tile >> 2)*4, jj = (tile & 3)*4;
        if (s == 0) {
#pragma unroll
          for (int i = 0; i < 4; ++i)
#pragma unroll
            for (int j = 0; j < 4; ++j)
              zh[(e0+i)*16 + jj + j] += acc[i][j];
        }
        __syncthreads();
        // gates -> h(t+1), c update (block-local)
        if (tid < 128) {
          int e2 = tid >> 2, d = tid & 3;
          float zi = zh[e2*16 + d], zf = zh[e2*16 + 4 + d];
          float zg = zh[e2*16 + 8 + d], zo = zh[e2*16 + 12 + d];
          float cn = sig_(zf)*cst[tid] + sig_(zi)*tanhf(zg);
          float hn = sig_(zo)*tanhf(cn);
          cst[tid] = cn; hl[tid] = hn;
        }
        __syncthreads();
        if (tid < 64) {
          int e2 = tid >> 1, p = tid & 1;
          float2 hv = { hl[e2*4 + 2*p], hl[e2*4 + 2*p + 1] };
          st2(&Uh[(size_t)(t+1)*UHT + e2*768 + 256 + cb*4 + 2*p], hv);
        }
      }
      gbar(flags, ++gen);   // bar_a(t+1)
    }
  }
}

extern "C" void kernel_launch(void* const* d_in, const int* in_sizes, int n_in,
                              void* d_out, int out_size, void* d_ws, size_t ws_size,
                              hipStream_t stream) {
  const float* x   = (const float*)d_in[0];
  const float* Wx  = (const float*)d_in[1];
  const float* Wh  = (const float*)d_in[2];
  const float* bl  = (const float*)d_in[3];
  const float* Wif = (const float*)d_in[4];
  const float* bif = (const float*)d_in[5];
  const float* Wo  = (const float*)d_in[6];
  const float* bo  = (const float*)d_in[7];
  float* out = (float*)d_out;

  float* Xp = (float*)d_ws;                         // 4096*2048       = 8388608
  float* Uh = Xp + (size_t)4096*2048;               // 128*UHT         = 3153920
  float* Vh = Uh + (size_t)TT*UHT;                  // 128*VHT         = 1974272
  unsigned* fl = (unsigned*)(Vh + (size_t)TT*VHT);  // 256
  // total ~54.1 MB

  // 1) Xproj = x @ Wx[:512] + b_lstm
  gemm_bias<<<dim3(2048/64, 4096/64), dim3(256), 0, stream>>>(x, Wx, bl, Xp, 2048, 512);

  // 2) flags
  init_flags<<<dim3(1), dim3(256), 0, stream>>>(fl);

  // 3) cooperative weight-stationary recurrent core
  const int smem_bytes = CL_TOT * 4;  // 126784
  hipFuncSetAttribute((const void*)dnc_coop, hipFuncAttributeMaxDynamicSharedMemorySize, smem_bytes);
  void* args[] = { (void*)&Xp, (void*)&Wx, (void*)&Wh, (void*)&Wif, (void*)&bif,
                   (void*)&Uh, (void*)&Vh, (void*)&fl };
  hipLaunchCooperativeKernel((void*)dnc_coop, dim3(NBLK), dim3(1024), args,
                             (unsigned int)smem_bytes, stream);

  // 4) out = [reads,h] @ W_out + b_out  (reads Uh directly, remaps rows)
  gemm_out<<<dim3(512/64, 4096/64), dim3(256), 0, stream>>>(Uh, Wo, bo, out);
}

// Round 5
// 5946.544 us; speedup vs baseline: 3.7418x; 1.1116x over previous
//
#include <hip/hip_runtime.h>
#include <math.h>

#define TT 128
#define ZD 2048
#define IFC 471
#define EPSF 1e-6f
#define MST 68      // M LDS row stride
#define LST 132     // link LDS row stride
#define NBLK 160
#define UHT 24640   // per-t stride of Uh: 32*768 + 64 guard floats
#define VHT 15424   // per-t stride of Vh: 32*480 + 64 guard floats
#define USS 516     // staged activation LDS row stride
#define WSS 772     // z weight slice LDS row stride
#define WIS 516     // iface weight slice LDS row stride

#define D4(a,b) ((a).x*(b).x + (a).y*(b).y + (a).z*(b).z + (a).w*(b).w)

__device__ __forceinline__ float sig_(float x){ return 1.f/(1.f+expf(-x)); }
__device__ __forceinline__ float sp_(float x){ return fmaxf(x,0.f)+log1pf(expf(-fabsf(x))); }

// -------- agent-scope (write-through, cache-bypassing) publishes --------
__device__ __forceinline__ void st1(float* p, float v){
  unsigned u; __builtin_memcpy(&u,&v,4);
  __hip_atomic_store((unsigned*)p, u, __ATOMIC_RELAXED, __HIP_MEMORY_SCOPE_AGENT);
}
__device__ __forceinline__ void st2(float* p, float2 v){
  unsigned long long u; __builtin_memcpy(&u,&v,8);
  __hip_atomic_store((unsigned long long*)p, u, __ATOMIC_RELAXED, __HIP_MEMORY_SCOPE_AGENT);
}

// -------- fence-free all-report/all-check barrier: wave 0 polls ----------
// Flag store is RELAXED (not RELEASE): RELEASE at agent scope emits
// buffer_wbl2 sc1 (whole-L2 dirty writeback) per call — measured as the
// ~4 MB/barrier WRITE_SIZE storm in round 4. Ordering is already provided
// by __syncthreads(): the compiler emits s_waitcnt vmcnt(0) before
// s_barrier, so every wave's agent-scope data stores have reached the
// coherent point before any wave can reach the flag store.
__device__ __forceinline__ void gbar(unsigned* flags, unsigned gen){
  __syncthreads();
  if (threadIdx.x == 0)
    __hip_atomic_store(&flags[blockIdx.x], gen, __ATOMIC_RELAXED, __HIP_MEMORY_SCOPE_AGENT);
  if (threadIdx.x < 64){
    for (int f = threadIdx.x; f < NBLK; f += 64){
      while (__hip_atomic_load(&flags[f], __ATOMIC_RELAXED, __HIP_MEMORY_SCOPE_AGENT) < gen)
        __builtin_amdgcn_s_sleep(2);
    }
  }
  __syncthreads();
}

// ---------------- GEMM #1: C[M,N] = A[M,K] @ B[K,N] + bias[N]
__global__ __launch_bounds__(256) void gemm_bias(
    const float* __restrict__ A, const float* __restrict__ B,
    const float* __restrict__ bias, float* __restrict__ C,
    int Nc, int K)
{
  __shared__ float As[16][68];
  __shared__ float Bs[16][68];
  const int tid = threadIdx.x;
  const int bx = blockIdx.x, by = blockIdx.y;
  const int tx = tid & 15, ty = tid >> 4;
  const int am = tid >> 2, ak = (tid & 3) * 4;
  const int bk = tid >> 4, bn = (tid & 15) * 4;
  float acc[4][4] = {};
  const float* Ap = A + (size_t)(by*64+am)*K + ak;
  const float* Bp = B + (size_t)bk*Nc + bx*64 + bn;
  for (int k0 = 0; k0 < K; k0 += 16) {
    float4 av = *(const float4*)Ap; Ap += 16;
    float4 bv = *(const float4*)Bp; Bp += (size_t)16*Nc;
    As[ak+0][am]=av.x; As[ak+1][am]=av.y; As[ak+2][am]=av.z; As[ak+3][am]=av.w;
    *(float4*)&Bs[bk][bn] = bv;
    __syncthreads();
#pragma unroll
    for (int kk = 0; kk < 16; ++kk) {
      float4 a4 = *(const float4*)&As[kk][ty*4];
      float4 b4 = *(const float4*)&Bs[kk][tx*4];
      acc[0][0]+=a4.x*b4.x; acc[0][1]+=a4.x*b4.y; acc[0][2]+=a4.x*b4.z; acc[0][3]+=a4.x*b4.w;
      acc[1][0]+=a4.y*b4.x; acc[1][1]+=a4.y*b4.y; acc[1][2]+=a4.y*b4.z; acc[1][3]+=a4.y*b4.w;
      acc[2][0]+=a4.z*b4.x; acc[2][1]+=a4.z*b4.y; acc[2][2]+=a4.z*b4.z; acc[2][3]+=a4.z*b4.w;
      acc[3][0]+=a4.w*b4.x; acc[3][1]+=a4.w*b4.y; acc[3][2]+=a4.w*b4.z; acc[3][3]+=a4.w*b4.w;
    }
    __syncthreads();
  }
  float4 bb = *(const float4*)(bias + bx*64 + tx*4);
#pragma unroll
  for (int i = 0; i < 4; ++i) {
    float4 o;
    o.x = acc[i][0]+bb.x; o.y = acc[i][1]+bb.y; o.z = acc[i][2]+bb.z; o.w = acc[i][3]+bb.w;
    *(float4*)(C + (size_t)(by*64+ty*4+i)*Nc + bx*64 + tx*4) = o;
  }
}

// ---------------- GEMM #2 (output): A rows live in Uh[t][e] layout.
__global__ __launch_bounds__(256) void gemm_out(
    const float* __restrict__ A, const float* __restrict__ B,
    const float* __restrict__ bias, float* __restrict__ C)
{
  __shared__ float As[16][68];
  __shared__ float Bs[16][68];
  const int tid = threadIdx.x;
  const int bx = blockIdx.x, by = blockIdx.y;
  const int tx = tid & 15, ty = tid >> 4;
  const int am = tid >> 2, ak = (tid & 3) * 4;
  const int bk = tid >> 4, bn = (tid & 15) * 4;
  float acc[4][4] = {};
  const int arow = by*64 + am;
  const float* Ap = A + (size_t)(arow >> 5)*UHT + (size_t)(arow & 31)*768 + ak;
  const float* Bp = B + (size_t)bk*512 + bx*64 + bn;
  for (int k0 = 0; k0 < 768; k0 += 16) {
    float4 av = *(const float4*)Ap; Ap += 16;
    float4 bv = *(const float4*)Bp; Bp += (size_t)16*512;
    As[ak+0][am]=av.x; As[ak+1][am]=av.y; As[ak+2][am]=av.z; As[ak+3][am]=av.w;
    *(float4*)&Bs[bk][bn] = bv;
    __syncthreads();
#pragma unroll
    for (int kk = 0; kk < 16; ++kk) {
      float4 a4 = *(const float4*)&As[kk][ty*4];
      float4 b4 = *(const float4*)&Bs[kk][tx*4];
      acc[0][0]+=a4.x*b4.x; acc[0][1]+=a4.x*b4.y; acc[0][2]+=a4.x*b4.z; acc[0][3]+=a4.x*b4.w;
      acc[1][0]+=a4.y*b4.x; acc[1][1]+=a4.y*b4.y; acc[1][2]+=a4.y*b4.z; acc[1][3]+=a4.y*b4.w;
      acc[2][0]+=a4.z*b4.x; acc[2][1]+=a4.z*b4.y; acc[2][2]+=a4.z*b4.z; acc[2][3]+=a4.z*b4.w;
      acc[3][0]+=a4.w*b4.x; acc[3][1]+=a4.w*b4.y; acc[3][2]+=a4.w*b4.z; acc[3][3]+=a4.w*b4.w;
    }
    __syncthreads();
  }
  float4 bb = *(const float4*)(bias + bx*64 + tx*4);
#pragma unroll
  for (int i = 0; i < 4; ++i) {
    int row = by*64 + ty*4 + i;
    int crow = (row & 31)*128 + (row >> 5);   // (e,t) -> e*128+t
    float4 o;
    o.x = acc[i][0]+bb.x; o.y = acc[i][1]+bb.y; o.z = acc[i][2]+bb.z; o.w = acc[i][3]+bb.w;
    *(float4*)(C + (size_t)crow*512 + bx*64 + tx*4) = o;
  }
}

// ---------------- state-block LDS layout (floats)
#define SL_L    0
#define SL_M    16896
#define SL_V    25600
#define SL_WR   26080
#define SL_FW   26592
#define SL_BW   27104
#define SL_CR   27616
#define SL_USG  28128
#define SL_PRC  28256
#define SL_WW   28384
#define SL_SU   28512
#define SL_CPX  28640
#define SL_MN   28768
#define SL_SW   28896
#define SL_CW   29024
#define SL_RNK  29152
#define SL_MSC  29280
#define SL_ER   29344
#define SL_WV   29408
#define SL_TOT  29472

// ---------------- col-block LDS layout (floats)
#define CL_WS  0                      // Ws [16][772] = 12352
#define CL_WI  12352                  // Wi [4][516]  = 2064
#define CL_US  14416                  // us [32][516] = 16512
#define CL_ZH  30928                  // zh [512]
#define CL_CS  31440                  // c  [128]
#define CL_HL  31568                  // h  [128]
#define CL_TOT 31696                  // 126784 bytes

__device__ __forceinline__ void zgemm(const float* Ws, const float* us, int wofs,
                                      int giters, float acc[4][4]) {
  const int tid = threadIdx.x;
  const int tile = tid >> 5, s = tid & 31;
  const int e0 = (tile >> 2)*4, jj = (tile & 3)*4;
  for (int g = 0; g < giters; ++g) {
    int kk = g*128 + s*4;
    float4 u0 = *(const float4*)&us[(e0+0)*USS + kk];
    float4 u1 = *(const float4*)&us[(e0+1)*USS + kk];
    float4 u2 = *(const float4*)&us[(e0+2)*USS + kk];
    float4 u3 = *(const float4*)&us[(e0+3)*USS + kk];
    float4 w0 = *(const float4*)&Ws[(jj+0)*WSS + wofs + kk];
    float4 w1 = *(const float4*)&Ws[(jj+1)*WSS + wofs + kk];
    float4 w2 = *(const float4*)&Ws[(jj+2)*WSS + wofs + kk];
    float4 w3 = *(const float4*)&Ws[(jj+3)*WSS + wofs + kk];
    acc[0][0]+=D4(u0,w0); acc[0][1]+=D4(u0,w1); acc[0][2]+=D4(u0,w2); acc[0][3]+=D4(u0,w3);
    acc[1][0]+=D4(u1,w0); acc[1][1]+=D4(u1,w1); acc[1][2]+=D4(u1,w2); acc[1][3]+=D4(u1,w3);
    acc[2][0]+=D4(u2,w0); acc[2][1]+=D4(u2,w1); acc[2][2]+=D4(u2,w2); acc[2][3]+=D4(u2,w3);
    acc[3][0]+=D4(u3,w0); acc[3][1]+=D4(u3,w1); acc[3][2]+=D4(u3,w2); acc[3][3]+=D4(u3,w3);
  }
}

__device__ __forceinline__ void zreduce(float acc[4][4]) {
#pragma unroll
  for (int i = 0; i < 4; ++i)
#pragma unroll
    for (int j = 0; j < 4; ++j) {
      float a = acc[i][j];
      a += __shfl_xor(a, 1); a += __shfl_xor(a, 2); a += __shfl_xor(a, 4);
      a += __shfl_xor(a, 8); a += __shfl_xor(a, 16);
      acc[i][j] = a;
    }
}

__global__ void init_flags(unsigned* flags) {
  if (threadIdx.x < 256)
    __hip_atomic_store(&flags[threadIdx.x], 0u, __ATOMIC_RELAXED, __HIP_MEMORY_SCOPE_AGENT);
}

__global__ __launch_bounds__(1024) void dnc_coop(
    const float* __restrict__ Xproj, const float* __restrict__ Wx,
    const float* __restrict__ Wh, const float* __restrict__ Wif,
    const float* __restrict__ bif,
    float* __restrict__ Uh, float* __restrict__ Vh,
    unsigned* __restrict__ flags)
{
  const int blk = blockIdx.x, tid = threadIdx.x;
  extern __shared__ float sm[];
  unsigned gen = 0;

  if (blk < 32) {
    // ================= STATE BLOCK (one example) =================
    const int e = blk;
    float* L   = sm + SL_L;   float* Ms  = sm + SL_M;
    float* v   = sm + SL_V;   float* wr  = sm + SL_WR;
    float* fw  = sm + SL_FW;  float* bw  = sm + SL_BW;
    float* cr  = sm + SL_CR;  float* usg = sm + SL_USG;
    float* prc = sm + SL_PRC; float* ww  = sm + SL_WW;
    float* su  = sm + SL_SU;  float* cpx = sm + SL_CPX;
    float* Mn  = sm + SL_MN;  float* swv = sm + SL_SW;
    float* cw  = sm + SL_CW;  int*   rnk = (int*)(sm + SL_RNK);
    float* msc = sm + SL_MSC; float* er_ = sm + SL_ER; float* wv_ = sm + SL_WV;

    for (int i = tid; i < SL_TOT; i += 1024) sm[i] = 0.f;
    gbar(flags, ++gen);   // bar_a(0)

    for (int t = 0; t < TT; ++t) {
      gbar(flags, ++gen);   // bar_b: v(t) visible
      // A: v copy (plain cached loads from fresh per-t region)
      if (tid < IFC) v[tid] = Vh[(size_t)t*VHT + e*480 + tid];
      __syncthreads();
      // B: usage update / write sim / key norms / modes / erase-write prep
      if (tid < 128) {
        float ret = 1.f;
#pragma unroll
        for (int r = 0; r < 4; ++r) { float fr = sig_(v[453+r]); ret *= 1.f - fr*wr[r*128+tid]; }
        float u = usg[tid], w_ = ww[tid];
        usg[tid] = (u + w_ - u*w_) * ret;
      } else if (tid < 256) {
        int n = tid - 128; float nk = 0.f, dot = 0.f;
#pragma unroll
        for (int w = 0; w < 64; w += 4) {
          float4 k4 = *(float4*)&v[260+w];
          float4 m4 = *(float4*)&Ms[n*MST+w];
          nk += D4(k4,k4); dot += D4(m4,k4);
        }
        float beta = 1.f + sp_(v[324]);
        swv[n] = beta * dot / ((Mn[n]+EPSF)*(sqrtf(nk)+EPSF));
      } else if (tid < 260) {
        int r = tid - 256; float s = 0.f;
#pragma unroll
        for (int w = 0; w < 64; w += 4) { float4 k4 = *(float4*)&v[r*64+w]; s += D4(k4,k4); }
        msc[1+r] = sqrtf(s);
      } else if (tid == 260) {
        for (int r = 0; r < 4; ++r) {
          float a0 = v[459+r*3], a1 = v[459+r*3+1], a2 = v[459+r*3+2];
          float mx = fmaxf(a0, fmaxf(a1, a2));
          float e0 = expf(a0-mx), e1 = expf(a1-mx), e2 = expf(a2-mx);
          float dn = e0+e1+e2;
          msc[8+r*3] = e0/dn; msc[8+r*3+1] = e1/dn; msc[8+r*3+2] = e2/dn;
        }
      } else if (tid >= 640 && tid < 704) { int w = tid-640; er_[w] = sig_(v[325+w]); }
      else if (tid >= 704 && tid < 768) { int w = tid-704; wv_[w] = v[389+w]; }
      __syncthreads();
      // C: stable-ascending rank + write softmax
      if (tid < 128) {
        float ui = usg[tid]; int rk = 0;
        for (int j = 0; j < 128; ++j) {
          float uj = usg[j];
          rk += (uj < ui || (uj == ui && j < tid)) ? 1 : 0;
        }
        rnk[tid] = rk; su[rk] = ui;
      } else if (tid < 192) {
        int l = tid - 128;
        float s1 = swv[l], s2 = swv[l+64];
        float m = fmaxf(s1, s2);
#pragma unroll
        for (int o = 32; o > 0; o >>= 1) m = fmaxf(m, __shfl_xor(m, o));
        float e1 = expf(s1-m), e2 = expf(s2-m);
        float dn = e1 + e2;
#pragma unroll
        for (int o = 32; o > 0; o >>= 1) dn += __shfl_xor(dn, o);
        cw[l] = e1/dn; cw[l+64] = e2/dn;
      }
      __syncthreads();
      // D: exclusive cumprod via wave scan
      if (tid < 64) {
        float a0 = su[2*tid], a1 = su[2*tid+1];
        float p = a0*a1, sc = p;
#pragma unroll
        for (int off = 1; off < 64; off <<= 1) {
          float o = __shfl_up(sc, off);
          if ((int)tid >= off) sc *= o;
        }
        float ex = __shfl_up(sc, 1);
        if (tid == 0) ex = 1.f;
        cpx[2*tid] = ex;
        cpx[2*tid+1] = ex*a0;
      }
      __syncthreads();
      // E: ww_n
      if (tid < 128) {
        float a_i = (1.f - usg[tid]) * cpx[rnk[tid]];
        float ag = sig_(v[457]), wg = sig_(v[458]);
        ww[tid] = wg * (ag*a_i + (1.f-ag)*cw[tid]);
      }
      __syncthreads();
      // F: M erase/write + link update (old prec)
      {
        int n = tid >> 3, q = tid & 7;
        float wwn = ww[n];
        int w8 = q*8;
#pragma unroll
        for (int g = 0; g < 2; ++g) {
          int w = w8 + g*4;
          float4 m = *(float4*)&Ms[n*MST+w];
          float4 e4 = *(float4*)&er_[w];
          float4 v4 = *(float4*)&wv_[w];
          m.x = m.x*(1.f - wwn*e4.x) + wwn*v4.x;
          m.y = m.y*(1.f - wwn*e4.y) + wwn*v4.y;
          m.z = m.z*(1.f - wwn*e4.z) + wwn*v4.z;
          m.w = m.w*(1.f - wwn*e4.w) + wwn*v4.w;
          *(float4*)&Ms[n*MST+w] = m;
        }
        int j16 = q*16;
#pragma unroll
        for (int g = 0; g < 4; ++g) {
          int j = j16 + g*4;
          float4 lv = *(float4*)&L[n*LST + j];
          float4 p4 = *(float4*)&prc[j];
          float4 w4 = *(float4*)&ww[j];
          lv.x = (1.f - wwn - w4.x)*lv.x + wwn*p4.x;
          lv.y = (1.f - wwn - w4.y)*lv.y + wwn*p4.y;
          lv.z = (1.f - wwn - w4.z)*lv.z + wwn*p4.z;
          lv.w = (1.f - wwn - w4.w)*lv.w + wwn*p4.w;
          int d = n - j;
          if (d >= 0 && d < 4) ((float*)&lv)[d] = 0.f;
          *(float4*)&L[n*LST + j] = lv;
        }
      }
      __syncthreads();
      // G: sum(ww) + new M norms
      if (tid < 64) {
        float s = ww[tid] + ww[tid+64];
#pragma unroll
        for (int o = 32; o > 0; o >>= 1) s += __shfl_xor(s, o);
        if (tid == 0) msc[0] = s;
      } else if (tid < 192) {
        int n = tid - 64; float s = 0.f;
#pragma unroll
        for (int w = 0; w < 64; w += 4) { float4 m = *(float4*)&Ms[n*MST+w]; s += D4(m,m); }
        Mn[n] = sqrtf(s);
      }
      __syncthreads();
      // H: fw/bw = link_n · wr_prev
      if (tid < 256) {
        int half = tid >> 7, t2 = tid & 127;
        int i0 = (t2 >> 2) * 4, sg = t2 & 3;
        float4 av[4] = {{0,0,0,0},{0,0,0,0},{0,0,0,0},{0,0,0,0}};
        if (half == 0) {
#pragma unroll
          for (int m = 0; m < 8; ++m) {
            int j = sg*4 + m*16;
            float4 w0 = *(float4*)&wr[0*128+j];
            float4 w1 = *(float4*)&wr[1*128+j];
            float4 w2 = *(float4*)&wr[2*128+j];
            float4 w3 = *(float4*)&wr[3*128+j];
            float4 l0 = *(float4*)&L[(i0+0)*LST+j];
            float4 l1 = *(float4*)&L[(i0+1)*LST+j];
            float4 l2 = *(float4*)&L[(i0+2)*LST+j];
            float4 l3 = *(float4*)&L[(i0+3)*LST+j];
            av[0].x+=D4(l0,w0); av[0].y+=D4(l1,w0); av[0].z+=D4(l2,w0); av[0].w+=D4(l3,w0);
            av[1].x+=D4(l0,w1); av[1].y+=D4(l1,w1); av[1].z+=D4(l2,w1); av[1].w+=D4(l3,w1);
            av[2].x+=D4(l0,w2); av[2].y+=D4(l1,w2); av[2].z+=D4(l2,w2); av[2].w+=D4(l3,w2);
            av[3].x+=D4(l0,w3); av[3].y+=D4(l1,w3); av[3].z+=D4(l2,w3); av[3].w+=D4(l3,w3);
          }
        } else {
#pragma unroll
          for (int m = 0; m < 32; ++m) {
            int j = sg + m*4;
            float4 lv = *(float4*)&L[j*LST + i0];
            float w0 = wr[j], w1 = wr[128+j], w2 = wr[256+j], w3 = wr[384+j];
            av[0].x+=w0*lv.x; av[0].y+=w0*lv.y; av[0].z+=w0*lv.z; av[0].w+=w0*lv.w;
            av[1].x+=w1*lv.x; av[1].y+=w1*lv.y; av[1].z+=w1*lv.z; av[1].w+=w1*lv.w;
            av[2].x+=w2*lv.x; av[2].y+=w2*lv.y; av[2].z+=w2*lv.z; av[2].w+=w2*lv.w;
            av[3].x+=w3*lv.x; av[3].y+=w3*lv.y; av[3].z+=w3*lv.z; av[3].w+=w3*lv.w;
          }
        }
#pragma unroll
        for (int r = 0; r < 4; ++r) {
          av[r].x += __shfl_xor(av[r].x,1); av[r].x += __shfl_xor(av[r].x,2);
          av[r].y += __shfl_xor(av[r].y,1); av[r].y += __shfl_xor(av[r].y,2);
          av[r].z += __shfl_xor(av[r].z,1); av[r].z += __shfl_xor(av[r].z,2);
          av[r].w += __shfl_xor(av[r].w,1); av[r].w += __shfl_xor(av[r].w,2);
        }
        if (sg == 0) {
          float* dst = half ? bw : fw;
#pragma unroll
          for (int r = 0; r < 4; ++r) {
            dst[r*128 + i0+0] = av[r].x; dst[r*128 + i0+1] = av[r].y;
            dst[r*128 + i0+2] = av[r].z; dst[r*128 + i0+3] = av[r].w;
          }
        }
      }
      __syncthreads();
      // I: prec update + read sims (new M)
      if (tid < 128) {
        prc[tid] = (1.f - msc[0])*prc[tid] + ww[tid];
      } else if (tid >= 512) {
        int r = (tid >> 7) & 3, n = tid & 127;
        float dot = 0.f;
#pragma unroll
        for (int w = 0; w < 64; w += 4) {
          float4 m4 = *(float4*)&Ms[n*MST+w];
          float4 k4 = *(float4*)&v[r*64+w];
          dot += D4(m4,k4);
        }
        float beta = 1.f + sp_(v[256+r]);
        cr[r*128+n] = beta * dot / ((Mn[n]+EPSF)*(msc[1+r]+EPSF));
      }
      __syncthreads();
      // J: per-head read softmax
      if (tid < 256) {
        int r = tid >> 6, l = tid & 63;
        float s1 = cr[r*128+l], s2 = cr[r*128+l+64];
        float m = fmaxf(s1, s2);
#pragma unroll
        for (int o = 32; o > 0; o >>= 1) m = fmaxf(m, __shfl_xor(m, o));
        float e1 = expf(s1-m), e2 = expf(s2-m);
        float dn = e1 + e2;
#pragma unroll
        for (int o = 32; o > 0; o >>= 1) dn += __shfl_xor(dn, o);
        cr[r*128+l] = e1/dn; cr[r*128+l+64] = e2/dn;
      }
      __syncthreads();
      // K: wr_n
      if (tid < 512) {
        int r = tid >> 7;
        wr[tid] = msc[8+r*3]*bw[tid] + msc[8+r*3+1]*cr[tid] + msc[8+r*3+2]*fw[tid];
      }
      __syncthreads();
      // L: reads_n = wr_n @ M_n, publish to Uh[t]
      if (tid < 512) {
        int r = tid >> 7, t2 = tid & 127;
        int w0 = (t2 >> 3) * 4, ns = t2 & 7;
        float4 a = {0,0,0,0};
#pragma unroll
        for (int m = 0; m < 16; ++m) {
          int n = ns + m*8;
          float4 mr = *(float4*)&Ms[n*MST + w0];
          float wv = wr[r*128 + n];
          a.x += wv*mr.x; a.y += wv*mr.y; a.z += wv*mr.z; a.w += wv*mr.w;
        }
        a.x += __shfl_xor(a.x,1); a.x += __shfl_xor(a.x,2); a.x += __shfl_xor(a.x,4);
        a.y += __shfl_xor(a.y,1); a.y += __shfl_xor(a.y,2); a.y += __shfl_xor(a.y,4);
        a.z += __shfl_xor(a.z,1); a.z += __shfl_xor(a.z,2); a.z += __shfl_xor(a.z,4);
        a.w += __shfl_xor(a.w,1); a.w += __shfl_xor(a.w,2); a.w += __shfl_xor(a.w,4);
        if (ns == 0) {
          int o = r*64 + w0;
          float2 lo = {a.x, a.y}, hi = {a.z, a.w};
          st2(&Uh[(size_t)t*UHT + e*768 + o], lo);
          st2(&Uh[(size_t)t*UHT + e*768 + o + 2], hi);
        }
      }
      gbar(flags, ++gen);   // bar_c: reads(t) published
      gbar(flags, ++gen);   // bar_a(t+1): h(t+1) published by col-blocks
    }
  } else {
    // ======== COL BLOCK: z-cols {q*512 + cb*4 + d} + 4 iface cols ========
    const int cb = blk - 32;
    float* Ws = sm + CL_WS;
    float* Wi = sm + CL_WI;
    float* us = sm + CL_US;
    float* zh = sm + CL_ZH;
    float* cst= sm + CL_CS;
    float* hl = sm + CL_HL;
    // load weight slices (once)
    for (int i = tid; i < 16*768; i += 1024) {
      int j = i & 15, k = i >> 4;
      int gc = (j >> 2)*512 + cb*4 + (j & 3);
      Ws[j*WSS + k] = (k < 256) ? Wx[(size_t)(512+k)*ZD + gc]
                                : Wh[(size_t)(k-256)*ZD + gc];
    }
    for (int i = tid; i < 4*512; i += 1024) {
      int j = i & 3, k = i >> 2;
      int col = cb*4 + j;
      Wi[j*WIS + k] = (col < IFC) ? Wif[(size_t)k*IFC + col] : 0.f;
    }
    if (tid < 512) {
      int e2 = tid >> 4, j = tid & 15;
      int gc = (j >> 2)*512 + cb*4 + (j & 3);
      zh[tid] = Xproj[((size_t)e2*TT + 0)*ZD + gc];
    }
    if (tid < 128) cst[tid] = 0.f;
    __syncthreads();
    // gates t=0 (h_prev=0, c_prev=0, reads_prev=0 => z = Xproj)
    if (tid < 128) {
      int e2 = tid >> 2, d = tid & 3;
      float zi = zh[e2*16 + d];
      float zg = zh[e2*16 + 8 + d], zo = zh[e2*16 + 12 + d];
      float cn = sig_(zi)*tanhf(zg);              // f*0 dropped
      float hn = sig_(zo)*tanhf(cn);
      cst[tid] = cn; hl[tid] = hn;
    }
    __syncthreads();
    if (tid < 64) {
      int e2 = tid >> 1, p = tid & 1;
      float2 hv = { hl[e2*4 + 2*p], hl[e2*4 + 2*p + 1] };
      st2(&Uh[(size_t)0*UHT + e2*768 + 256 + cb*4 + 2*p], hv);
    }
    gbar(flags, ++gen);   // bar_a(0)

    for (int t = 0; t < TT; ++t) {
      const size_t uhb = (size_t)t*UHT;
      // stage h(t) — plain cached float4 loads of fresh per-t region
      for (int i = tid; i < 4096; i += 1024) {
        int e2 = i >> 7, q4 = (i & 127) * 4;
        *(float4*)&us[e2*USS + q4] = *(const float4*)&Uh[uhb + e2*768 + 256 + q4];
      }
      // prefetch Xproj(t+1) into a register — latency hides under v compute
      float xpr = 0.f;
      if (t+1 < TT && tid < 512) {
        int e2 = tid >> 4, j = tid & 15;
        int gc = (j >> 2)*512 + cb*4 + (j & 3);
        xpr = Xproj[((size_t)e2*TT + t+1)*ZD + gc];
      }
      __syncthreads();
      // v slice: 4 cols, K=512
      if (tid < 512) {
        float accI[4] = {0,0,0,0};
        int e2 = tid >> 4, ks = tid & 15;
#pragma unroll
        for (int g = 0; g < 8; ++g) {
          int kk = g*64 + ks*4;
          float4 u4 = *(const float4*)&us[e2*USS + kk];
#pragma unroll
          for (int j = 0; j < 4; ++j) {
            float4 w4 = *(const float4*)&Wi[j*WIS + kk];
            accI[j] += D4(u4,w4);
          }
        }
#pragma unroll
        for (int j = 0; j < 4; ++j) {
          float a = accI[j];
          a += __shfl_xor(a,1); a += __shfl_xor(a,2); a += __shfl_xor(a,4); a += __shfl_xor(a,8);
          accI[j] = a;
        }
        if (ks == 0) {
          int c0 = cb*4;
          float* vrow = Vh + (size_t)t*VHT + e2*480;
          if (c0+1 < IFC) { float2 vv = {bif[c0]+accI[0], bif[c0+1]+accI[1]}; st2(&vrow[c0], vv); }
          else if (c0 < IFC) st1(&vrow[c0], bif[c0]+accI[0]);
          if (c0+3 < IFC) { float2 vv = {bif[c0+2]+accI[2], bif[c0+3]+accI[3]}; st2(&vrow[c0+2], vv); }
          else if (c0+2 < IFC) st1(&vrow[c0+2], bif[c0+2]+accI[2]);
        }
      }
      gbar(flags, ++gen);   // bar_b (v published)
      if (t+1 < TT) {
        // zh(t+1) = Xproj(t+1) + h(t)@Wh — overlaps state's DNC chain
        if (tid < 512) zh[tid] = xpr;
        __syncthreads();
        float acc[4][4] = {};
        zgemm(Ws, us, 256, 4, acc);
        zreduce(acc);
        int tile = tid >> 5, s = tid & 31;
        int e0 = (tile >> 2)*4, jj = (tile & 3)*4;
        if (s == 0) {
#pragma unroll
          for (int i = 0; i < 4; ++i)
#pragma unroll
            for (int j = 0; j < 4; ++j)
              zh[(e0+i)*16 + jj + j] += acc[i][j];
        }
      }
      gbar(flags, ++gen);   // bar_c (reads(t) visible)
      if (t+1 < TT) {
        // stage reads(t)
        for (int i = tid; i < 2048; i += 1024) {
          int e2 = i >> 6, q4 = (i & 63) * 4;
          *(float4*)&us[e2*USS + q4] = *(const float4*)&Uh[uhb + e2*768 + q4];
        }
        __syncthreads();
        float acc[4][4] = {};
        zgemm(Ws, us, 0, 2, acc);
        zreduce(acc);
        int tile = tid >> 5, s = tid & 31;
        int e0 = (tile >> 2)*4, jj = (tile & 3)*4;
        if (s == 0) {
#pragma unroll
          for (int i = 0; i < 4; ++i)
#pragma unroll
            for (int j = 0; j < 4; ++j)
              zh[(e0+i)*16 + jj + j] += acc[i][j];
        }
        __syncthreads();
        // gates -> h(t+1), c update (block-local)
        if (tid < 128) {
          int e2 = tid >> 2, d = tid & 3;
          float zi = zh[e2*16 + d], zf = zh[e2*16 + 4 + d];
          float zg = zh[e2*16 + 8 + d], zo = zh[e2*16 + 12 + d];
          float cn = sig_(zf)*cst[tid] + sig_(zi)*tanhf(zg);
          float hn = sig_(zo)*tanhf(cn);
          cst[tid] = cn; hl[tid] = hn;
        }
        __syncthreads();
        if (tid < 64) {
          int e2 = tid >> 1, p = tid & 1;
          float2 hv = { hl[e2*4 + 2*p], hl[e2*4 + 2*p + 1] };
          st2(&Uh[(size_t)(t+1)*UHT + e2*768 + 256 + cb*4 + 2*p], hv);
        }
      }
      gbar(flags, ++gen);   // bar_a(t+1)
    }
  }
}

extern "C" void kernel_launch(void* const* d_in, const int* in_sizes, int n_in,
                              void* d_out, int out_size, void* d_ws, size_t ws_size,
                              hipStream_t stream) {
  const float* x   = (const float*)d_in[0];
  const float* Wx  = (const float*)d_in[1];
  const float* Wh  = (const float*)d_in[2];
  const float* bl  = (const float*)d_in[3];
  const float* Wif = (const float*)d_in[4];
  const float* bif = (const float*)d_in[5];
  const float* Wo  = (const float*)d_in[6];
  const float* bo  = (const float*)d_in[7];
  float* out = (float*)d_out;

  float* Xp = (float*)d_ws;                         // 4096*2048
  float* Uh = Xp + (size_t)4096*2048;               // 128*UHT
  float* Vh = Uh + (size_t)TT*UHT;                  // 128*VHT
  unsigned* fl = (unsigned*)(Vh + (size_t)TT*VHT);  // 256

  // 1) Xproj = x @ Wx[:512] + b_lstm
  gemm_bias<<<dim3(2048/64, 4096/64), dim3(256), 0, stream>>>(x, Wx, bl, Xp, 2048, 512);

  // 2) flags
  init_flags<<<dim3(1), dim3(256), 0, stream>>>(fl);

  // 3) cooperative weight-stationary recurrent core
  const int smem_bytes = CL_TOT * 4;  // 126784
  hipFuncSetAttribute((const void*)dnc_coop, hipFuncAttributeMaxDynamicSharedMemorySize, smem_bytes);
  void* args[] = { (void*)&Xp, (void*)&Wx, (void*)&Wh, (void*)&Wif, (void*)&bif,
                   (void*)&Uh, (void*)&Vh, (void*)&fl };
  hipLaunchCooperativeKernel((void*)dnc_coop, dim3(NBLK), dim3(1024), args,
                             (unsigned int)smem_bytes, stream);

  // 4) out = [reads,h] @ W_out + b_out  (reads Uh directly, remaps rows)
  gemm_out<<<dim3(512/64, 4096/64), dim3(256), 0, stream>>>(Uh, Wo, bo, out);
}

// Round 6
// 5763.890 us; speedup vs baseline: 3.8604x; 1.0317x over previous
//
#include <hip/hip_runtime.h>
#include <math.h>

#define TT 128
#define ZD 2048
#define IFC 471
#define EPSF 1e-6f
#define MST 68      // M LDS row stride
#define LST 132     // link LDS row stride
#define NBLK 160
#define UHT 24640   // per-t stride of Uh: 32*768 + 64 guard floats
#define VHT 15424   // per-t stride of Vh: 32*480 + 64 guard floats
#define USS 516     // staged activation LDS row stride
#define WSS 772     // z weight slice LDS row stride
#define WIS 516     // iface weight slice LDS row stride

// dataflow flag arrays (unsigned), disjoint cache-line sets
#define FH_OFF 0     // [128] col h arrivals
#define FV_OFF 128   // [128] col v arrivals
#define FR_OFF 256   // [32]  state reads arrivals
#define NFLAGS 512

#define D4(a,b) ((a).x*(b).x + (a).y*(b).y + (a).z*(b).z + (a).w*(b).w)

__device__ __forceinline__ float sig_(float x){ return 1.f/(1.f+expf(-x)); }
__device__ __forceinline__ float sp_(float x){ return fmaxf(x,0.f)+log1pf(expf(-fabsf(x))); }

// -------- agent-scope (write-through, cache-bypassing) publishes --------
__device__ __forceinline__ void st1(float* p, float v){
  unsigned u; __builtin_memcpy(&u,&v,4);
  __hip_atomic_store((unsigned*)p, u, __ATOMIC_RELAXED, __HIP_MEMORY_SCOPE_AGENT);
}
__device__ __forceinline__ void st2(float* p, float2 v){
  unsigned long long u; __builtin_memcpy(&u,&v,8);
  __hip_atomic_store((unsigned long long*)p, u, __ATOMIC_RELAXED, __HIP_MEMORY_SCOPE_AGENT);
}

// -------- dataflow sync: arrive (publish my step counter) / wait (consume) --
// arrive: __syncthreads() drains every wave's vmcnt(0) before s_barrier, so
// all prior agent-scope data stores are at the coherent point before the
// relaxed flag store (same ordering argument rounds 3-5 relied on).
__device__ __forceinline__ void arrive(unsigned* f, unsigned gen){
  __syncthreads();
  if (threadIdx.x == 0)
    __hip_atomic_store(f, gen, __ATOMIC_RELAXED, __HIP_MEMORY_SCOPE_AGENT);
}
// wait_ge: wave 0 polls n flags; other waves park at the syncthreads.
__device__ __forceinline__ void wait_ge(const unsigned* f, int n, unsigned gen){
  if (threadIdx.x < 64){
    for (int i = threadIdx.x; i < n; i += 64){
      while (__hip_atomic_load(&f[i], __ATOMIC_RELAXED, __HIP_MEMORY_SCOPE_AGENT) < gen)
        __builtin_amdgcn_s_sleep(2);
    }
  }
  __syncthreads();
}

// ---------------- GEMM #1: C[M,N] = A[M,K] @ B[K,N] + bias[N]
__global__ __launch_bounds__(256) void gemm_bias(
    const float* __restrict__ A, const float* __restrict__ B,
    const float* __restrict__ bias, float* __restrict__ C,
    int Nc, int K)
{
  __shared__ float As[16][68];
  __shared__ float Bs[16][68];
  const int tid = threadIdx.x;
  const int bx = blockIdx.x, by = blockIdx.y;
  const int tx = tid & 15, ty = tid >> 4;
  const int am = tid >> 2, ak = (tid & 3) * 4;
  const int bk = tid >> 4, bn = (tid & 15) * 4;
  float acc[4][4] = {};
  const float* Ap = A + (size_t)(by*64+am)*K + ak;
  const float* Bp = B + (size_t)bk*Nc + bx*64 + bn;
  for (int k0 = 0; k0 < K; k0 += 16) {
    float4 av = *(const float4*)Ap; Ap += 16;
    float4 bv = *(const float4*)Bp; Bp += (size_t)16*Nc;
    As[ak+0][am]=av.x; As[ak+1][am]=av.y; As[ak+2][am]=av.z; As[ak+3][am]=av.w;
    *(float4*)&Bs[bk][bn] = bv;
    __syncthreads();
#pragma unroll
    for (int kk = 0; kk < 16; ++kk) {
      float4 a4 = *(const float4*)&As[kk][ty*4];
      float4 b4 = *(const float4*)&Bs[kk][tx*4];
      acc[0][0]+=a4.x*b4.x; acc[0][1]+=a4.x*b4.y; acc[0][2]+=a4.x*b4.z; acc[0][3]+=a4.x*b4.w;
      acc[1][0]+=a4.y*b4.x; acc[1][1]+=a4.y*b4.y; acc[1][2]+=a4.y*b4.z; acc[1][3]+=a4.y*b4.w;
      acc[2][0]+=a4.z*b4.x; acc[2][1]+=a4.z*b4.y; acc[2][2]+=a4.z*b4.z; acc[2][3]+=a4.z*b4.w;
      acc[3][0]+=a4.w*b4.x; acc[3][1]+=a4.w*b4.y; acc[3][2]+=a4.w*b4.z; acc[3][3]+=a4.w*b4.w;
    }
    __syncthreads();
  }
  float4 bb = *(const float4*)(bias + bx*64 + tx*4);
#pragma unroll
  for (int i = 0; i < 4; ++i) {
    float4 o;
    o.x = acc[i][0]+bb.x; o.y = acc[i][1]+bb.y; o.z = acc[i][2]+bb.z; o.w = acc[i][3]+bb.w;
    *(float4*)(C + (size_t)(by*64+ty*4+i)*Nc + bx*64 + tx*4) = o;
  }
}

// ---------------- GEMM #2 (output): A rows live in Uh[t][e] layout.
__global__ __launch_bounds__(256) void gemm_out(
    const float* __restrict__ A, const float* __restrict__ B,
    const float* __restrict__ bias, float* __restrict__ C)
{
  __shared__ float As[16][68];
  __shared__ float Bs[16][68];
  const int tid = threadIdx.x;
  const int bx = blockIdx.x, by = blockIdx.y;
  const int tx = tid & 15, ty = tid >> 4;
  const int am = tid >> 2, ak = (tid & 3) * 4;
  const int bk = tid >> 4, bn = (tid & 15) * 4;
  float acc[4][4] = {};
  const int arow = by*64 + am;
  const float* Ap = A + (size_t)(arow >> 5)*UHT + (size_t)(arow & 31)*768 + ak;
  const float* Bp = B + (size_t)bk*512 + bx*64 + bn;
  for (int k0 = 0; k0 < 768; k0 += 16) {
    float4 av = *(const float4*)Ap; Ap += 16;
    float4 bv = *(const float4*)Bp; Bp += (size_t)16*512;
    As[ak+0][am]=av.x; As[ak+1][am]=av.y; As[ak+2][am]=av.z; As[ak+3][am]=av.w;
    *(float4*)&Bs[bk][bn] = bv;
    __syncthreads();
#pragma unroll
    for (int kk = 0; kk < 16; ++kk) {
      float4 a4 = *(const float4*)&As[kk][ty*4];
      float4 b4 = *(const float4*)&Bs[kk][tx*4];
      acc[0][0]+=a4.x*b4.x; acc[0][1]+=a4.x*b4.y; acc[0][2]+=a4.x*b4.z; acc[0][3]+=a4.x*b4.w;
      acc[1][0]+=a4.y*b4.x; acc[1][1]+=a4.y*b4.y; acc[1][2]+=a4.y*b4.z; acc[1][3]+=a4.y*b4.w;
      acc[2][0]+=a4.z*b4.x; acc[2][1]+=a4.z*b4.y; acc[2][2]+=a4.z*b4.z; acc[2][3]+=a4.z*b4.w;
      acc[3][0]+=a4.w*b4.x; acc[3][1]+=a4.w*b4.y; acc[3][2]+=a4.w*b4.z; acc[3][3]+=a4.w*b4.w;
    }
    __syncthreads();
  }
  float4 bb = *(const float4*)(bias + bx*64 + tx*4);
#pragma unroll
  for (int i = 0; i < 4; ++i) {
    int row = by*64 + ty*4 + i;
    int crow = (row & 31)*128 + (row >> 5);   // (e,t) -> e*128+t
    float4 o;
    o.x = acc[i][0]+bb.x; o.y = acc[i][1]+bb.y; o.z = acc[i][2]+bb.z; o.w = acc[i][3]+bb.w;
    *(float4*)(C + (size_t)crow*512 + bx*64 + tx*4) = o;
  }
}

// ---------------- state-block LDS layout (floats)
#define SL_L    0
#define SL_M    16896
#define SL_V    25600
#define SL_WR   26080
#define SL_FW   26592
#define SL_BW   27104
#define SL_CR   27616
#define SL_USG  28128
#define SL_PRC  28256
#define SL_WW   28384
#define SL_SU   28512
#define SL_CPX  28640
#define SL_MN   28768
#define SL_SW   28896
#define SL_CW   29024
#define SL_RNK  29152
#define SL_MSC  29280
#define SL_ER   29344
#define SL_WV   29408
#define SL_TOT  29472

// ---------------- col-block LDS layout (floats)
#define CL_WS  0                      // Ws [16][772] = 12352
#define CL_WI  12352                  // Wi [4][516]  = 2064
#define CL_US  14416                  // us [32][516] = 16512
#define CL_ZH  30928                  // zh [512]
#define CL_CS  31440                  // c  [128]
#define CL_HL  31568                  // h  [128]
#define CL_TOT 31696                  // 126784 bytes

__device__ __forceinline__ void zgemm(const float* Ws, const float* us, int wofs,
                                      int giters, float acc[4][4]) {
  const int tid = threadIdx.x;
  const int tile = tid >> 5, s = tid & 31;
  const int e0 = (tile >> 2)*4, jj = (tile & 3)*4;
  for (int g = 0; g < giters; ++g) {
    int kk = g*128 + s*4;
    float4 u0 = *(const float4*)&us[(e0+0)*USS + kk];
    float4 u1 = *(const float4*)&us[(e0+1)*USS + kk];
    float4 u2 = *(const float4*)&us[(e0+2)*USS + kk];
    float4 u3 = *(const float4*)&us[(e0+3)*USS + kk];
    float4 w0 = *(const float4*)&Ws[(jj+0)*WSS + wofs + kk];
    float4 w1 = *(const float4*)&Ws[(jj+1)*WSS + wofs + kk];
    float4 w2 = *(const float4*)&Ws[(jj+2)*WSS + wofs + kk];
    float4 w3 = *(const float4*)&Ws[(jj+3)*WSS + wofs + kk];
    acc[0][0]+=D4(u0,w0); acc[0][1]+=D4(u0,w1); acc[0][2]+=D4(u0,w2); acc[0][3]+=D4(u0,w3);
    acc[1][0]+=D4(u1,w0); acc[1][1]+=D4(u1,w1); acc[1][2]+=D4(u1,w2); acc[1][3]+=D4(u1,w3);
    acc[2][0]+=D4(u2,w0); acc[2][1]+=D4(u2,w1); acc[2][2]+=D4(u2,w2); acc[2][3]+=D4(u2,w3);
    acc[3][0]+=D4(u3,w0); acc[3][1]+=D4(u3,w1); acc[3][2]+=D4(u3,w2); acc[3][3]+=D4(u3,w3);
  }
}

__device__ __forceinline__ void zreduce(float acc[4][4]) {
#pragma unroll
  for (int i = 0; i < 4; ++i)
#pragma unroll
    for (int j = 0; j < 4; ++j) {
      float a = acc[i][j];
      a += __shfl_xor(a, 1); a += __shfl_xor(a, 2); a += __shfl_xor(a, 4);
      a += __shfl_xor(a, 8); a += __shfl_xor(a, 16);
      acc[i][j] = a;
    }
}

__global__ void init_flags(unsigned* flags) {
  if (threadIdx.x < NFLAGS)
    __hip_atomic_store(&flags[threadIdx.x], 0u, __ATOMIC_RELAXED, __HIP_MEMORY_SCOPE_AGENT);
}

__global__ __launch_bounds__(1024) void dnc_coop(
    const float* __restrict__ Xproj, const float* __restrict__ Wx,
    const float* __restrict__ Wh, const float* __restrict__ Wif,
    const float* __restrict__ bif,
    float* __restrict__ Uh, float* __restrict__ Vh,
    unsigned* __restrict__ flags)
{
  const int blk = blockIdx.x, tid = threadIdx.x;
  extern __shared__ float sm[];
  unsigned* FH = flags + FH_OFF;
  unsigned* FV = flags + FV_OFF;
  unsigned* FR = flags + FR_OFF;

  if (blk < 32) {
    // ================= STATE BLOCK (one example) =================
    const int e = blk;
    float* L   = sm + SL_L;   float* Ms  = sm + SL_M;
    float* v   = sm + SL_V;   float* wr  = sm + SL_WR;
    float* fw  = sm + SL_FW;  float* bw  = sm + SL_BW;
    float* cr  = sm + SL_CR;  float* usg = sm + SL_USG;
    float* prc = sm + SL_PRC; float* ww  = sm + SL_WW;
    float* su  = sm + SL_SU;  float* cpx = sm + SL_CPX;
    float* Mn  = sm + SL_MN;  float* swv = sm + SL_SW;
    float* cw  = sm + SL_CW;  int*   rnk = (int*)(sm + SL_RNK);
    float* msc = sm + SL_MSC; float* er_ = sm + SL_ER; float* wv_ = sm + SL_WV;

    for (int i = tid; i < SL_TOT; i += 1024) sm[i] = 0.f;
    __syncthreads();

    for (int t = 0; t < TT; ++t) {
      wait_ge(FV, 128, t+1);   // v(t) published by all col-blocks
      // A: v copy (plain cached loads from fresh per-t region)
      if (tid < IFC) v[tid] = Vh[(size_t)t*VHT + e*480 + tid];
      __syncthreads();
      // B: usage update / write sim / key norms / modes / erase-write prep
      if (tid < 128) {
        float ret = 1.f;
#pragma unroll
        for (int r = 0; r < 4; ++r) { float fr = sig_(v[453+r]); ret *= 1.f - fr*wr[r*128+tid]; }
        float u = usg[tid], w_ = ww[tid];
        usg[tid] = (u + w_ - u*w_) * ret;
      } else if (tid < 256) {
        int n = tid - 128; float nk = 0.f, dot = 0.f;
#pragma unroll
        for (int w = 0; w < 64; w += 4) {
          float4 k4 = *(float4*)&v[260+w];
          float4 m4 = *(float4*)&Ms[n*MST+w];
          nk += D4(k4,k4); dot += D4(m4,k4);
        }
        float beta = 1.f + sp_(v[324]);
        swv[n] = beta * dot / ((Mn[n]+EPSF)*(sqrtf(nk)+EPSF));
      } else if (tid < 260) {
        int r = tid - 256; float s = 0.f;
#pragma unroll
        for (int w = 0; w < 64; w += 4) { float4 k4 = *(float4*)&v[r*64+w]; s += D4(k4,k4); }
        msc[1+r] = sqrtf(s);
      } else if (tid == 260) {
        for (int r = 0; r < 4; ++r) {
          float a0 = v[459+r*3], a1 = v[459+r*3+1], a2 = v[459+r*3+2];
          float mx = fmaxf(a0, fmaxf(a1, a2));
          float e0 = expf(a0-mx), e1 = expf(a1-mx), e2 = expf(a2-mx);
          float dn = e0+e1+e2;
          msc[8+r*3] = e0/dn; msc[8+r*3+1] = e1/dn; msc[8+r*3+2] = e2/dn;
        }
      } else if (tid >= 640 && tid < 704) { int w = tid-640; er_[w] = sig_(v[325+w]); }
      else if (tid >= 704 && tid < 768) { int w = tid-704; wv_[w] = v[389+w]; }
      __syncthreads();
      // C: stable-ascending rank + write softmax
      if (tid < 128) {
        float ui = usg[tid]; int rk = 0;
        for (int j = 0; j < 128; ++j) {
          float uj = usg[j];
          rk += (uj < ui || (uj == ui && j < tid)) ? 1 : 0;
        }
        rnk[tid] = rk; su[rk] = ui;
      } else if (tid < 192) {
        int l = tid - 128;
        float s1 = swv[l], s2 = swv[l+64];
        float m = fmaxf(s1, s2);
#pragma unroll
        for (int o = 32; o > 0; o >>= 1) m = fmaxf(m, __shfl_xor(m, o));
        float e1 = expf(s1-m), e2 = expf(s2-m);
        float dn = e1 + e2;
#pragma unroll
        for (int o = 32; o > 0; o >>= 1) dn += __shfl_xor(dn, o);
        cw[l] = e1/dn; cw[l+64] = e2/dn;
      }
      __syncthreads();
      // D: exclusive cumprod via wave scan
      if (tid < 64) {
        float a0 = su[2*tid], a1 = su[2*tid+1];
        float p = a0*a1, sc = p;
#pragma unroll
        for (int off = 1; off < 64; off <<= 1) {
          float o = __shfl_up(sc, off);
          if ((int)tid >= off) sc *= o;
        }
        float ex = __shfl_up(sc, 1);
        if (tid == 0) ex = 1.f;
        cpx[2*tid] = ex;
        cpx[2*tid+1] = ex*a0;
      }
      __syncthreads();
      // E: ww_n
      if (tid < 128) {
        float a_i = (1.f - usg[tid]) * cpx[rnk[tid]];
        float ag = sig_(v[457]), wg = sig_(v[458]);
        ww[tid] = wg * (ag*a_i + (1.f-ag)*cw[tid]);
      }
      __syncthreads();
      // F: M erase/write + link update (old prec)
      {
        int n = tid >> 3, q = tid & 7;
        float wwn = ww[n];
        int w8 = q*8;
#pragma unroll
        for (int g = 0; g < 2; ++g) {
          int w = w8 + g*4;
          float4 m = *(float4*)&Ms[n*MST+w];
          float4 e4 = *(float4*)&er_[w];
          float4 v4 = *(float4*)&wv_[w];
          m.x = m.x*(1.f - wwn*e4.x) + wwn*v4.x;
          m.y = m.y*(1.f - wwn*e4.y) + wwn*v4.y;
          m.z = m.z*(1.f - wwn*e4.z) + wwn*v4.z;
          m.w = m.w*(1.f - wwn*e4.w) + wwn*v4.w;
          *(float4*)&Ms[n*MST+w] = m;
        }
        int j16 = q*16;
#pragma unroll
        for (int g = 0; g < 4; ++g) {
          int j = j16 + g*4;
          float4 lv = *(float4*)&L[n*LST + j];
          float4 p4 = *(float4*)&prc[j];
          float4 w4 = *(float4*)&ww[j];
          lv.x = (1.f - wwn - w4.x)*lv.x + wwn*p4.x;
          lv.y = (1.f - wwn - w4.y)*lv.y + wwn*p4.y;
          lv.z = (1.f - wwn - w4.z)*lv.z + wwn*p4.z;
          lv.w = (1.f - wwn - w4.w)*lv.w + wwn*p4.w;
          int d = n - j;
          if (d >= 0 && d < 4) ((float*)&lv)[d] = 0.f;
          *(float4*)&L[n*LST + j] = lv;
        }
      }
      __syncthreads();
      // G: sum(ww) + new M norms
      if (tid < 64) {
        float s = ww[tid] + ww[tid+64];
#pragma unroll
        for (int o = 32; o > 0; o >>= 1) s += __shfl_xor(s, o);
        if (tid == 0) msc[0] = s;
      } else if (tid < 192) {
        int n = tid - 64; float s = 0.f;
#pragma unroll
        for (int w = 0; w < 64; w += 4) { float4 m = *(float4*)&Ms[n*MST+w]; s += D4(m,m); }
        Mn[n] = sqrtf(s);
      }
      __syncthreads();
      // H: fw/bw = link_n · wr_prev
      if (tid < 256) {
        int half = tid >> 7, t2 = tid & 127;
        int i0 = (t2 >> 2) * 4, sg = t2 & 3;
        float4 av[4] = {{0,0,0,0},{0,0,0,0},{0,0,0,0},{0,0,0,0}};
        if (half == 0) {
#pragma unroll
          for (int m = 0; m < 8; ++m) {
            int j = sg*4 + m*16;
            float4 w0 = *(float4*)&wr[0*128+j];
            float4 w1 = *(float4*)&wr[1*128+j];
            float4 w2 = *(float4*)&wr[2*128+j];
            float4 w3 = *(float4*)&wr[3*128+j];
            float4 l0 = *(float4*)&L[(i0+0)*LST+j];
            float4 l1 = *(float4*)&L[(i0+1)*LST+j];
            float4 l2 = *(float4*)&L[(i0+2)*LST+j];
            float4 l3 = *(float4*)&L[(i0+3)*LST+j];
            av[0].x+=D4(l0,w0); av[0].y+=D4(l1,w0); av[0].z+=D4(l2,w0); av[0].w+=D4(l3,w0);
            av[1].x+=D4(l0,w1); av[1].y+=D4(l1,w1); av[1].z+=D4(l2,w1); av[1].w+=D4(l3,w1);
            av[2].x+=D4(l0,w2); av[2].y+=D4(l1,w2); av[2].z+=D4(l2,w2); av[2].w+=D4(l3,w2);
            av[3].x+=D4(l0,w3); av[3].y+=D4(l1,w3); av[3].z+=D4(l2,w3); av[3].w+=D4(l3,w3);
          }
        } else {
#pragma unroll
          for (int m = 0; m < 32; ++m) {
            int j = sg + m*4;
            float4 lv = *(float4*)&L[j*LST + i0];
            float w0 = wr[j], w1 = wr[128+j], w2 = wr[256+j], w3 = wr[384+j];
            av[0].x+=w0*lv.x; av[0].y+=w0*lv.y; av[0].z+=w0*lv.z; av[0].w+=w0*lv.w;
            av[1].x+=w1*lv.x; av[1].y+=w1*lv.y; av[1].z+=w1*lv.z; av[1].w+=w1*lv.w;
            av[2].x+=w2*lv.x; av[2].y+=w2*lv.y; av[2].z+=w2*lv.z; av[2].w+=w2*lv.w;
            av[3].x+=w3*lv.x; av[3].y+=w3*lv.y; av[3].z+=w3*lv.z; av[3].w+=w3*lv.w;
          }
        }
#pragma unroll
        for (int r = 0; r < 4; ++r) {
          av[r].x += __shfl_xor(av[r].x,1); av[r].x += __shfl_xor(av[r].x,2);
          av[r].y += __shfl_xor(av[r].y,1); av[r].y += __shfl_xor(av[r].y,2);
          av[r].z += __shfl_xor(av[r].z,1); av[r].z += __shfl_xor(av[r].z,2);
          av[r].w += __shfl_xor(av[r].w,1); av[r].w += __shfl_xor(av[r].w,2);
        }
        if (sg == 0) {
          float* dst = half ? bw : fw;
#pragma unroll
          for (int r = 0; r < 4; ++r) {
            dst[r*128 + i0+0] = av[r].x; dst[r*128 + i0+1] = av[r].y;
            dst[r*128 + i0+2] = av[r].z; dst[r*128 + i0+3] = av[r].w;
          }
        }
      }
      __syncthreads();
      // I: prec update + read sims (new M)
      if (tid < 128) {
        prc[tid] = (1.f - msc[0])*prc[tid] + ww[tid];
      } else if (tid >= 512) {
        int r = (tid >> 7) & 3, n = tid & 127;
        float dot = 0.f;
#pragma unroll
        for (int w = 0; w < 64; w += 4) {
          float4 m4 = *(float4*)&Ms[n*MST+w];
          float4 k4 = *(float4*)&v[r*64+w];
          dot += D4(m4,k4);
        }
        float beta = 1.f + sp_(v[256+r]);
        cr[r*128+n] = beta * dot / ((Mn[n]+EPSF)*(msc[1+r]+EPSF));
      }
      __syncthreads();
      // J: per-head read softmax
      if (tid < 256) {
        int r = tid >> 6, l = tid & 63;
        float s1 = cr[r*128+l], s2 = cr[r*128+l+64];
        float m = fmaxf(s1, s2);
#pragma unroll
        for (int o = 32; o > 0; o >>= 1) m = fmaxf(m, __shfl_xor(m, o));
        float e1 = expf(s1-m), e2 = expf(s2-m);
        float dn = e1 + e2;
#pragma unroll
        for (int o = 32; o > 0; o >>= 1) dn += __shfl_xor(dn, o);
        cr[r*128+l] = e1/dn; cr[r*128+l+64] = e2/dn;
      }
      __syncthreads();
      // K: wr_n
      if (tid < 512) {
        int r = tid >> 7;
        wr[tid] = msc[8+r*3]*bw[tid] + msc[8+r*3+1]*cr[tid] + msc[8+r*3+2]*fw[tid];
      }
      __syncthreads();
      // L: reads_n = wr_n @ M_n, publish to Uh[t]
      if (tid < 512) {
        int r = tid >> 7, t2 = tid & 127;
        int w0 = (t2 >> 3) * 4, ns = t2 & 7;
        float4 a = {0,0,0,0};
#pragma unroll
        for (int m = 0; m < 16; ++m) {
          int n = ns + m*8;
          float4 mr = *(float4*)&Ms[n*MST + w0];
          float wv = wr[r*128 + n];
          a.x += wv*mr.x; a.y += wv*mr.y; a.z += wv*mr.z; a.w += wv*mr.w;
        }
        a.x += __shfl_xor(a.x,1); a.x += __shfl_xor(a.x,2); a.x += __shfl_xor(a.x,4);
        a.y += __shfl_xor(a.y,1); a.y += __shfl_xor(a.y,2); a.y += __shfl_xor(a.y,4);
        a.z += __shfl_xor(a.z,1); a.z += __shfl_xor(a.z,2); a.z += __shfl_xor(a.z,4);
        a.w += __shfl_xor(a.w,1); a.w += __shfl_xor(a.w,2); a.w += __shfl_xor(a.w,4);
        if (ns == 0) {
          int o = r*64 + w0;
          float2 lo = {a.x, a.y}, hi = {a.z, a.w};
          st2(&Uh[(size_t)t*UHT + e*768 + o], lo);
          st2(&Uh[(size_t)t*UHT + e*768 + o + 2], hi);
        }
      }
      arrive(&FR[e], t+1);   // reads(t) published
    }
  } else {
    // ======== COL BLOCK: z-cols {q*512 + cb*4 + d} + 4 iface cols ========
    const int cb = blk - 32;
    float* Ws = sm + CL_WS;
    float* Wi = sm + CL_WI;
    float* us = sm + CL_US;
    float* zh = sm + CL_ZH;
    float* cst= sm + CL_CS;
    float* hl = sm + CL_HL;
    // load weight slices (once)
    for (int i = tid; i < 16*768; i += 1024) {
      int j = i & 15, k = i >> 4;
      int gc = (j >> 2)*512 + cb*4 + (j & 3);
      Ws[j*WSS + k] = (k < 256) ? Wx[(size_t)(512+k)*ZD + gc]
                                : Wh[(size_t)(k-256)*ZD + gc];
    }
    for (int i = tid; i < 4*512; i += 1024) {
      int j = i & 3, k = i >> 2;
      int col = cb*4 + j;
      Wi[j*WIS + k] = (col < IFC) ? Wif[(size_t)k*IFC + col] : 0.f;
    }
    if (tid < 512) {
      int e2 = tid >> 4, j = tid & 15;
      int gc = (j >> 2)*512 + cb*4 + (j & 3);
      zh[tid] = Xproj[((size_t)e2*TT + 0)*ZD + gc];
    }
    if (tid < 128) cst[tid] = 0.f;
    __syncthreads();
    // gates t=0 (h_prev=0, c_prev=0, reads_prev=0 => z = Xproj)
    if (tid < 128) {
      int e2 = tid >> 2, d = tid & 3;
      float zi = zh[e2*16 + d];
      float zg = zh[e2*16 + 8 + d], zo = zh[e2*16 + 12 + d];
      float cn = sig_(zi)*tanhf(zg);              // f*0 dropped
      float hn = sig_(zo)*tanhf(cn);
      cst[tid] = cn; hl[tid] = hn;
    }
    __syncthreads();
    if (tid < 64) {
      int e2 = tid >> 1, p = tid & 1;
      float2 hv = { hl[e2*4 + 2*p], hl[e2*4 + 2*p + 1] };
      st2(&Uh[(size_t)0*UHT + e2*768 + 256 + cb*4 + 2*p], hv);
    }
    arrive(&FH[cb], 1);   // h(0) published

    for (int t = 0; t < TT; ++t) {
      const size_t uhb = (size_t)t*UHT;
      wait_ge(FH, 128, t+1);   // h(t) fully published
      // stage h(t) — plain cached float4 loads of fresh per-t region
      for (int i = tid; i < 4096; i += 1024) {
        int e2 = i >> 7, q4 = (i & 127) * 4;
        *(float4*)&us[e2*USS + q4] = *(const float4*)&Uh[uhb + e2*768 + 256 + q4];
      }
      // prefetch Xproj(t+1) into a register — latency hides under v compute
      float xpr = 0.f;
      if (t+1 < TT && tid < 512) {
        int e2 = tid >> 4, j = tid & 15;
        int gc = (j >> 2)*512 + cb*4 + (j & 3);
        xpr = Xproj[((size_t)e2*TT + t+1)*ZD + gc];
      }
      __syncthreads();
      // v slice: 4 cols, K=512
      if (tid < 512) {
        float accI[4] = {0,0,0,0};
        int e2 = tid >> 4, ks = tid & 15;
#pragma unroll
        for (int g = 0; g < 8; ++g) {
          int kk = g*64 + ks*4;
          float4 u4 = *(const float4*)&us[e2*USS + kk];
#pragma unroll
          for (int j = 0; j < 4; ++j) {
            float4 w4 = *(const float4*)&Wi[j*WIS + kk];
            accI[j] += D4(u4,w4);
          }
        }
#pragma unroll
        for (int j = 0; j < 4; ++j) {
          float a = accI[j];
          a += __shfl_xor(a,1); a += __shfl_xor(a,2); a += __shfl_xor(a,4); a += __shfl_xor(a,8);
          accI[j] = a;
        }
        if (ks == 0) {
          int c0 = cb*4;
          float* vrow = Vh + (size_t)t*VHT + e2*480;
          if (c0+1 < IFC) { float2 vv = {bif[c0]+accI[0], bif[c0+1]+accI[1]}; st2(&vrow[c0], vv); }
          else if (c0 < IFC) st1(&vrow[c0], bif[c0]+accI[0]);
          if (c0+3 < IFC) { float2 vv = {bif[c0+2]+accI[2], bif[c0+3]+accI[3]}; st2(&vrow[c0+2], vv); }
          else if (c0+2 < IFC) st1(&vrow[c0+2], bif[c0+2]+accI[2]);
        }
      }
      arrive(&FV[cb], t+1);   // v(t) published
      if (t+1 < TT) {
        // zh(t+1) = Xproj(t+1) + h(t)@Wh — no cross-block dependency,
        // overlaps the state blocks' DNC chain
        if (tid < 512) zh[tid] = xpr;
        __syncthreads();
        float acc[4][4] = {};
        zgemm(Ws, us, 256, 4, acc);
        zreduce(acc);
        int tile = tid >> 5, s = tid & 31;
        int e0 = (tile >> 2)*4, jj = (tile & 3)*4;
        if (s == 0) {
#pragma unroll
          for (int i = 0; i < 4; ++i)
#pragma unroll
            for (int j = 0; j < 4; ++j)
              zh[(e0+i)*16 + jj + j] += acc[i][j];
        }
        wait_ge(FR, 32, t+1);   // reads(t) published by all state blocks
        // stage reads(t)  (us[.. 0..255] overwrite — zh gemm already consumed)
        for (int i = tid; i < 2048; i += 1024) {
          int e2 = i >> 6, q4 = (i & 63) * 4;
          *(float4*)&us[e2*USS + q4] = *(const float4*)&Uh[uhb + e2*768 + q4];
        }
        __syncthreads();
        float acc2[4][4] = {};
        zgemm(Ws, us, 0, 2, acc2);
        zreduce(acc2);
        if (s == 0) {
#pragma unroll
          for (int i = 0; i < 4; ++i)
#pragma unroll
            for (int j = 0; j < 4; ++j)
              zh[(e0+i)*16 + jj + j] += acc2[i][j];
        }
        __syncthreads();
        // gates -> h(t+1), c update (block-local)
        if (tid < 128) {
          int e2 = tid >> 2, d = tid & 3;
          float zi = zh[e2*16 + d], zf = zh[e2*16 + 4 + d];
          float zg = zh[e2*16 + 8 + d], zo = zh[e2*16 + 12 + d];
          float cn = sig_(zf)*cst[tid] + sig_(zi)*tanhf(zg);
          float hn = sig_(zo)*tanhf(cn);
          cst[tid] = cn; hl[tid] = hn;
        }
        __syncthreads();
        if (tid < 64) {
          int e2 = tid >> 1, p = tid & 1;
          float2 hv = { hl[e2*4 + 2*p], hl[e2*4 + 2*p + 1] };
          st2(&Uh[(size_t)(t+1)*UHT + e2*768 + 256 + cb*4 + 2*p], hv);
        }
        arrive(&FH[cb], t+2);   // h(t+1) published
      }
    }
  }
}

extern "C" void kernel_launch(void* const* d_in, const int* in_sizes, int n_in,
                              void* d_out, int out_size, void* d_ws, size_t ws_size,
                              hipStream_t stream) {
  const float* x   = (const float*)d_in[0];
  const float* Wx  = (const float*)d_in[1];
  const float* Wh  = (const float*)d_in[2];
  const float* bl  = (const float*)d_in[3];
  const float* Wif = (const float*)d_in[4];
  const float* bif = (const float*)d_in[5];
  const float* Wo  = (const float*)d_in[6];
  const float* bo  = (const float*)d_in[7];
  float* out = (float*)d_out;

  float* Xp = (float*)d_ws;                         // 4096*2048
  float* Uh = Xp + (size_t)4096*2048;               // 128*UHT
  float* Vh = Uh + (size_t)TT*UHT;                  // 128*VHT
  unsigned* fl = (unsigned*)(Vh + (size_t)TT*VHT);  // NFLAGS

  // 1) Xproj = x @ Wx[:512] + b_lstm
  gemm_bias<<<dim3(2048/64, 4096/64), dim3(256), 0, stream>>>(x, Wx, bl, Xp, 2048, 512);

  // 2) flags
  init_flags<<<dim3(1), dim3(512), 0, stream>>>(fl);

  // 3) cooperative weight-stationary recurrent core (dataflow sync)
  const int smem_bytes = CL_TOT * 4;  // 126784
  hipFuncSetAttribute((const void*)dnc_coop, hipFuncAttributeMaxDynamicSharedMemorySize, smem_bytes);
  void* args[] = { (void*)&Xp, (void*)&Wx, (void*)&Wh, (void*)&Wif, (void*)&bif,
                   (void*)&Uh, (void*)&Vh, (void*)&fl };
  hipLaunchCooperativeKernel((void*)dnc_coop, dim3(NBLK), dim3(1024), args,
                             (unsigned int)smem_bytes, stream);

  // 4) out = [reads,h] @ W_out + b_out  (reads Uh directly, remaps rows)
  gemm_out<<<dim3(512/64, 4096/64), dim3(256), 0, stream>>>(Uh, Wo, bo, out);
}

// Round 8
// 5250.594 us; speedup vs baseline: 4.2378x; 1.0978x over previous
//
#include <hip/hip_runtime.h>
#include <math.h>

#define TT 128
#define ZD 2048
#define IFC 471
#define EPSF 1e-6f
#define MST 68      // M LDS row stride
#define LST 132     // link LDS row stride
#define NBLK 160
#define UHT 24640   // per-t stride of Uh: 32*768 + 64 guard floats
#define VHT 15424   // per-t stride of Vh: 32*480 + 64 guard floats
#define USS 516     // staged activation LDS row stride
#define WSS 772     // z weight slice LDS row stride
#define WIS 516     // iface weight slice LDS row stride

// dataflow flag arrays (unsigned), disjoint cache-line sets
#define FH_OFF 0     // [128] col h arrivals
#define FV_OFF 128   // [128] col v arrivals
#define FR_OFF 256   // [32]  state reads arrivals
#define NFLAGS 512

#define D4(a,b) ((a).x*(b).x + (a).y*(b).y + (a).z*(b).z + (a).w*(b).w)

__device__ __forceinline__ float sig_(float x){ return 1.f/(1.f+expf(-x)); }
__device__ __forceinline__ float sp_(float x){ return fmaxf(x,0.f)+log1pf(expf(-fabsf(x))); }

// -------- agent-scope (write-through, cache-bypassing) publishes --------
__device__ __forceinline__ void st1(float* p, float v){
  unsigned u; __builtin_memcpy(&u,&v,4);
  __hip_atomic_store((unsigned*)p, u, __ATOMIC_RELAXED, __HIP_MEMORY_SCOPE_AGENT);
}
__device__ __forceinline__ void st2(float* p, float2 v){
  unsigned long long u; __builtin_memcpy(&u,&v,8);
  __hip_atomic_store((unsigned long long*)p, u, __ATOMIC_RELAXED, __HIP_MEMORY_SCOPE_AGENT);
}

// -------- dataflow sync ------------------------------------------------
// arrive: __syncthreads() drains vmcnt(0) (payload store acks) before the
// flag RMW. The RMW (vs round-6's plain relaxed store) executes at the
// coherent point on arrival — it cannot linger in write-combining buffers,
// which is the round-6 ~11us/hop visibility-latency suspect.
__device__ __forceinline__ void arrive(unsigned* f){
  __syncthreads();
  if (threadIdx.x == 0)
    __hip_atomic_fetch_add(f, 1u, __ATOMIC_RELAXED, __HIP_MEMORY_SCOPE_AGENT);
}
// wait_ge: wave 0 polls n flags (fast-path check, then two-phase constant
// backoff — s_sleep operand must be a compile-time constant). Other waves
// park at the syncthreads.
__device__ __forceinline__ void wait_ge(const unsigned* f, int n, unsigned gen){
  if (threadIdx.x < 64){
    for (int i = threadIdx.x; i < n; i += 64){
      if (__hip_atomic_load(&f[i], __ATOMIC_RELAXED, __HIP_MEMORY_SCOPE_AGENT) >= gen) continue;
      int spins = 0;
      bool done = false;
      while (spins < 64){
        if (__hip_atomic_load(&f[i], __ATOMIC_RELAXED, __HIP_MEMORY_SCOPE_AGENT) >= gen){ done = true; break; }
        __builtin_amdgcn_s_sleep(1);
        ++spins;
      }
      if (!done){
        while (__hip_atomic_load(&f[i], __ATOMIC_RELAXED, __HIP_MEMORY_SCOPE_AGENT) < gen)
          __builtin_amdgcn_s_sleep(8);
      }
    }
  }
  __syncthreads();
}

// ---------------- GEMM #1: C[M,N] = A[M,K] @ B[K,N] + bias[N]
__global__ __launch_bounds__(256) void gemm_bias(
    const float* __restrict__ A, const float* __restrict__ B,
    const float* __restrict__ bias, float* __restrict__ C,
    int Nc, int K)
{
  __shared__ float As[16][68];
  __shared__ float Bs[16][68];
  const int tid = threadIdx.x;
  const int bx = blockIdx.x, by = blockIdx.y;
  const int tx = tid & 15, ty = tid >> 4;
  const int am = tid >> 2, ak = (tid & 3) * 4;
  const int bk = tid >> 4, bn = (tid & 15) * 4;
  float acc[4][4] = {};
  const float* Ap = A + (size_t)(by*64+am)*K + ak;
  const float* Bp = B + (size_t)bk*Nc + bx*64 + bn;
  for (int k0 = 0; k0 < K; k0 += 16) {
    float4 av = *(const float4*)Ap; Ap += 16;
    float4 bv = *(const float4*)Bp; Bp += (size_t)16*Nc;
    As[ak+0][am]=av.x; As[ak+1][am]=av.y; As[ak+2][am]=av.z; As[ak+3][am]=av.w;
    *(float4*)&Bs[bk][bn] = bv;
    __syncthreads();
#pragma unroll
    for (int kk = 0; kk < 16; ++kk) {
      float4 a4 = *(const float4*)&As[kk][ty*4];
      float4 b4 = *(const float4*)&Bs[kk][tx*4];
      acc[0][0]+=a4.x*b4.x; acc[0][1]+=a4.x*b4.y; acc[0][2]+=a4.x*b4.z; acc[0][3]+=a4.x*b4.w;
      acc[1][0]+=a4.y*b4.x; acc[1][1]+=a4.y*b4.y; acc[1][2]+=a4.y*b4.z; acc[1][3]+=a4.y*b4.w;
      acc[2][0]+=a4.z*b4.x; acc[2][1]+=a4.z*b4.y; acc[2][2]+=a4.z*b4.z; acc[2][3]+=a4.z*b4.w;
      acc[3][0]+=a4.w*b4.x; acc[3][1]+=a4.w*b4.y; acc[3][2]+=a4.w*b4.z; acc[3][3]+=a4.w*b4.w;
    }
    __syncthreads();
  }
  float4 bb = *(const float4*)(bias + bx*64 + tx*4);
#pragma unroll
  for (int i = 0; i < 4; ++i) {
    float4 o;
    o.x = acc[i][0]+bb.x; o.y = acc[i][1]+bb.y; o.z = acc[i][2]+bb.z; o.w = acc[i][3]+bb.w;
    *(float4*)(C + (size_t)(by*64+ty*4+i)*Nc + bx*64 + tx*4) = o;
  }
}

// ---------------- GEMM #2 (output): A rows live in Uh[t][e] layout.
__global__ __launch_bounds__(256) void gemm_out(
    const float* __restrict__ A, const float* __restrict__ B,
    const float* __restrict__ bias, float* __restrict__ C)
{
  __shared__ float As[16][68];
  __shared__ float Bs[16][68];
  const int tid = threadIdx.x;
  const int bx = blockIdx.x, by = blockIdx.y;
  const int tx = tid & 15, ty = tid >> 4;
  const int am = tid >> 2, ak = (tid & 3) * 4;
  const int bk = tid >> 4, bn = (tid & 15) * 4;
  float acc[4][4] = {};
  const int arow = by*64 + am;
  const float* Ap = A + (size_t)(arow >> 5)*UHT + (size_t)(arow & 31)*768 + ak;
  const float* Bp = B + (size_t)bk*512 + bx*64 + bn;
  for (int k0 = 0; k0 < 768; k0 += 16) {
    float4 av = *(const float4*)Ap; Ap += 16;
    float4 bv = *(const float4*)Bp; Bp += (size_t)16*512;
    As[ak+0][am]=av.x; As[ak+1][am]=av.y; As[ak+2][am]=av.z; As[ak+3][am]=av.w;
    *(float4*)&Bs[bk][bn] = bv;
    __syncthreads();
#pragma unroll
    for (int kk = 0; kk < 16; ++kk) {
      float4 a4 = *(const float4*)&As[kk][ty*4];
      float4 b4 = *(const float4*)&Bs[kk][tx*4];
      acc[0][0]+=a4.x*b4.x; acc[0][1]+=a4.x*b4.y; acc[0][2]+=a4.x*b4.z; acc[0][3]+=a4.x*b4.w;
      acc[1][0]+=a4.y*b4.x; acc[1][1]+=a4.y*b4.y; acc[1][2]+=a4.y*b4.z; acc[1][3]+=a4.y*b4.w;
      acc[2][0]+=a4.z*b4.x; acc[2][1]+=a4.z*b4.y; acc[2][2]+=a4.z*b4.z; acc[2][3]+=a4.z*b4.w;
      acc[3][0]+=a4.w*b4.x; acc[3][1]+=a4.w*b4.y; acc[3][2]+=a4.w*b4.z; acc[3][3]+=a4.w*b4.w;
    }
    __syncthreads();
  }
  float4 bb = *(const float4*)(bias + bx*64 + tx*4);
#pragma unroll
  for (int i = 0; i < 4; ++i) {
    int row = by*64 + ty*4 + i;
    int crow = (row & 31)*128 + (row >> 5);   // (e,t) -> e*128+t
    float4 o;
    o.x = acc[i][0]+bb.x; o.y = acc[i][1]+bb.y; o.z = acc[i][2]+bb.z; o.w = acc[i][3]+bb.w;
    *(float4*)(C + (size_t)crow*512 + bx*64 + tx*4) = o;
  }
}

// ---------------- state-block LDS layout (floats)
#define SL_L    0
#define SL_M    16896
#define SL_V    25600
#define SL_WR   26080
#define SL_FW   26592
#define SL_BW   27104
#define SL_CR   27616
#define SL_USG  28128
#define SL_PRC  28256
#define SL_WW   28384
#define SL_SU   28512
#define SL_CPX  28640
#define SL_MN   28768
#define SL_SW   28896
#define SL_CW   29024
#define SL_RNK  29152
#define SL_MSC  29280
#define SL_ER   29344
#define SL_WV   29408
#define SL_TOT  29472

// ---------------- col-block LDS layout (floats)
#define CL_WS  0                      // Ws [16][772] = 12352
#define CL_WI  12352                  // Wi [4][516]  = 2064
#define CL_US  14416                  // us [32][516] = 16512
#define CL_ZH  30928                  // zh [512]
#define CL_CS  31440                  // c  [128]
#define CL_HL  31568                  // h  [128]
#define CL_TOT 31696                  // 126784 bytes

__device__ __forceinline__ void zgemm(const float* Ws, const float* us, int wofs,
                                      int giters, float acc[4][4]) {
  const int tid = threadIdx.x;
  const int tile = tid >> 5, s = tid & 31;
  const int e0 = (tile >> 2)*4, jj = (tile & 3)*4;
  for (int g = 0; g < giters; ++g) {
    int kk = g*128 + s*4;
    float4 u0 = *(const float4*)&us[(e0+0)*USS + kk];
    float4 u1 = *(const float4*)&us[(e0+1)*USS + kk];
    float4 u2 = *(const float4*)&us[(e0+2)*USS + kk];
    float4 u3 = *(const float4*)&us[(e0+3)*USS + kk];
    float4 w0 = *(const float4*)&Ws[(jj+0)*WSS + wofs + kk];
    float4 w1 = *(const float4*)&Ws[(jj+1)*WSS + wofs + kk];
    float4 w2 = *(const float4*)&Ws[(jj+2)*WSS + wofs + kk];
    float4 w3 = *(const float4*)&Ws[(jj+3)*WSS + wofs + kk];
    acc[0][0]+=D4(u0,w0); acc[0][1]+=D4(u0,w1); acc[0][2]+=D4(u0,w2); acc[0][3]+=D4(u0,w3);
    acc[1][0]+=D4(u1,w0); acc[1][1]+=D4(u1,w1); acc[1][2]+=D4(u1,w2); acc[1][3]+=D4(u1,w3);
    acc[2][0]+=D4(u2,w0); acc[2][1]+=D4(u2,w1); acc[2][2]+=D4(u2,w2); acc[2][3]+=D4(u2,w3);
    acc[3][0]+=D4(u3,w0); acc[3][1]+=D4(u3,w1); acc[3][2]+=D4(u3,w2); acc[3][3]+=D4(u3,w3);
  }
}

__device__ __forceinline__ void zreduce(float acc[4][4]) {
#pragma unroll
  for (int i = 0; i < 4; ++i)
#pragma unroll
    for (int j = 0; j < 4; ++j) {
      float a = acc[i][j];
      a += __shfl_xor(a, 1); a += __shfl_xor(a, 2); a += __shfl_xor(a, 4);
      a += __shfl_xor(a, 8); a += __shfl_xor(a, 16);
      acc[i][j] = a;
    }
}

__global__ void init_flags(unsigned* flags) {
  if (threadIdx.x < NFLAGS)
    __hip_atomic_store(&flags[threadIdx.x], 0u, __ATOMIC_RELAXED, __HIP_MEMORY_SCOPE_AGENT);
}

__global__ __launch_bounds__(1024) void dnc_coop(
    const float* __restrict__ Xproj, const float* __restrict__ Wx,
    const float* __restrict__ Wh, const float* __restrict__ Wif,
    const float* __restrict__ bif,
    float* __restrict__ Uh, float* __restrict__ Vh,
    unsigned* __restrict__ flags)
{
  const int blk = blockIdx.x, tid = threadIdx.x;
  extern __shared__ float sm[];
  unsigned* FH = flags + FH_OFF;
  unsigned* FV = flags + FV_OFF;
  unsigned* FR = flags + FR_OFF;

  if (blk < 32) {
    // ================= STATE BLOCK (one example) =================
    const int e = blk;
    float* L   = sm + SL_L;   float* Ms  = sm + SL_M;
    float* v   = sm + SL_V;   float* wr  = sm + SL_WR;
    float* fw  = sm + SL_FW;  float* bw  = sm + SL_BW;
    float* cr  = sm + SL_CR;  float* usg = sm + SL_USG;
    float* prc = sm + SL_PRC; float* ww  = sm + SL_WW;
    float* su  = sm + SL_SU;  float* cpx = sm + SL_CPX;
    float* Mn  = sm + SL_MN;  float* swv = sm + SL_SW;
    float* cw  = sm + SL_CW;  int*   rnk = (int*)(sm + SL_RNK);
    float* msc = sm + SL_MSC; float* er_ = sm + SL_ER; float* wv_ = sm + SL_WV;

    for (int i = tid; i < SL_TOT; i += 1024) sm[i] = 0.f;
    __syncthreads();

    for (int t = 0; t < TT; ++t) {
      wait_ge(FV, 128, t+1);   // v(t) published by all col-blocks
      // A: v copy (plain cached loads from fresh per-t region)
      if (tid < IFC) v[tid] = Vh[(size_t)t*VHT + e*480 + tid];
      __syncthreads();
      // B: usage update / write sim / key norms / modes / erase-write prep
      if (tid < 128) {
        float ret = 1.f;
#pragma unroll
        for (int r = 0; r < 4; ++r) { float fr = sig_(v[453+r]); ret *= 1.f - fr*wr[r*128+tid]; }
        float u = usg[tid], w_ = ww[tid];
        usg[tid] = (u + w_ - u*w_) * ret;
      } else if (tid < 256) {
        int n = tid - 128; float nk = 0.f, dot = 0.f;
#pragma unroll
        for (int w = 0; w < 64; w += 4) {
          float4 k4 = *(float4*)&v[260+w];
          float4 m4 = *(float4*)&Ms[n*MST+w];
          nk += D4(k4,k4); dot += D4(m4,k4);
        }
        float beta = 1.f + sp_(v[324]);
        swv[n] = beta * dot / ((Mn[n]+EPSF)*(sqrtf(nk)+EPSF));
      } else if (tid < 260) {
        int r = tid - 256; float s = 0.f;
#pragma unroll
        for (int w = 0; w < 64; w += 4) { float4 k4 = *(float4*)&v[r*64+w]; s += D4(k4,k4); }
        msc[1+r] = sqrtf(s);
      } else if (tid == 260) {
        for (int r = 0; r < 4; ++r) {
          float a0 = v[459+r*3], a1 = v[459+r*3+1], a2 = v[459+r*3+2];
          float mx = fmaxf(a0, fmaxf(a1, a2));
          float e0 = expf(a0-mx), e1 = expf(a1-mx), e2 = expf(a2-mx);
          float dn = e0+e1+e2;
          msc[8+r*3] = e0/dn; msc[8+r*3+1] = e1/dn; msc[8+r*3+2] = e2/dn;
        }
      } else if (tid >= 640 && tid < 704) { int w = tid-640; er_[w] = sig_(v[325+w]); }
      else if (tid >= 704 && tid < 768) { int w = tid-704; wv_[w] = v[389+w]; }
      __syncthreads();
      // C: stable-ascending rank + write softmax
      if (tid < 128) {
        float ui = usg[tid]; int rk = 0;
        for (int j = 0; j < 128; ++j) {
          float uj = usg[j];
          rk += (uj < ui || (uj == ui && j < tid)) ? 1 : 0;
        }
        rnk[tid] = rk; su[rk] = ui;
      } else if (tid < 192) {
        int l = tid - 128;
        float s1 = swv[l], s2 = swv[l+64];
        float m = fmaxf(s1, s2);
#pragma unroll
        for (int o = 32; o > 0; o >>= 1) m = fmaxf(m, __shfl_xor(m, o));
        float e1 = expf(s1-m), e2 = expf(s2-m);
        float dn = e1 + e2;
#pragma unroll
        for (int o = 32; o > 0; o >>= 1) dn += __shfl_xor(dn, o);
        cw[l] = e1/dn; cw[l+64] = e2/dn;
      }
      __syncthreads();
      // D': exclusive cumprod via wave scan + ww (fused; intra-wave LDS RAW
      // between the cpx write and the permuted cpx[rnk[n]] read is safe —
      // single wave, ds ops ordered by lgkmcnt)
      if (tid < 64) {
        float a0 = su[2*tid], a1 = su[2*tid+1];
        float p = a0*a1, sc = p;
#pragma unroll
        for (int off = 1; off < 64; off <<= 1) {
          float o = __shfl_up(sc, off);
          if ((int)tid >= off) sc *= o;
        }
        float ex = __shfl_up(sc, 1);
        if (tid == 0) ex = 1.f;
        cpx[2*tid] = ex;
        cpx[2*tid+1] = ex*a0;
        float ag = sig_(v[457]), wg = sig_(v[458]);
#pragma unroll
        for (int q = 0; q < 2; ++q) {
          int n = 2*tid + q;
          float a_i = (1.f - usg[n]) * cpx[rnk[n]];
          ww[n] = wg * (ag*a_i + (1.f-ag)*cw[n]);
        }
      }
      __syncthreads();
      // F: M erase/write + link update (old prec)
      {
        int n = tid >> 3, q = tid & 7;
        float wwn = ww[n];
        int w8 = q*8;
#pragma unroll
        for (int g = 0; g < 2; ++g) {
          int w = w8 + g*4;
          float4 m = *(float4*)&Ms[n*MST+w];
          float4 e4 = *(float4*)&er_[w];
          float4 v4 = *(float4*)&wv_[w];
          m.x = m.x*(1.f - wwn*e4.x) + wwn*v4.x;
          m.y = m.y*(1.f - wwn*e4.y) + wwn*v4.y;
          m.z = m.z*(1.f - wwn*e4.z) + wwn*v4.z;
          m.w = m.w*(1.f - wwn*e4.w) + wwn*v4.w;
          *(float4*)&Ms[n*MST+w] = m;
        }
        int j16 = q*16;
#pragma unroll
        for (int g = 0; g < 4; ++g) {
          int j = j16 + g*4;
          float4 lv = *(float4*)&L[n*LST + j];
          float4 p4 = *(float4*)&prc[j];
          float4 w4 = *(float4*)&ww[j];
          lv.x = (1.f - wwn - w4.x)*lv.x + wwn*p4.x;
          lv.y = (1.f - wwn - w4.y)*lv.y + wwn*p4.y;
          lv.z = (1.f - wwn - w4.z)*lv.z + wwn*p4.z;
          lv.w = (1.f - wwn - w4.w)*lv.w + wwn*p4.w;
          int d = n - j;
          if (d >= 0 && d < 4) ((float*)&lv)[d] = 0.f;
          *(float4*)&L[n*LST + j] = lv;
        }
      }
      __syncthreads();
      // G: sum(ww) + new M norms
      if (tid < 64) {
        float s = ww[tid] + ww[tid+64];
#pragma unroll
        for (int o = 32; o > 0; o >>= 1) s += __shfl_xor(s, o);
        if (tid == 0) msc[0] = s;
      } else if (tid < 192) {
        int n = tid - 64; float s = 0.f;
#pragma unroll
        for (int w = 0; w < 64; w += 4) { float4 m = *(float4*)&Ms[n*MST+w]; s += D4(m,m); }
        Mn[n] = sqrtf(s);
      }
      __syncthreads();
      // H': fw/bw (tid<256) | prec (256..383) | read sims vs new M (>=512)
      if (tid < 256) {
        int half = tid >> 7, t2 = tid & 127;
        int i0 = (t2 >> 2) * 4, sg = t2 & 3;
        float4 av[4] = {{0,0,0,0},{0,0,0,0},{0,0,0,0},{0,0,0,0}};
        if (half == 0) {
#pragma unroll
          for (int m = 0; m < 8; ++m) {
            int j = sg*4 + m*16;
            float4 w0 = *(float4*)&wr[0*128+j];
            float4 w1 = *(float4*)&wr[1*128+j];
            float4 w2 = *(float4*)&wr[2*128+j];
            float4 w3 = *(float4*)&wr[3*128+j];
            float4 l0 = *(float4*)&L[(i0+0)*LST+j];
            float4 l1 = *(float4*)&L[(i0+1)*LST+j];
            float4 l2 = *(float4*)&L[(i0+2)*LST+j];
            float4 l3 = *(float4*)&L[(i0+3)*LST+j];
            av[0].x+=D4(l0,w0); av[0].y+=D4(l1,w0); av[0].z+=D4(l2,w0); av[0].w+=D4(l3,w0);
            av[1].x+=D4(l0,w1); av[1].y+=D4(l1,w1); av[1].z+=D4(l2,w1); av[1].w+=D4(l3,w1);
            av[2].x+=D4(l0,w2); av[2].y+=D4(l1,w2); av[2].z+=D4(l2,w2); av[2].w+=D4(l3,w2);
            av[3].x+=D4(l0,w3); av[3].y+=D4(l1,w3); av[3].z+=D4(l2,w3); av[3].w+=D4(l3,w3);
          }
        } else {
#pragma unroll
          for (int m = 0; m < 32; ++m) {
            int j = sg + m*4;
            float4 lv = *(float4*)&L[j*LST + i0];
            float w0 = wr[j], w1 = wr[128+j], w2 = wr[256+j], w3 = wr[384+j];
            av[0].x+=w0*lv.x; av[0].y+=w0*lv.y; av[0].z+=w0*lv.z; av[0].w+=w0*lv.w;
            av[1].x+=w1*lv.x; av[1].y+=w1*lv.y; av[1].z+=w1*lv.z; av[1].w+=w1*lv.w;
            av[2].x+=w2*lv.x; av[2].y+=w2*lv.y; av[2].z+=w2*lv.z; av[2].w+=w2*lv.w;
            av[3].x+=w3*lv.x; av[3].y+=w3*lv.y; av[3].z+=w3*lv.z; av[3].w+=w3*lv.w;
          }
        }
#pragma unroll
        for (int r = 0; r < 4; ++r) {
          av[r].x += __shfl_xor(av[r].x,1); av[r].x += __shfl_xor(av[r].x,2);
          av[r].y += __shfl_xor(av[r].y,1); av[r].y += __shfl_xor(av[r].y,2);
          av[r].z += __shfl_xor(av[r].z,1); av[r].z += __shfl_xor(av[r].z,2);
          av[r].w += __shfl_xor(av[r].w,1); av[r].w += __shfl_xor(av[r].w,2);
        }
        if (sg == 0) {
          float* dst = half ? bw : fw;
#pragma unroll
          for (int r = 0; r < 4; ++r) {
            dst[r*128 + i0+0] = av[r].x; dst[r*128 + i0+1] = av[r].y;
            dst[r*128 + i0+2] = av[r].z; dst[r*128 + i0+3] = av[r].w;
          }
        }
      } else if (tid < 384) {
        int n = tid - 256;
        prc[n] = (1.f - msc[0])*prc[n] + ww[n];
      } else if (tid >= 512) {
        int r = (tid >> 7) & 3, n = tid & 127;
        float dot = 0.f;
#pragma unroll
        for (int w = 0; w < 64; w += 4) {
          float4 m4 = *(float4*)&Ms[n*MST+w];
          float4 k4 = *(float4*)&v[r*64+w];
          dot += D4(m4,k4);
        }
        float beta = 1.f + sp_(v[256+r]);
        cr[r*128+n] = beta * dot / ((Mn[n]+EPSF)*(msc[1+r]+EPSF));
      }
      __syncthreads();
      // J': per-head read softmax + wr_n (fused; bw/fw/modes ready since H'/B)
      if (tid < 256) {
        int r = tid >> 6, l = tid & 63;
        float s1 = cr[r*128+l], s2 = cr[r*128+l+64];
        float m = fmaxf(s1, s2);
#pragma unroll
        for (int o = 32; o > 0; o >>= 1) m = fmaxf(m, __shfl_xor(m, o));
        float e1 = expf(s1-m), e2 = expf(s2-m);
        float dn = e1 + e2;
#pragma unroll
        for (int o = 32; o > 0; o >>= 1) dn += __shfl_xor(dn, o);
        float m0 = msc[8+r*3], m1 = msc[8+r*3+1], m2 = msc[8+r*3+2];
        wr[r*128+l]    = m0*bw[r*128+l]    + m1*(e1/dn) + m2*fw[r*128+l];
        wr[r*128+l+64] = m0*bw[r*128+l+64] + m1*(e2/dn) + m2*fw[r*128+l+64];
      }
      __syncthreads();
      // L: reads_n = wr_n @ M_n, publish to Uh[t]
      if (tid < 512) {
        int r = tid >> 7, t2 = tid & 127;
        int w0 = (t2 >> 3) * 4, ns = t2 & 7;
        float4 a = {0,0,0,0};
#pragma unroll
        for (int m = 0; m < 16; ++m) {
          int n = ns + m*8;
          float4 mr = *(float4*)&Ms[n*MST + w0];
          float wv = wr[r*128 + n];
          a.x += wv*mr.x; a.y += wv*mr.y; a.z += wv*mr.z; a.w += wv*mr.w;
        }
        a.x += __shfl_xor(a.x,1); a.x += __shfl_xor(a.x,2); a.x += __shfl_xor(a.x,4);
        a.y += __shfl_xor(a.y,1); a.y += __shfl_xor(a.y,2); a.y += __shfl_xor(a.y,4);
        a.z += __shfl_xor(a.z,1); a.z += __shfl_xor(a.z,2); a.z += __shfl_xor(a.z,4);
        a.w += __shfl_xor(a.w,1); a.w += __shfl_xor(a.w,2); a.w += __shfl_xor(a.w,4);
        if (ns == 0) {
          int o = r*64 + w0;
          float2 lo = {a.x, a.y}, hi = {a.z, a.w};
          st2(&Uh[(size_t)t*UHT + e*768 + o], lo);
          st2(&Uh[(size_t)t*UHT + e*768 + o + 2], hi);
        }
      }
      arrive(&FR[e]);   // reads(t) published
    }
  } else {
    // ======== COL BLOCK: z-cols {q*512 + cb*4 + d} + 4 iface cols ========
    const int cb = blk - 32;
    float* Ws = sm + CL_WS;
    float* Wi = sm + CL_WI;
    float* us = sm + CL_US;
    float* zh = sm + CL_ZH;
    float* cst= sm + CL_CS;
    float* hl = sm + CL_HL;
    // load weight slices (once)
    for (int i = tid; i < 16*768; i += 1024) {
      int j = i & 15, k = i >> 4;
      int gc = (j >> 2)*512 + cb*4 + (j & 3);
      Ws[j*WSS + k] = (k < 256) ? Wx[(size_t)(512+k)*ZD + gc]
                                : Wh[(size_t)(k-256)*ZD + gc];
    }
    for (int i = tid; i < 4*512; i += 1024) {
      int j = i & 3, k = i >> 2;
      int col = cb*4 + j;
      Wi[j*WIS + k] = (col < IFC) ? Wif[(size_t)k*IFC + col] : 0.f;
    }
    if (tid < 512) {
      int e2 = tid >> 4, j = tid & 15;
      int gc = (j >> 2)*512 + cb*4 + (j & 3);
      zh[tid] = Xproj[((size_t)e2*TT + 0)*ZD + gc];
    }
    if (tid < 128) cst[tid] = 0.f;
    __syncthreads();
    // gates t=0 (h_prev=0, c_prev=0, reads_prev=0 => z = Xproj)
    if (tid < 128) {
      int e2 = tid >> 2, d = tid & 3;
      float zi = zh[e2*16 + d];
      float zg = zh[e2*16 + 8 + d], zo = zh[e2*16 + 12 + d];
      float cn = sig_(zi)*tanhf(zg);              // f*0 dropped
      float hn = sig_(zo)*tanhf(cn);
      cst[tid] = cn; hl[tid] = hn;
    }
    __syncthreads();
    if (tid < 64) {
      int e2 = tid >> 1, p = tid & 1;
      float2 hv = { hl[e2*4 + 2*p], hl[e2*4 + 2*p + 1] };
      st2(&Uh[(size_t)0*UHT + e2*768 + 256 + cb*4 + 2*p], hv);
    }
    arrive(&FH[cb]);   // h(0) published -> FH[cb]=1

    for (int t = 0; t < TT; ++t) {
      const size_t uhb = (size_t)t*UHT;
      wait_ge(FH, 128, t+1);   // h(t) fully published
      // stage h(t) — plain cached float4 loads of fresh per-t region
      for (int i = tid; i < 4096; i += 1024) {
        int e2 = i >> 7, q4 = (i & 127) * 4;
        *(float4*)&us[e2*USS + q4] = *(const float4*)&Uh[uhb + e2*768 + 256 + q4];
      }
      // prefetch Xproj(t+1) into a register — latency hides under v compute
      float xpr = 0.f;
      if (t+1 < TT && tid < 512) {
        int e2 = tid >> 4, j = tid & 15;
        int gc = (j >> 2)*512 + cb*4 + (j & 3);
        xpr = Xproj[((size_t)e2*TT + t+1)*ZD + gc];
      }
      __syncthreads();
      // v slice: 4 cols, K=512
      if (tid < 512) {
        float accI[4] = {0,0,0,0};
        int e2 = tid >> 4, ks = tid & 15;
#pragma unroll
        for (int g = 0; g < 8; ++g) {
          int kk = g*64 + ks*4;
          float4 u4 = *(const float4*)&us[e2*USS + kk];
#pragma unroll
          for (int j = 0; j < 4; ++j) {
            float4 w4 = *(const float4*)&Wi[j*WIS + kk];
            accI[j] += D4(u4,w4);
          }
        }
#pragma unroll
        for (int j = 0; j < 4; ++j) {
          float a = accI[j];
          a += __shfl_xor(a,1); a += __shfl_xor(a,2); a += __shfl_xor(a,4); a += __shfl_xor(a,8);
          accI[j] = a;
        }
        if (ks == 0) {
          int c0 = cb*4;
          float* vrow = Vh + (size_t)t*VHT + e2*480;
          if (c0+1 < IFC) { float2 vv = {bif[c0]+accI[0], bif[c0+1]+accI[1]}; st2(&vrow[c0], vv); }
          else if (c0 < IFC) st1(&vrow[c0], bif[c0]+accI[0]);
          if (c0+3 < IFC) { float2 vv = {bif[c0+2]+accI[2], bif[c0+3]+accI[3]}; st2(&vrow[c0+2], vv); }
          else if (c0+2 < IFC) st1(&vrow[c0+2], bif[c0+2]+accI[2]);
        }
      }
      arrive(&FV[cb]);   // v(t) published
      if (t+1 < TT) {
        // zh(t+1) = Xproj(t+1) + h(t)@Wh — no cross-block dependency,
        // overlaps the state blocks' DNC chain
        if (tid < 512) zh[tid] = xpr;
        __syncthreads();
        float acc[4][4] = {};
        zgemm(Ws, us, 256, 4, acc);
        zreduce(acc);
        int tile = tid >> 5, s = tid & 31;
        int e0 = (tile >> 2)*4, jj = (tile & 3)*4;
        if (s == 0) {
#pragma unroll
          for (int i = 0; i < 4; ++i)
#pragma unroll
            for (int j = 0; j < 4; ++j)
              zh[(e0+i)*16 + jj + j] += acc[i][j];
        }
        wait_ge(FR, 32, t+1);   // reads(t) published by all state blocks
        // stage reads(t)
        for (int i = tid; i < 2048; i += 1024) {
          int e2 = i >> 6, q4 = (i & 63) * 4;
          *(float4*)&us[e2*USS + q4] = *(const float4*)&Uh[uhb + e2*768 + q4];
        }
        __syncthreads();
        float acc2[4][4] = {};
        zgemm(Ws, us, 0, 2, acc2);
        zreduce(acc2);
        if (s == 0) {
#pragma unroll
          for (int i = 0; i < 4; ++i)
#pragma unroll
            for (int j = 0; j < 4; ++j)
              zh[(e0+i)*16 + jj + j] += acc2[i][j];
        }
        __syncthreads();
        // gates -> h(t+1), c update (block-local)
        if (tid < 128) {
          int e2 = tid >> 2, d = tid & 3;
          float zi = zh[e2*16 + d], zf = zh[e2*16 + 4 + d];
          float zg = zh[e2*16 + 8 + d], zo = zh[e2*16 + 12 + d];
          float cn = sig_(zf)*cst[tid] + sig_(zi)*tanhf(zg);
          float hn = sig_(zo)*tanhf(cn);
          cst[tid] = cn; hl[tid] = hn;
        }
        __syncthreads();
        if (tid < 64) {
          int e2 = tid >> 1, p = tid & 1;
          float2 hv = { hl[e2*4 + 2*p], hl[e2*4 + 2*p + 1] };
          st2(&Uh[(size_t)(t+1)*UHT + e2*768 + 256 + cb*4 + 2*p], hv);
        }
        arrive(&FH[cb]);   // h(t+1) published
      }
    }
  }
}

extern "C" void kernel_launch(void* const* d_in, const int* in_sizes, int n_in,
                              void* d_out, int out_size, void* d_ws, size_t ws_size,
                              hipStream_t stream) {
  const float* x   = (const float*)d_in[0];
  const float* Wx  = (const float*)d_in[1];
  const float* Wh  = (const float*)d_in[2];
  const float* bl  = (const float*)d_in[3];
  const float* Wif = (const float*)d_in[4];
  const float* bif = (const float*)d_in[5];
  const float* Wo  = (const float*)d_in[6];
  const float* bo  = (const float*)d_in[7];
  float* out = (float*)d_out;

  float* Xp = (float*)d_ws;                         // 4096*2048
  float* Uh = Xp + (size_t)4096*2048;               // 128*UHT
  float* Vh = Uh + (size_t)TT*UHT;                  // 128*VHT
  unsigned* fl = (unsigned*)(Vh + (size_t)TT*VHT);  // NFLAGS

  // 1) Xproj = x @ Wx[:512] + b_lstm
  gemm_bias<<<dim3(2048/64, 4096/64), dim3(256), 0, stream>>>(x, Wx, bl, Xp, 2048, 512);

  // 2) flags
  init_flags<<<dim3(1), dim3(512), 0, stream>>>(fl);

  // 3) cooperative weight-stationary recurrent core (dataflow sync, RMW flags)
  const int smem_bytes = CL_TOT * 4;  // 126784
  (void)hipFuncSetAttribute((const void*)dnc_coop, hipFuncAttributeMaxDynamicSharedMemorySize, smem_bytes);
  void* args[] = { (void*)&Xp, (void*)&Wx, (void*)&Wh, (void*)&Wif, (void*)&bif,
                   (void*)&Uh, (void*)&Vh, (void*)&fl };
  (void)hipLaunchCooperativeKernel((void*)dnc_coop, dim3(NBLK), dim3(1024), args,
                                   (unsigned int)smem_bytes, stream);

  // 4) out = [reads,h] @ W_out + b_out  (reads Uh directly, remaps rows)
  gemm_out<<<dim3(512/64, 4096/64), dim3(256), 0, stream>>>(Uh, Wo, bo, out);
}